// Round 5
// baseline (397.125 us; speedup 1.0000x reference)
//
#include <hip/hip_runtime.h>

// SegmentedAttention round 14 = r13 non-attn + attn {PV->mfma32 via K-row
// permutation, intra-block KV-split for 4 waves/SIMD}.
// r13 floor analysis: MFMA pipe 48us of 71 (PV's 16x16x16 = half rate =
// 34us) + 2 waves/SIMD latency exposure. Fix A: stage K rows permuted by
// phi(L)=[nt1|q1q0|nt0|r1r0] (free: applied to global src row) -> swapped
// QK output IS the mfma_16x16x32 A-frag -> PV = 16 mfma32 + 8 b128 reads
// (MFMA pipe 48->31us). Fix B: 512-thr blocks, 2 halves x 4 waves, each
// half streams 18 KV tiles in its own LDS dbuf (73728B, 2 blk/CU = 16
// waves/CU); Wg gate weights read direct from global (L2); halves combine
// via LDS CombO/ls0 alias; half1 runs epilogue. launch_bounds(512,4).
// ws (MB): kb16@0(8) qb16@8(8) vb16@16(8) vt16@24(8) xh@32(8,=fusedb)
//   xl@40(8) Wqt@48(2) Wvt@50(2) Wot@52(2) Wkh@54(2) Wkl@56(2) Wgt@58(1)
//   norms2@59(1) gk@60(1) gvt@61(1) -> 62MB

constexpr int SEQ    = 2048;
constexpr int DMODEL = 1024;
constexpr int NH     = 16;
constexpr int DHEAD  = 64;
constexpr int BHT    = 32;
constexpr int NG     = 204;
constexpr int NGPAD  = 256;
constexpr float LNEPS = 1e-5f;

typedef __attribute__((ext_vector_type(8))) short short8;
typedef __attribute__((ext_vector_type(4))) short short4v;
typedef __attribute__((ext_vector_type(4))) float f32x4;

__device__ __forceinline__ unsigned short f2bf(float f) {
    unsigned int u = __float_as_uint(f);
    u += 0x7FFFu + ((u >> 16) & 1u);
    return (unsigned short)(u >> 16);
}
__device__ __forceinline__ float bf2f(unsigned short b) {
    return __uint_as_float(((unsigned int)b) << 16);
}

// ---------------------------------------------------------------------------
// prep: blocks [0,2048): x hilo split; [2048,3072): weight transposes;
// block 3072: Wg^T bf16.
// ---------------------------------------------------------------------------
__global__ __launch_bounds__(256)
void prep_k(const float* __restrict__ x,
            const float* __restrict__ Wq, const float* __restrict__ Wv,
            const float* __restrict__ Wo, const float* __restrict__ Wk,
            const float* __restrict__ Wg,
            unsigned short* __restrict__ xh, unsigned short* __restrict__ xl,
            unsigned short* __restrict__ Wqt, unsigned short* __restrict__ Wvt,
            unsigned short* __restrict__ Wot, unsigned short* __restrict__ Wkh,
            unsigned short* __restrict__ Wkl, unsigned short* __restrict__ Wgt)
{
    const int bid = blockIdx.x;
    const int tid = threadIdx.x;

    if (bid < 2048) {
        int i = (bid * 256 + tid) << 3;
        short8 h, l;
#pragma unroll
        for (int j = 0; j < 8; ++j) {
            float v = x[i + j];
            unsigned short hb = f2bf(v);
            h[j] = (short)hb;
            l[j] = (short)f2bf(v - bf2f(hb));
        }
        *(short8*)(xh + i) = h;
        *(short8*)(xl + i) = l;
        return;
    }
    if (bid == 3072) {
#pragma unroll
        for (int i = 0; i < 32; ++i) {
            int o = tid * 32 + i;
            int dg = o >> 7, jj = o & 127;
            Wgt[o] = f2bf(Wg[jj * 64 + dg]);
        }
        return;
    }

    __shared__ float tile[64][68];
    const int sub = bid - 2048;
    const int which = sub >> 8;             // 0:Wq 1:Wv 2:Wo 3:Wk
    const int b = sub & 255;
    const int n0 = (b & 15) * 64, k0 = (b >> 4) * 64;
    const float* W = (which == 0) ? Wq : (which == 1) ? Wv : (which == 2) ? Wo : Wk;
    const int Kd = DMODEL, Nd = DMODEL;

#pragma unroll
    for (int p = 0; p < 4; ++p) {
        int c = tid + (p << 8);
        int r = c >> 4, c4 = (c & 15) << 2;
        *(float4*)&tile[r][c4] = *(const float4*)(W + (size_t)(k0 + r) * Nd + n0 + c4);
    }
    __syncthreads();
#pragma unroll
    for (int p = 0; p < 4; ++p) {
        int c = tid + (p << 8);
        int n = c >> 4, k4 = (c & 15) << 2;
        if (which < 3) {
            unsigned short* Wt = (which == 0) ? Wqt : (which == 1) ? Wvt : Wot;
            short4v o;
#pragma unroll
            for (int j = 0; j < 4; ++j) o[j] = (short)f2bf(tile[k4 + j][n]);
            *(short4v*)(Wt + (size_t)(n0 + n) * Kd + k0 + k4) = o;
        } else {
            short4v oh, ol;
#pragma unroll
            for (int j = 0; j < 4; ++j) {
                float v = tile[k4 + j][n];
                unsigned short hb = f2bf(v);
                oh[j] = (short)hb;
                ol[j] = (short)f2bf(v - bf2f(hb));
            }
            *(short4v*)(Wkh + (size_t)(n0 + n) * Kd + k0 + k4) = oh;
            *(short4v*)(Wkl + (size_t)(n0 + n) * Kd + k0 + k4) = ol;
        }
    }
}

// ---------------------------------------------------------------------------
// bf16 MFMA GEMM, 512 thr, 128x128 tile, 8 waves 2x4, reg-prefetch dbuf.
// mode 0: fp32 out = acc + bias.
// mode 3: Q|V: n<1024 -> qb (acc*0.125*log2e, exp2-folded); n>=1024 -> vb
//         AND vt (transposed).
// ---------------------------------------------------------------------------
__global__ __launch_bounds__(512)
void gemm_bf16_k(const unsigned short* __restrict__ A,
                 const unsigned short* __restrict__ Bt,
                 const float* __restrict__ bias,
                 void* __restrict__ outv, void* __restrict__ outv2,
                 unsigned short* __restrict__ vtout,
                 int M, int N, int K, int mode)
{
    __shared__ __align__(16) unsigned short As[128][72];
    __shared__ __align__(16) unsigned short Bs[128][72];
    const int tid = threadIdx.x;
    const int lane = tid & 63, wave = tid >> 6;
    const int quad = lane >> 4, ln = lane & 15;
    const int mh = (wave >> 2) << 6;
    const int nh = (wave & 3) << 5;
    const int m0 = blockIdx.y * 128, n0 = blockIdx.x * 128;

    f32x4 acc[4][2];
#pragma unroll
    for (int i = 0; i < 4; ++i)
#pragma unroll
        for (int j = 0; j < 2; ++j) acc[i][j] = (f32x4){0.f, 0.f, 0.f, 0.f};

    short8 areg[2], breg[2];
#pragma unroll
    for (int p = 0; p < 2; ++p) {
        int c = tid + (p << 9);
        int row = c >> 3, col8 = (c & 7) << 3;
        areg[p] = *(const short8*)(A + (size_t)(m0 + row) * K + col8);
        breg[p] = *(const short8*)(Bt + (size_t)(n0 + row) * K + col8);
    }

    for (int k0 = 0; k0 < K; k0 += 64) {
        __syncthreads();
#pragma unroll
        for (int p = 0; p < 2; ++p) {
            int c = tid + (p << 9);
            int row = c >> 3, col8 = (c & 7) << 3;
            *(short8*)&As[row][col8] = areg[p];
            *(short8*)&Bs[row][col8] = breg[p];
        }
        __syncthreads();
        if (k0 + 64 < K) {
#pragma unroll
            for (int p = 0; p < 2; ++p) {
                int c = tid + (p << 9);
                int row = c >> 3, col8 = (c & 7) << 3;
                areg[p] = *(const short8*)(A + (size_t)(m0 + row) * K + k0 + 64 + col8);
                breg[p] = *(const short8*)(Bt + (size_t)(n0 + row) * K + k0 + 64 + col8);
            }
        }
#pragma unroll
        for (int ch = 0; ch < 2; ++ch) {
            short8 af[4], bf[2];
#pragma unroll
            for (int mt = 0; mt < 4; ++mt)
                af[mt] = *(const short8*)&As[mh + mt * 16 + ln][ch * 32 + quad * 8];
#pragma unroll
            for (int nt = 0; nt < 2; ++nt)
                bf[nt] = *(const short8*)&Bs[nh + nt * 16 + ln][ch * 32 + quad * 8];
#pragma unroll
            for (int mt = 0; mt < 4; ++mt)
#pragma unroll
                for (int nt = 0; nt < 2; ++nt)
                    acc[mt][nt] = __builtin_amdgcn_mfma_f32_16x16x32_bf16(
                        af[mt], bf[nt], acc[mt][nt], 0, 0, 0);
        }
    }

    if (mode == 0) {
        float* out = (float*)outv;
#pragma unroll
        for (int mt = 0; mt < 4; ++mt)
#pragma unroll
            for (int nt = 0; nt < 2; ++nt)
#pragma unroll
                for (int r = 0; r < 4; ++r) {
                    int m = m0 + mh + mt * 16 + quad * 4 + r;
                    int n = n0 + nh + nt * 16 + ln;
                    out[(size_t)m * N + n] = acc[mt][nt][r] + bias[n];
                }
    } else {
#pragma unroll
        for (int mt = 0; mt < 4; ++mt)
#pragma unroll
            for (int nt = 0; nt < 2; ++nt) {
                int n = n0 + nh + nt * 16 + ln;
                int mb = m0 + mh + mt * 16 + quad * 4;
                int b = mb >> 11, s0 = mb & (SEQ - 1);
                int d = n & 63;
                if (n < DMODEL) {           // Q, pre-scaled incl. log2(e)
                    int h = n >> 6;
                    unsigned short* qp_ =
                        (unsigned short*)outv + ((size_t)(b * NH + h) * SEQ + s0) * DHEAD + d;
#pragma unroll
                    for (int r = 0; r < 4; ++r)
                        qp_[(size_t)r * DHEAD] = f2bf(acc[mt][nt][r] * 0.18033688f);
                } else {                    // V: row-major + transposed
                    int h = (n >> 6) - NH;
                    unsigned short* vp_ =
                        (unsigned short*)outv2 + ((size_t)(b * NH + h) * SEQ + s0) * DHEAD + d;
                    short4v tv;
#pragma unroll
                    for (int r = 0; r < 4; ++r) {
                        unsigned short bv = f2bf(acc[mt][nt][r]);
                        vp_[(size_t)r * DHEAD] = bv;
                        tv[r] = (short)bv;
                    }
                    *(short4v*)(vtout + ((size_t)(b * NH + h) * DHEAD + d) * SEQ + s0) = tv;
                }
            }
    }
}

// ---------------------------------------------------------------------------
// Compensated K projection: 512 thr, 64x128 tile, reg-prefetch dbuf.
// ---------------------------------------------------------------------------
__global__ __launch_bounds__(512)
void gemm_kproj_mfma(const unsigned short* __restrict__ xh,
                     const unsigned short* __restrict__ xl,
                     const unsigned short* __restrict__ Wh,
                     const unsigned short* __restrict__ Wl,
                     unsigned short* __restrict__ kout,
                     float* __restrict__ norms2)
{
    __shared__ __align__(16) unsigned short Ah[64][72];
    __shared__ __align__(16) unsigned short Al[64][72];
    __shared__ __align__(16) unsigned short Bh[128][72];
    __shared__ __align__(16) unsigned short Bl[128][72];
    const int K = DMODEL;
    const int tid = threadIdx.x;
    const int lane = tid & 63, wave = tid >> 6;
    const int quad = lane >> 4, ln = lane & 15;
    const int mh = (wave >> 1) << 4;
    const int nh = (wave & 1) << 6;
    const int m0 = blockIdx.y * 64, n0 = blockIdx.x * 128;

    f32x4 acc[4];
#pragma unroll
    for (int j = 0; j < 4; ++j) acc[j] = (f32x4){0.f, 0.f, 0.f, 0.f};

    const int arow = tid >> 3, acol8 = (tid & 7) << 3;
    short8 ahreg, alreg, bhreg[2], blreg[2];
    {
        size_t ga = (size_t)(m0 + arow) * K + acol8;
        ahreg = *(const short8*)(xh + ga);
        alreg = *(const short8*)(xl + ga);
#pragma unroll
        for (int p = 0; p < 2; ++p) {
            int c = tid + (p << 9);
            int row = c >> 3, col8 = (c & 7) << 3;
            size_t gb = (size_t)(n0 + row) * K + col8;
            bhreg[p] = *(const short8*)(Wh + gb);
            blreg[p] = *(const short8*)(Wl + gb);
        }
    }

    for (int k0 = 0; k0 < K; k0 += 64) {
        __syncthreads();
        *(short8*)&Ah[arow][acol8] = ahreg;
        *(short8*)&Al[arow][acol8] = alreg;
#pragma unroll
        for (int p = 0; p < 2; ++p) {
            int c = tid + (p << 9);
            int row = c >> 3, col8 = (c & 7) << 3;
            *(short8*)&Bh[row][col8] = bhreg[p];
            *(short8*)&Bl[row][col8] = blreg[p];
        }
        __syncthreads();
        if (k0 + 64 < K) {
            size_t ga = (size_t)(m0 + arow) * K + k0 + 64 + acol8;
            ahreg = *(const short8*)(xh + ga);
            alreg = *(const short8*)(xl + ga);
#pragma unroll
            for (int p = 0; p < 2; ++p) {
                int c = tid + (p << 9);
                int row = c >> 3, col8 = (c & 7) << 3;
                size_t gb = (size_t)(n0 + row) * K + k0 + 64 + col8;
                bhreg[p] = *(const short8*)(Wh + gb);
                blreg[p] = *(const short8*)(Wl + gb);
            }
        }
#pragma unroll
        for (int ch = 0; ch < 2; ++ch) {
            short8 bh4[4], bl4[4];
#pragma unroll
            for (int nt = 0; nt < 4; ++nt) {
                bh4[nt] = *(const short8*)&Bh[nh + nt * 16 + ln][ch * 32 + quad * 8];
                bl4[nt] = *(const short8*)&Bl[nh + nt * 16 + ln][ch * 32 + quad * 8];
            }
            short8 ah = *(const short8*)&Ah[mh + ln][ch * 32 + quad * 8];
            short8 al = *(const short8*)&Al[mh + ln][ch * 32 + quad * 8];
#pragma unroll
            for (int nt = 0; nt < 4; ++nt) {
                acc[nt] = __builtin_amdgcn_mfma_f32_16x16x32_bf16(ah, bh4[nt], acc[nt], 0, 0, 0);
                acc[nt] = __builtin_amdgcn_mfma_f32_16x16x32_bf16(ah, bl4[nt], acc[nt], 0, 0, 0);
                acc[nt] = __builtin_amdgcn_mfma_f32_16x16x32_bf16(al, bh4[nt], acc[nt], 0, 0, 0);
            }
        }
    }

    const int h = (n0 + nh) >> 6;
#pragma unroll
    for (int r = 0; r < 4; ++r) {
        int m = m0 + mh + quad * 4 + r;
        int b = m >> 11, s = m & (SEQ - 1);
        size_t rowbase = ((size_t)(b * NH + h) * SEQ + s) * DHEAD;
#pragma unroll
        for (int nt = 0; nt < 4; ++nt)
            kout[rowbase + nt * 16 + ln] = f2bf(acc[nt][r]);
        float s2 = acc[0][r] * acc[0][r] + acc[1][r] * acc[1][r] +
                   acc[2][r] * acc[2][r] + acc[3][r] * acc[3][r];
#pragma unroll
        for (int off = 1; off <= 8; off <<= 1)
            s2 += __shfl_xor(s2, off);
        if (ln == 0)
            norms2[(size_t)(b * NH + h) * SEQ + s] = s2;
    }
}

// ---------------------------------------------------------------------------
// topk + gather fused, 512 threads.
// ---------------------------------------------------------------------------
__global__ __launch_bounds__(512)
void topk_gather_k(const float* __restrict__ norms2,
                   const unsigned short* __restrict__ k,
                   const unsigned short* __restrict__ v,
                   unsigned short* __restrict__ gk,
                   unsigned short* __restrict__ gvt)
{
    __shared__ unsigned long long keys[SEQ];
    __shared__ int tix[NGPAD];
    __shared__ __align__(16) unsigned short T[64][72];
    const int bh = blockIdx.x;
    const int tid = threadIdx.x;
    const float* nb = norms2 + (size_t)bh * SEQ;
    const size_t base = (size_t)bh * SEQ * DHEAD;

    for (int i = tid; i < SEQ; i += 512) {
        float nrm = sqrtf(nb[i]);
        keys[i] = ((unsigned long long)__float_as_uint(nrm) << 32) |
                  (unsigned int)(0xFFFFFFFFu - (unsigned int)i);
    }
    __syncthreads();
    for (int kk = 2; kk <= SEQ; kk <<= 1) {
        for (int j = kk >> 1; j > 0; j >>= 1) {
            for (int i = tid; i < SEQ; i += 512) {
                int ixj = i ^ j;
                if (ixj > i) {
                    unsigned long long a = keys[i], b = keys[ixj];
                    bool up = ((i & kk) == 0);
                    if ((a > b) == up) { keys[i] = b; keys[ixj] = a; }
                }
            }
            __syncthreads();
        }
    }
    if (tid < NGPAD) {
        tix[tid] = (tid < NG)
            ? (int)(0xFFFFFFFFu - (unsigned int)(keys[SEQ - 1 - tid] & 0xFFFFFFFFu))
            : 0;
    }
    __syncthreads();

    for (int t = 0; t < NGPAD / 64; ++t) {
        {
            int idx = tid;
            int row = idx >> 3, col8 = (idx & 7) << 3;
            int g = t * 64 + row;
            short8 kv = (short8)0, vv = (short8)0;
            if (g < NG) {
                int sidx = tix[g];
                kv = *(const short8*)(k + base + (size_t)sidx * DHEAD + col8);
                vv = *(const short8*)(v + base + (size_t)sidx * DHEAD + col8);
            }
            *(short8*)(gk + ((size_t)bh * NGPAD + g) * DHEAD + col8) = kv;
            *(short8*)&T[row][col8] = vv;
        }
        __syncthreads();
        {
            int idx = tid;
            int d = idx >> 3, k8 = (idx & 7) << 3;
            short8 o;
#pragma unroll
            for (int i = 0; i < 8; ++i) o[i] = (short)T[k8 + i][d];
            *(short8*)(gvt + ((size_t)bh * DHEAD + d) * NGPAD + t * 64 + k8) = o;
        }
        __syncthreads();
    }
}

// ---------------------------------------------------------------------------
// Fused attention r14: 512 thr = 2 halves x 4 waves x 32 q-rows. Each half
// streams 18 KV tiles (half0: 0..17, half1: 18..31 local + 4 global) in its
// own LDS dbuf. K rows staged permuted by phi so swapped-QK P output is the
// mfma_16x16x32 A-frag (PV at full rate). Halves combine via LDS; half1
// runs epilogue with Wg read direct from global.
// ---------------------------------------------------------------------------
__global__ __launch_bounds__(512, 4)
void attn_fused_k(const unsigned short* __restrict__ qb,
                  const unsigned short* __restrict__ kb,
                  const unsigned short* __restrict__ vt,
                  const unsigned short* __restrict__ gk,
                  const unsigned short* __restrict__ gvt,
                  const unsigned short* __restrict__ Wgt,
                  const float* __restrict__ gamma,
                  const float* __restrict__ beta,
                  const float* __restrict__ bg,
                  unsigned short* __restrict__ fused)
{
    // smem shorts[36864] = 73728 B:
    //   [0,9216)      half0 Ks dbuf [2][64][72]
    //   [9216,18432)  half1 Ks dbuf
    //   [18432,27648) half0 Vt dbuf
    //   [27648,36864) half1 Vt dbuf
    // epilogue aliases (ordered by barriers):
    //   CombO f32[128][65] at float-off 0   (shorts [0,16640))
    //   ls0   f32[128]     at float-off 8320 (shorts [16640,16896))
    //   Ps    u16[128][72] at short-off 16896 (shorts [16896,26112))
    __shared__ __align__(16) unsigned short smem[36864];

    const int flat = blockIdx.x;
    const int bh = ((flat >> 7) << 3) | (flat & 7);   // flat%8 == bh%8 (XCD)
    const int q0 = ((flat >> 3) & 15) * 128;
    const int tid = threadIdx.x;
    const int lane = tid & 63, wave = tid >> 6;       // 8 waves
    const int half = wave >> 2, w4 = wave & 3;
    const int quad = lane >> 4, ln = lane & 15;
    const size_t base = (size_t)bh * SEQ * DHEAD;
    const unsigned short* gkb = gk + (size_t)bh * NGPAD * DHEAD;
    const unsigned short* gvb = gvt + (size_t)bh * DHEAD * NGPAD;

    unsigned short* const myKs = smem + half * 9216;
    unsigned short* const myVt = smem + 18432 + half * 9216;
    float* const CombO = (float*)smem;                 // [128][65]
    float* const ls0f  = (float*)smem + 8320;          // [128]
    unsigned short (*Ps)[72] = (unsigned short (*)[72])(smem + 16896);

    short8 qf[2][2];
#pragma unroll
    for (int mt = 0; mt < 2; ++mt) {
        const unsigned short* qp = qb + base + (size_t)(q0 + w4 * 32 + mt * 16 + ln) * DHEAD;
        qf[mt][0] = *(const short8*)(qp + quad * 8);
        qf[mt][1] = *(const short8*)(qp + 32 + quad * 8);
    }

    f32x4 O[2][4], Og[2][4];
#pragma unroll
    for (int mt = 0; mt < 2; ++mt)
#pragma unroll
        for (int nt = 0; nt < 4; ++nt) {
            O[mt][nt] = (f32x4){0.f, 0.f, 0.f, 0.f};
            Og[mt][nt] = (f32x4){0.f, 0.f, 0.f, 0.f};
        }
    float ls[2] = {0.f, 0.f}, lg[2] = {0.f, 0.f};

    // staging roles: 256 threads per half, 2 short8 each for K and V
    const int tid_h = tid & 255;
    short8 kreg[2], vreg[2];
    int srow[2], scol8[2], psrow[2];
#pragma unroll
    for (int p = 0; p < 2; ++p) {
        int idx = tid_h + (p << 8);
        srow[p] = idx >> 3;
        scol8[p] = (idx & 7) << 3;
        // phi: [b5 | b3 b2 | b4 | b1 b0]  (K-row permutation)
        psrow[p] = (srow[p] & 0x20) | ((srow[p] & 0x0C) << 1) |
                   ((srow[p] & 0x10) >> 2) | (srow[p] & 3);
    }

    const int T0 = half * 18;   // half0: tiles 0..17; half1: 18..35

    auto loadT = [&](int T) {
#pragma unroll
        for (int p = 0; p < 2; ++p) {
            if (T < 32) {
                kreg[p] = *(const short8*)(kb + base + (size_t)(T * 64 + psrow[p]) * DHEAD + scol8[p]);
                vreg[p] = *(const short8*)(vt + base + (size_t)srow[p] * SEQ + T * 64 + scol8[p]);
            } else {
                int g = T - 32;
                kreg[p] = *(const short8*)(gkb + (size_t)(g * 64 + psrow[p]) * DHEAD + scol8[p]);
                vreg[p] = *(const short8*)(gvb + (size_t)srow[p] * NGPAD + g * 64 + scol8[p]);
            }
        }
    };
    auto storeT = [&](int buf) {
        unsigned short* kd = myKs + buf * 4608;
        unsigned short* vd = myVt + buf * 4608;
#pragma unroll
        for (int p = 0; p < 2; ++p) {
            *(short8*)&kd[srow[p] * 72 + scol8[p]] = kreg[p];
            *(short8*)&vd[srow[p] * 72 + scol8[p]] = vreg[p];
        }
    };

    loadT(T0);
    storeT(0);
    loadT(T0 + 1);
    __syncthreads();

    for (int i = 0; i < 18; ++i) {
        const int T = T0 + i;
        const int cur = i & 1;
        const unsigned short* Kc = myKs + cur * 4608;
        const unsigned short* Vc = myVt + cur * 4608;

        // swapped QK^T: lane holds S^T[k_phys = phi(nt*16+quad*4+r)][q=ln]
        f32x4 s[2][4];
#pragma unroll
        for (int mt = 0; mt < 2; ++mt)
#pragma unroll
            for (int nt = 0; nt < 4; ++nt) s[mt][nt] = (f32x4){0.f, 0.f, 0.f, 0.f};
        __builtin_amdgcn_s_setprio(1);
#pragma unroll
        for (int nt = 0; nt < 4; ++nt) {
            short8 kf0 = *(const short8*)&Kc[(nt * 16 + ln) * 72 + quad * 8];
            short8 kf1 = *(const short8*)&Kc[(nt * 16 + ln) * 72 + 32 + quad * 8];
#pragma unroll
            for (int mt = 0; mt < 2; ++mt) {
                s[mt][nt] = __builtin_amdgcn_mfma_f32_16x16x32_bf16(kf0, qf[mt][0], s[mt][nt], 0, 0, 0);
                s[mt][nt] = __builtin_amdgcn_mfma_f32_16x16x32_bf16(kf1, qf[mt][1], s[mt][nt], 0, 0, 0);
            }
        }
        __builtin_amdgcn_s_setprio(0);

        // exp + pack into mfma32 A-frags: pf8[mt][c] covers k_phys c*32+quad*8+[0..7]
        short8 pf8[2][2];
        if (T < 32) {
#pragma unroll
            for (int mt = 0; mt < 2; ++mt)
#pragma unroll
                for (int nt = 0; nt < 4; ++nt)
#pragma unroll
                    for (int r = 0; r < 4; ++r) {
                        unsigned int u = __float_as_uint(__builtin_amdgcn_exp2f(s[mt][nt][r]));
                        ls[mt] += __uint_as_float(u & 0xFFFF0000u);
                        pf8[mt][nt >> 1][((nt & 1) << 2) | r] = (short)(u >> 16);
                    }
            __builtin_amdgcn_s_setprio(1);
#pragma unroll
            for (int dt = 0; dt < 4; ++dt)
#pragma unroll
                for (int c = 0; c < 2; ++c) {
                    short8 vf = *(const short8*)&Vc[(dt * 16 + ln) * 72 + c * 32 + quad * 8];
#pragma unroll
                    for (int mt = 0; mt < 2; ++mt)
                        O[mt][dt] = __builtin_amdgcn_mfma_f32_16x16x32_bf16(
                            pf8[mt][c], vf, O[mt][dt], 0, 0, 0);
                }
            __builtin_amdgcn_s_setprio(0);
        } else {
            const int tg = T - 32;
#pragma unroll
            for (int nt = 0; nt < 4; ++nt)
#pragma unroll
                for (int r = 0; r < 4; ++r) {
                    int phi = ((nt >> 1) << 5) | (quad << 3) | ((nt & 1) << 2) | r;
                    bool valid = (tg * 64 + phi) < NG;
#pragma unroll
                    for (int mt = 0; mt < 2; ++mt) {
                        float p = valid ? __builtin_amdgcn_exp2f(s[mt][nt][r]) : 0.f;
                        unsigned int u = __float_as_uint(p);
                        lg[mt] += __uint_as_float(u & 0xFFFF0000u);
                        pf8[mt][nt >> 1][((nt & 1) << 2) | r] = (short)(u >> 16);
                    }
                }
            __builtin_amdgcn_s_setprio(1);
#pragma unroll
            for (int dt = 0; dt < 4; ++dt)
#pragma unroll
                for (int c = 0; c < 2; ++c) {
                    short8 vf = *(const short8*)&Vc[(dt * 16 + ln) * 72 + c * 32 + quad * 8];
#pragma unroll
                    for (int mt = 0; mt < 2; ++mt)
                        Og[mt][dt] = __builtin_amdgcn_mfma_f32_16x16x32_bf16(
                            pf8[mt][c], vf, Og[mt][dt], 0, 0, 0);
                }
            __builtin_amdgcn_s_setprio(0);
        }

        if (i < 17) {
            storeT(cur ^ 1);                // regs hold tile T+1
            if (i < 16) loadT(T0 + i + 2);
        }
        __syncthreads();
    }

    // ---- reductions (all waves): per-q partials over (quad) ----
#pragma unroll
    for (int mt = 0; mt < 2; ++mt) {
        ls[mt] += __shfl_xor(ls[mt], 16);
        ls[mt] += __shfl_xor(ls[mt], 32);
        lg[mt] += __shfl_xor(lg[mt], 16);
        lg[mt] += __shfl_xor(lg[mt], 32);
    }

    // ---- half0 publishes partials ----
    if (half == 0) {
#pragma unroll
        for (int mt = 0; mt < 2; ++mt)
#pragma unroll
            for (int dt = 0; dt < 4; ++dt)
#pragma unroll
                for (int r = 0; r < 4; ++r)
                    CombO[(size_t)(w4 * 32 + mt * 16 + quad * 4 + r) * 65 + dt * 16 + ln] =
                        O[mt][dt][r];
        if (quad == 0) {
            ls0f[w4 * 32 + ln] = ls[0];
            ls0f[w4 * 32 + 16 + ln] = ls[1];
        }
    }
    __syncthreads();
    if (half == 0) return;

    // ---- half1: combine + epilogue ----
    float lsT[2];
    lsT[0] = ls[0] + ls0f[w4 * 32 + ln];
    lsT[1] = ls[1] + ls0f[w4 * 32 + 16 + ln];
#pragma unroll
    for (int mt = 0; mt < 2; ++mt)
#pragma unroll
        for (int dt = 0; dt < 4; ++dt)
#pragma unroll
            for (int r = 0; r < 4; ++r)
                O[mt][dt][r] += CombO[(size_t)(w4 * 32 + mt * 16 + quad * 4 + r) * 65 + dt * 16 + ln];

    float invl[2][4], invg[2][4];
#pragma unroll
    for (int mt = 0; mt < 2; ++mt)
#pragma unroll
        for (int r = 0; r < 4; ++r) {
            invl[mt][r] = 1.f / __shfl(lsT[mt], quad * 4 + r);
            invg[mt][r] = 1.f / __shfl(lg[mt], quad * 4 + r);
        }

    // ---- layernorm(global) ----
    float xs[2][4][4];
#pragma unroll
    for (int mt = 0; mt < 2; ++mt)
#pragma unroll
        for (int r = 0; r < 4; ++r) {
            float inv = invg[mt][r];
#pragma unroll
            for (int nt = 0; nt < 4; ++nt) xs[mt][nt][r] = Og[mt][nt][r] * inv;
        }
    float mu[2][4], rsd[2][4];
#pragma unroll
    for (int mt = 0; mt < 2; ++mt)
#pragma unroll
        for (int r = 0; r < 4; ++r) {
            float sm = xs[mt][0][r] + xs[mt][1][r] + xs[mt][2][r] + xs[mt][3][r];
#pragma unroll
            for (int off = 1; off <= 8; off <<= 1) sm += __shfl_xor(sm, off);
            mu[mt][r] = sm * (1.f / 64.f);
        }
#pragma unroll
    for (int mt = 0; mt < 2; ++mt)
#pragma unroll
        for (int r = 0; r < 4; ++r) {
            float sv = 0.f;
#pragma unroll
            for (int nt = 0; nt < 4; ++nt) {
                float d = xs[mt][nt][r] - mu[mt][r];
                sv += d * d;
            }
#pragma unroll
            for (int off = 1; off <= 8; off <<= 1) sv += __shfl_xor(sv, off);
            rsd[mt][r] = rsqrtf(sv * (1.f / 64.f) + LNEPS);
        }
#pragma unroll
    for (int nt = 0; nt < 4; ++nt) {
        float g = gamma[nt * 16 + ln], bb = beta[nt * 16 + ln];
#pragma unroll
        for (int mt = 0; mt < 2; ++mt)
#pragma unroll
            for (int r = 0; r < 4; ++r)
                xs[mt][nt][r] = (xs[mt][nt][r] - mu[mt][r]) * rsd[mt][r] * g + bb;
    }

    // ---- gate via MFMA (Ps alias; intra-wave rows, no barrier; Wg global) --
    float lf[2][4][4];
#pragma unroll
    for (int mt = 0; mt < 2; ++mt)
#pragma unroll
        for (int nt = 0; nt < 4; ++nt)
#pragma unroll
            for (int r = 0; r < 4; ++r) {
                lf[mt][nt][r] = O[mt][nt][r] * invl[mt][r];
                Ps[w4 * 32 + mt * 16 + quad * 4 + r][nt * 16 + ln] = f2bf(lf[mt][nt][r]);
            }
    f32x4 gacc[2][4];
#pragma unroll
    for (int ng = 0; ng < 4; ++ng) {
        float bgv = bg[ng * 16 + ln];
#pragma unroll
        for (int mt = 0; mt < 2; ++mt)
            gacc[mt][ng] = (f32x4){bgv, bgv, bgv, bgv};
    }
#pragma unroll
    for (int ch = 0; ch < 2; ++ch) {
        short8 af[2];
#pragma unroll
        for (int mt = 0; mt < 2; ++mt)
            af[mt] = *(const short8*)&Ps[w4 * 32 + mt * 16 + ln][ch * 32 + quad * 8];
#pragma unroll
        for (int ng = 0; ng < 4; ++ng) {
            short8 bf = *(const short8*)(Wgt + (size_t)(ng * 16 + ln) * 128 + ch * 32 + quad * 8);
#pragma unroll
            for (int mt = 0; mt < 2; ++mt)
                gacc[mt][ng] = __builtin_amdgcn_mfma_f32_16x16x32_bf16(af[mt], bf, gacc[mt][ng], 0, 0, 0);
        }
    }
#pragma unroll
    for (int mt = 0; mt < 2; ++mt)
#pragma unroll
        for (int nt = 0; nt < 4; ++nt)
#pragma unroll
            for (int r = 0; r < 4; ++r)
                Ps[w4 * 32 + mt * 16 + quad * 4 + r][nt * 16 + ln] = f2bf(xs[mt][nt][r]);
#pragma unroll
    for (int ch = 0; ch < 2; ++ch) {
        short8 af[2];
#pragma unroll
        for (int mt = 0; mt < 2; ++mt)
            af[mt] = *(const short8*)&Ps[w4 * 32 + mt * 16 + ln][ch * 32 + quad * 8];
#pragma unroll
        for (int ng = 0; ng < 4; ++ng) {
            short8 bf = *(const short8*)(Wgt + (size_t)(ng * 16 + ln) * 128 + 64 + ch * 32 + quad * 8);
#pragma unroll
            for (int mt = 0; mt < 2; ++mt)
                gacc[mt][ng] = __builtin_amdgcn_mfma_f32_16x16x32_bf16(af[mt], bf, gacc[mt][ng], 0, 0, 0);
        }
    }

    // ---- fuse + store ----
    const int b = bh >> 4, h = bh & 15;
#pragma unroll
    for (int mt = 0; mt < 2; ++mt)
#pragma unroll
        for (int ng = 0; ng < 4; ++ng)
#pragma unroll
            for (int r = 0; r < 4; ++r) {
                float gt = 1.f / (1.f + __expf(-gacc[mt][ng][r]));
                float f = gt * lf[mt][ng][r] + (1.f - gt) * xs[mt][ng][r];
                int s = q0 + w4 * 32 + mt * 16 + quad * 4 + r;
                fused[((size_t)(b * SEQ + s)) * DMODEL + h * DHEAD + ng * 16 + ln] = f2bf(f);
            }
}

// ---------------------------------------------------------------------------
extern "C" void kernel_launch(void* const* d_in, const int* in_sizes, int n_in,
                              void* d_out, int out_size, void* d_ws, size_t ws_size,
                              hipStream_t stream)
{
    (void)in_sizes; (void)n_in; (void)out_size; (void)ws_size;
    const float* x    = (const float*)d_in[0];
    const float* Wq   = (const float*)d_in[1];
    const float* Wk   = (const float*)d_in[2];
    const float* Wv   = (const float*)d_in[3];
    const float* Wo   = (const float*)d_in[4];
    const float* bo   = (const float*)d_in[5];
    const float* ln_g = (const float*)d_in[6];
    const float* ln_b = (const float*)d_in[7];
    const float* Wg   = (const float*)d_in[8];
    const float* bg   = (const float*)d_in[9];

    char* w = (char*)d_ws;
    const size_t MB = 1024ull * 1024ull;
    unsigned short* kb16  = (unsigned short*)(w);
    unsigned short* qb16  = (unsigned short*)(w + 8 * MB);
    unsigned short* vb16  = (unsigned short*)(w + 16 * MB);
    unsigned short* vt16  = (unsigned short*)(w + 24 * MB);
    unsigned short* xh    = (unsigned short*)(w + 32 * MB);
    unsigned short* xl    = (unsigned short*)(w + 40 * MB);
    unsigned short* Wqt   = (unsigned short*)(w + 48 * MB);
    unsigned short* Wvt   = (unsigned short*)(w + 50 * MB);   // contiguous after Wqt
    unsigned short* Wot   = (unsigned short*)(w + 52 * MB);
    unsigned short* Wkh   = (unsigned short*)(w + 54 * MB);
    unsigned short* Wkl   = (unsigned short*)(w + 56 * MB);
    unsigned short* Wgt   = (unsigned short*)(w + 58 * MB);
    float*          norms2= (float*)(w + 59 * MB);
    unsigned short* gk16  = (unsigned short*)(w + 60 * MB);
    unsigned short* gvt16 = (unsigned short*)(w + 61 * MB);
    unsigned short* fusedb = xh;   // xh dead after projections

    const int M = 4096, N = 1024, K = 1024;

    prep_k<<<3073, 256, 0, stream>>>(x, Wq, Wv, Wo, Wk, Wg,
                                     xh, xl, Wqt, Wvt, Wot, Wkh, Wkl, Wgt);

    dim3 gqv(2048 / 128, M / 128);
    gemm_bf16_k<<<gqv, 512, 0, stream>>>(xh, Wqt, nullptr, qb16, vb16, vt16,
                                         M, 2048, K, 3);

    dim3 gkp(N / 128, M / 64);
    gemm_kproj_mfma<<<gkp, 512, 0, stream>>>(xh, xl, Wkh, Wkl, kb16, norms2);

    topk_gather_k<<<BHT, 512, 0, stream>>>(norms2, kb16, vb16, gk16, gvt16);

    attn_fused_k<<<512, 512, 0, stream>>>(qb16, kb16, vt16, gk16, gvt16, Wgt,
                                          ln_g, ln_b, bg, fusedb);

    dim3 go_(N / 128, M / 128);
    gemm_bf16_k<<<go_, 512, 0, stream>>>(fusedb, Wot, bo, (float*)d_out, nullptr,
                                         nullptr, M, N, K, 0);
}

// Round 6
// 267.800 us; speedup vs baseline: 1.4829x; 1.4829x over previous
//
#include <hip/hip_runtime.h>

// SegmentedAttention round 15 = r13 shell + verified PV->mfma32 K-perm.
// r14 post-mortem: launch_bounds(512,4) forced VGPR=64 -> massive spill
// (WRITE_SIZE 8MB->586MB, 190us). But it PASSED -> phi-permutation + PV
// mfma32 math verified correct. r15: revert occupancy split, keep Fix A
// on the r13 256-thr/2-blk shell (124 VGPR, no spill): K staged from
// permuted global row phi(L)=[b5|b3b2|b4|b1b0] -> swapped-QK P output IS
// the mfma_16x16x32 A-frag -> PV = 16 mfma32 + 8 b128 V reads per tile
// (MFMA pipe 48->31us of the 71us kernel).
// ws (MB): kb16@0(8) qb16@8(8) vb16@16(8) vt16@24(8) xh@32(8,=fusedb)
//   xl@40(8) Wqt@48(2) Wvt@50(2) Wot@52(2) Wkh@54(2) Wkl@56(2) Wgt@58(1)
//   norms2@59(1) gk@60(1) gvt@61(1) -> 62MB

constexpr int SEQ    = 2048;
constexpr int DMODEL = 1024;
constexpr int NH     = 16;
constexpr int DHEAD  = 64;
constexpr int BHT    = 32;
constexpr int NG     = 204;
constexpr int NGPAD  = 256;
constexpr float LNEPS = 1e-5f;

typedef __attribute__((ext_vector_type(8))) short short8;
typedef __attribute__((ext_vector_type(4))) short short4v;
typedef __attribute__((ext_vector_type(4))) float f32x4;

__device__ __forceinline__ unsigned short f2bf(float f) {
    unsigned int u = __float_as_uint(f);
    u += 0x7FFFu + ((u >> 16) & 1u);
    return (unsigned short)(u >> 16);
}
__device__ __forceinline__ float bf2f(unsigned short b) {
    return __uint_as_float(((unsigned int)b) << 16);
}

// ---------------------------------------------------------------------------
// prep: blocks [0,2048): x hilo split; [2048,3072): weight transposes;
// block 3072: Wg^T bf16.
// ---------------------------------------------------------------------------
__global__ __launch_bounds__(256)
void prep_k(const float* __restrict__ x,
            const float* __restrict__ Wq, const float* __restrict__ Wv,
            const float* __restrict__ Wo, const float* __restrict__ Wk,
            const float* __restrict__ Wg,
            unsigned short* __restrict__ xh, unsigned short* __restrict__ xl,
            unsigned short* __restrict__ Wqt, unsigned short* __restrict__ Wvt,
            unsigned short* __restrict__ Wot, unsigned short* __restrict__ Wkh,
            unsigned short* __restrict__ Wkl, unsigned short* __restrict__ Wgt)
{
    const int bid = blockIdx.x;
    const int tid = threadIdx.x;

    if (bid < 2048) {
        int i = (bid * 256 + tid) << 3;
        short8 h, l;
#pragma unroll
        for (int j = 0; j < 8; ++j) {
            float v = x[i + j];
            unsigned short hb = f2bf(v);
            h[j] = (short)hb;
            l[j] = (short)f2bf(v - bf2f(hb));
        }
        *(short8*)(xh + i) = h;
        *(short8*)(xl + i) = l;
        return;
    }
    if (bid == 3072) {
#pragma unroll
        for (int i = 0; i < 32; ++i) {
            int o = tid * 32 + i;
            int dg = o >> 7, jj = o & 127;
            Wgt[o] = f2bf(Wg[jj * 64 + dg]);
        }
        return;
    }

    __shared__ float tile[64][68];
    const int sub = bid - 2048;
    const int which = sub >> 8;             // 0:Wq 1:Wv 2:Wo 3:Wk
    const int b = sub & 255;
    const int n0 = (b & 15) * 64, k0 = (b >> 4) * 64;
    const float* W = (which == 0) ? Wq : (which == 1) ? Wv : (which == 2) ? Wo : Wk;
    const int Kd = DMODEL, Nd = DMODEL;

#pragma unroll
    for (int p = 0; p < 4; ++p) {
        int c = tid + (p << 8);
        int r = c >> 4, c4 = (c & 15) << 2;
        *(float4*)&tile[r][c4] = *(const float4*)(W + (size_t)(k0 + r) * Nd + n0 + c4);
    }
    __syncthreads();
#pragma unroll
    for (int p = 0; p < 4; ++p) {
        int c = tid + (p << 8);
        int n = c >> 4, k4 = (c & 15) << 2;
        if (which < 3) {
            unsigned short* Wt = (which == 0) ? Wqt : (which == 1) ? Wvt : Wot;
            short4v o;
#pragma unroll
            for (int j = 0; j < 4; ++j) o[j] = (short)f2bf(tile[k4 + j][n]);
            *(short4v*)(Wt + (size_t)(n0 + n) * Kd + k0 + k4) = o;
        } else {
            short4v oh, ol;
#pragma unroll
            for (int j = 0; j < 4; ++j) {
                float v = tile[k4 + j][n];
                unsigned short hb = f2bf(v);
                oh[j] = (short)hb;
                ol[j] = (short)f2bf(v - bf2f(hb));
            }
            *(short4v*)(Wkh + (size_t)(n0 + n) * Kd + k0 + k4) = oh;
            *(short4v*)(Wkl + (size_t)(n0 + n) * Kd + k0 + k4) = ol;
        }
    }
}

// ---------------------------------------------------------------------------
// bf16 MFMA GEMM, 512 thr, 128x128 tile, 8 waves 2x4, reg-prefetch dbuf.
// mode 0: fp32 out = acc + bias.
// mode 3: Q|V: n<1024 -> qb (acc*0.125*log2e, exp2-folded); n>=1024 -> vb
//         AND vt (transposed).
// ---------------------------------------------------------------------------
__global__ __launch_bounds__(512)
void gemm_bf16_k(const unsigned short* __restrict__ A,
                 const unsigned short* __restrict__ Bt,
                 const float* __restrict__ bias,
                 void* __restrict__ outv, void* __restrict__ outv2,
                 unsigned short* __restrict__ vtout,
                 int M, int N, int K, int mode)
{
    __shared__ __align__(16) unsigned short As[128][72];
    __shared__ __align__(16) unsigned short Bs[128][72];
    const int tid = threadIdx.x;
    const int lane = tid & 63, wave = tid >> 6;
    const int quad = lane >> 4, ln = lane & 15;
    const int mh = (wave >> 2) << 6;
    const int nh = (wave & 3) << 5;
    const int m0 = blockIdx.y * 128, n0 = blockIdx.x * 128;

    f32x4 acc[4][2];
#pragma unroll
    for (int i = 0; i < 4; ++i)
#pragma unroll
        for (int j = 0; j < 2; ++j) acc[i][j] = (f32x4){0.f, 0.f, 0.f, 0.f};

    short8 areg[2], breg[2];
#pragma unroll
    for (int p = 0; p < 2; ++p) {
        int c = tid + (p << 9);
        int row = c >> 3, col8 = (c & 7) << 3;
        areg[p] = *(const short8*)(A + (size_t)(m0 + row) * K + col8);
        breg[p] = *(const short8*)(Bt + (size_t)(n0 + row) * K + col8);
    }

    for (int k0 = 0; k0 < K; k0 += 64) {
        __syncthreads();
#pragma unroll
        for (int p = 0; p < 2; ++p) {
            int c = tid + (p << 9);
            int row = c >> 3, col8 = (c & 7) << 3;
            *(short8*)&As[row][col8] = areg[p];
            *(short8*)&Bs[row][col8] = breg[p];
        }
        __syncthreads();
        if (k0 + 64 < K) {
#pragma unroll
            for (int p = 0; p < 2; ++p) {
                int c = tid + (p << 9);
                int row = c >> 3, col8 = (c & 7) << 3;
                areg[p] = *(const short8*)(A + (size_t)(m0 + row) * K + k0 + 64 + col8);
                breg[p] = *(const short8*)(Bt + (size_t)(n0 + row) * K + k0 + 64 + col8);
            }
        }
#pragma unroll
        for (int ch = 0; ch < 2; ++ch) {
            short8 af[4], bf[2];
#pragma unroll
            for (int mt = 0; mt < 4; ++mt)
                af[mt] = *(const short8*)&As[mh + mt * 16 + ln][ch * 32 + quad * 8];
#pragma unroll
            for (int nt = 0; nt < 2; ++nt)
                bf[nt] = *(const short8*)&Bs[nh + nt * 16 + ln][ch * 32 + quad * 8];
#pragma unroll
            for (int mt = 0; mt < 4; ++mt)
#pragma unroll
                for (int nt = 0; nt < 2; ++nt)
                    acc[mt][nt] = __builtin_amdgcn_mfma_f32_16x16x32_bf16(
                        af[mt], bf[nt], acc[mt][nt], 0, 0, 0);
        }
    }

    if (mode == 0) {
        float* out = (float*)outv;
#pragma unroll
        for (int mt = 0; mt < 4; ++mt)
#pragma unroll
            for (int nt = 0; nt < 2; ++nt)
#pragma unroll
                for (int r = 0; r < 4; ++r) {
                    int m = m0 + mh + mt * 16 + quad * 4 + r;
                    int n = n0 + nh + nt * 16 + ln;
                    out[(size_t)m * N + n] = acc[mt][nt][r] + bias[n];
                }
    } else {
#pragma unroll
        for (int mt = 0; mt < 4; ++mt)
#pragma unroll
            for (int nt = 0; nt < 2; ++nt) {
                int n = n0 + nh + nt * 16 + ln;
                int mb = m0 + mh + mt * 16 + quad * 4;
                int b = mb >> 11, s0 = mb & (SEQ - 1);
                int d = n & 63;
                if (n < DMODEL) {           // Q, pre-scaled incl. log2(e)
                    int h = n >> 6;
                    unsigned short* qp_ =
                        (unsigned short*)outv + ((size_t)(b * NH + h) * SEQ + s0) * DHEAD + d;
#pragma unroll
                    for (int r = 0; r < 4; ++r)
                        qp_[(size_t)r * DHEAD] = f2bf(acc[mt][nt][r] * 0.18033688f);
                } else {                    // V: row-major + transposed
                    int h = (n >> 6) - NH;
                    unsigned short* vp_ =
                        (unsigned short*)outv2 + ((size_t)(b * NH + h) * SEQ + s0) * DHEAD + d;
                    short4v tv;
#pragma unroll
                    for (int r = 0; r < 4; ++r) {
                        unsigned short bv = f2bf(acc[mt][nt][r]);
                        vp_[(size_t)r * DHEAD] = bv;
                        tv[r] = (short)bv;
                    }
                    *(short4v*)(vtout + ((size_t)(b * NH + h) * DHEAD + d) * SEQ + s0) = tv;
                }
            }
    }
}

// ---------------------------------------------------------------------------
// Compensated K projection: 512 thr, 64x128 tile, reg-prefetch dbuf.
// ---------------------------------------------------------------------------
__global__ __launch_bounds__(512)
void gemm_kproj_mfma(const unsigned short* __restrict__ xh,
                     const unsigned short* __restrict__ xl,
                     const unsigned short* __restrict__ Wh,
                     const unsigned short* __restrict__ Wl,
                     unsigned short* __restrict__ kout,
                     float* __restrict__ norms2)
{
    __shared__ __align__(16) unsigned short Ah[64][72];
    __shared__ __align__(16) unsigned short Al[64][72];
    __shared__ __align__(16) unsigned short Bh[128][72];
    __shared__ __align__(16) unsigned short Bl[128][72];
    const int K = DMODEL;
    const int tid = threadIdx.x;
    const int lane = tid & 63, wave = tid >> 6;
    const int quad = lane >> 4, ln = lane & 15;
    const int mh = (wave >> 1) << 4;
    const int nh = (wave & 1) << 6;
    const int m0 = blockIdx.y * 64, n0 = blockIdx.x * 128;

    f32x4 acc[4];
#pragma unroll
    for (int j = 0; j < 4; ++j) acc[j] = (f32x4){0.f, 0.f, 0.f, 0.f};

    const int arow = tid >> 3, acol8 = (tid & 7) << 3;
    short8 ahreg, alreg, bhreg[2], blreg[2];
    {
        size_t ga = (size_t)(m0 + arow) * K + acol8;
        ahreg = *(const short8*)(xh + ga);
        alreg = *(const short8*)(xl + ga);
#pragma unroll
        for (int p = 0; p < 2; ++p) {
            int c = tid + (p << 9);
            int row = c >> 3, col8 = (c & 7) << 3;
            size_t gb = (size_t)(n0 + row) * K + col8;
            bhreg[p] = *(const short8*)(Wh + gb);
            blreg[p] = *(const short8*)(Wl + gb);
        }
    }

    for (int k0 = 0; k0 < K; k0 += 64) {
        __syncthreads();
        *(short8*)&Ah[arow][acol8] = ahreg;
        *(short8*)&Al[arow][acol8] = alreg;
#pragma unroll
        for (int p = 0; p < 2; ++p) {
            int c = tid + (p << 9);
            int row = c >> 3, col8 = (c & 7) << 3;
            *(short8*)&Bh[row][col8] = bhreg[p];
            *(short8*)&Bl[row][col8] = blreg[p];
        }
        __syncthreads();
        if (k0 + 64 < K) {
            size_t ga = (size_t)(m0 + arow) * K + k0 + 64 + acol8;
            ahreg = *(const short8*)(xh + ga);
            alreg = *(const short8*)(xl + ga);
#pragma unroll
            for (int p = 0; p < 2; ++p) {
                int c = tid + (p << 9);
                int row = c >> 3, col8 = (c & 7) << 3;
                size_t gb = (size_t)(n0 + row) * K + k0 + 64 + col8;
                bhreg[p] = *(const short8*)(Wh + gb);
                blreg[p] = *(const short8*)(Wl + gb);
            }
        }
#pragma unroll
        for (int ch = 0; ch < 2; ++ch) {
            short8 bh4[4], bl4[4];
#pragma unroll
            for (int nt = 0; nt < 4; ++nt) {
                bh4[nt] = *(const short8*)&Bh[nh + nt * 16 + ln][ch * 32 + quad * 8];
                bl4[nt] = *(const short8*)&Bl[nh + nt * 16 + ln][ch * 32 + quad * 8];
            }
            short8 ah = *(const short8*)&Ah[mh + ln][ch * 32 + quad * 8];
            short8 al = *(const short8*)&Al[mh + ln][ch * 32 + quad * 8];
#pragma unroll
            for (int nt = 0; nt < 4; ++nt) {
                acc[nt] = __builtin_amdgcn_mfma_f32_16x16x32_bf16(ah, bh4[nt], acc[nt], 0, 0, 0);
                acc[nt] = __builtin_amdgcn_mfma_f32_16x16x32_bf16(ah, bl4[nt], acc[nt], 0, 0, 0);
                acc[nt] = __builtin_amdgcn_mfma_f32_16x16x32_bf16(al, bh4[nt], acc[nt], 0, 0, 0);
            }
        }
    }

    const int h = (n0 + nh) >> 6;
#pragma unroll
    for (int r = 0; r < 4; ++r) {
        int m = m0 + mh + quad * 4 + r;
        int b = m >> 11, s = m & (SEQ - 1);
        size_t rowbase = ((size_t)(b * NH + h) * SEQ + s) * DHEAD;
#pragma unroll
        for (int nt = 0; nt < 4; ++nt)
            kout[rowbase + nt * 16 + ln] = f2bf(acc[nt][r]);
        float s2 = acc[0][r] * acc[0][r] + acc[1][r] * acc[1][r] +
                   acc[2][r] * acc[2][r] + acc[3][r] * acc[3][r];
#pragma unroll
        for (int off = 1; off <= 8; off <<= 1)
            s2 += __shfl_xor(s2, off);
        if (ln == 0)
            norms2[(size_t)(b * NH + h) * SEQ + s] = s2;
    }
}

// ---------------------------------------------------------------------------
// topk + gather fused, 512 threads.
// ---------------------------------------------------------------------------
__global__ __launch_bounds__(512)
void topk_gather_k(const float* __restrict__ norms2,
                   const unsigned short* __restrict__ k,
                   const unsigned short* __restrict__ v,
                   unsigned short* __restrict__ gk,
                   unsigned short* __restrict__ gvt)
{
    __shared__ unsigned long long keys[SEQ];
    __shared__ int tix[NGPAD];
    __shared__ __align__(16) unsigned short T[64][72];
    const int bh = blockIdx.x;
    const int tid = threadIdx.x;
    const float* nb = norms2 + (size_t)bh * SEQ;
    const size_t base = (size_t)bh * SEQ * DHEAD;

    for (int i = tid; i < SEQ; i += 512) {
        float nrm = sqrtf(nb[i]);
        keys[i] = ((unsigned long long)__float_as_uint(nrm) << 32) |
                  (unsigned int)(0xFFFFFFFFu - (unsigned int)i);
    }
    __syncthreads();
    for (int kk = 2; kk <= SEQ; kk <<= 1) {
        for (int j = kk >> 1; j > 0; j >>= 1) {
            for (int i = tid; i < SEQ; i += 512) {
                int ixj = i ^ j;
                if (ixj > i) {
                    unsigned long long a = keys[i], b = keys[ixj];
                    bool up = ((i & kk) == 0);
                    if ((a > b) == up) { keys[i] = b; keys[ixj] = a; }
                }
            }
            __syncthreads();
        }
    }
    if (tid < NGPAD) {
        tix[tid] = (tid < NG)
            ? (int)(0xFFFFFFFFu - (unsigned int)(keys[SEQ - 1 - tid] & 0xFFFFFFFFu))
            : 0;
    }
    __syncthreads();

    for (int t = 0; t < NGPAD / 64; ++t) {
        {
            int idx = tid;
            int row = idx >> 3, col8 = (idx & 7) << 3;
            int g = t * 64 + row;
            short8 kv = (short8)0, vv = (short8)0;
            if (g < NG) {
                int sidx = tix[g];
                kv = *(const short8*)(k + base + (size_t)sidx * DHEAD + col8);
                vv = *(const short8*)(v + base + (size_t)sidx * DHEAD + col8);
            }
            *(short8*)(gk + ((size_t)bh * NGPAD + g) * DHEAD + col8) = kv;
            *(short8*)&T[row][col8] = vv;
        }
        __syncthreads();
        {
            int idx = tid;
            int d = idx >> 3, k8 = (idx & 7) << 3;
            short8 o;
#pragma unroll
            for (int i = 0; i < 8; ++i) o[i] = (short)T[k8 + i][d];
            *(short8*)(gvt + ((size_t)bh * DHEAD + d) * NGPAD + t * 64 + k8) = o;
        }
        __syncthreads();
    }
}

// ---------------------------------------------------------------------------
// Fused attention r15: 256 thr, 4 waves x 32 q-rows, swapped QK^T, P in
// registers; K staged from phi-permuted global rows so the P output packs
// directly into mfma_16x16x32 A-frags (PV full rate); K/V double-buffered,
// one barrier per tile; exp via raw v_exp_f32.
// ---------------------------------------------------------------------------
__global__ __launch_bounds__(256, 2)
void attn_fused_k(const unsigned short* __restrict__ qb,
                  const unsigned short* __restrict__ kb,
                  const unsigned short* __restrict__ vt,
                  const unsigned short* __restrict__ gk,
                  const unsigned short* __restrict__ gvt,
                  const unsigned short* __restrict__ Wgt,
                  const float* __restrict__ gamma,
                  const float* __restrict__ beta,
                  const float* __restrict__ bg,
                  unsigned short* __restrict__ fused)
{
    // smem layout (shorts): [0,9216) Ks[2][64][72]  (= Ps[128][72] alias)
    //                       [9216,18432) Vt[2][64][72]
    //                       [18432,27136) Wgs[64][136]
    __shared__ __align__(16) unsigned short smem[27136];
    unsigned short* const KsB = smem;
    unsigned short* const VtB = smem + 9216;
    unsigned short (*Ps)[72]  = (unsigned short (*)[72])smem;
    unsigned short (*Wgs)[136] = (unsigned short (*)[136])(smem + 18432);

    const int flat = blockIdx.x;
    const int bh = ((flat >> 7) << 3) | (flat & 7);   // flat%8 == bh%8 (XCD)
    const int q0 = ((flat >> 3) & 15) * 128;
    const int tid = threadIdx.x;
    const int lane = tid & 63, wave = tid >> 6;       // 4 waves
    const int quad = lane >> 4, ln = lane & 15;
    const size_t base = (size_t)bh * SEQ * DHEAD;
    const unsigned short* gkb = gk + (size_t)bh * NGPAD * DHEAD;
    const unsigned short* gvb = gvt + (size_t)bh * DHEAD * NGPAD;

    // stage Wg^T (read only in epilogue; first barrier covers it)
#pragma unroll
    for (int p = 0; p < 4; ++p) {
        int idx = tid + (p << 8);
        *(short8*)&Wgs[idx >> 4][(idx & 15) << 3] = *(const short8*)(Wgt + idx * 8);
    }

    short8 qf[2][2];
#pragma unroll
    for (int mt = 0; mt < 2; ++mt) {
        const unsigned short* qp = qb + base + (size_t)(q0 + wave * 32 + mt * 16 + ln) * DHEAD;
        qf[mt][0] = *(const short8*)(qp + quad * 8);
        qf[mt][1] = *(const short8*)(qp + 32 + quad * 8);
    }

    f32x4 O[2][4], Og[2][4];
#pragma unroll
    for (int mt = 0; mt < 2; ++mt)
#pragma unroll
        for (int nt = 0; nt < 4; ++nt) {
            O[mt][nt] = (f32x4){0.f, 0.f, 0.f, 0.f};
            Og[mt][nt] = (f32x4){0.f, 0.f, 0.f, 0.f};
        }
    float ls[2] = {0.f, 0.f}, lg[2] = {0.f, 0.f};

    short8 kreg[2], vreg[2];
    int srow[2], scol8[2], psrow[2];
#pragma unroll
    for (int p = 0; p < 2; ++p) {
        int idx = tid + (p << 8);
        srow[p] = idx >> 3;
        scol8[p] = (idx & 7) << 3;
        // phi: [b5 | b3 b2 | b4 | b1 b0]  (K-row permutation, verified r14)
        psrow[p] = (srow[p] & 0x20) | ((srow[p] & 0x0C) << 1) |
                   ((srow[p] & 0x10) >> 2) | (srow[p] & 3);
    }

    auto loadT = [&](int i) {
#pragma unroll
        for (int p = 0; p < 2; ++p) {
            if (i < 32) {
                kreg[p] = *(const short8*)(kb + base + (size_t)(i * 64 + psrow[p]) * DHEAD + scol8[p]);
                vreg[p] = *(const short8*)(vt + base + (size_t)srow[p] * SEQ + i * 64 + scol8[p]);
            } else {
                int g = i - 32;
                kreg[p] = *(const short8*)(gkb + (size_t)(g * 64 + psrow[p]) * DHEAD + scol8[p]);
                vreg[p] = *(const short8*)(gvb + (size_t)srow[p] * NGPAD + g * 64 + scol8[p]);
            }
        }
    };
    auto storeT = [&](int buf) {
        unsigned short* kd = KsB + buf * 4608;
        unsigned short* vd = VtB + buf * 4608;
#pragma unroll
        for (int p = 0; p < 2; ++p) {
            *(short8*)&kd[srow[p] * 72 + scol8[p]] = kreg[p];
            *(short8*)&vd[srow[p] * 72 + scol8[p]] = vreg[p];
        }
    };

    loadT(0);
    storeT(0);
    loadT(1);
    __syncthreads();

    // ---- local: 32 tiles ----
    for (int t = 0; t < 32; ++t) {
        const int cur = t & 1;
        const unsigned short* Kc = KsB + cur * 4608;
        const unsigned short* Vc = VtB + cur * 4608;

        // swapped QK^T: lane holds S^T[k_phys = phi(nt*16+quad*4+r)][q=ln]
        f32x4 s[2][4];
#pragma unroll
        for (int mt = 0; mt < 2; ++mt)
#pragma unroll
            for (int nt = 0; nt < 4; ++nt) s[mt][nt] = (f32x4){0.f, 0.f, 0.f, 0.f};
        __builtin_amdgcn_s_setprio(1);
#pragma unroll
        for (int nt = 0; nt < 4; ++nt) {
            short8 kf0 = *(const short8*)&Kc[(nt * 16 + ln) * 72 + quad * 8];
            short8 kf1 = *(const short8*)&Kc[(nt * 16 + ln) * 72 + 32 + quad * 8];
#pragma unroll
            for (int mt = 0; mt < 2; ++mt) {
                s[mt][nt] = __builtin_amdgcn_mfma_f32_16x16x32_bf16(kf0, qf[mt][0], s[mt][nt], 0, 0, 0);
                s[mt][nt] = __builtin_amdgcn_mfma_f32_16x16x32_bf16(kf1, qf[mt][1], s[mt][nt], 0, 0, 0);
            }
        }
        __builtin_amdgcn_s_setprio(0);

        // exp + pack into mfma32 A-frags: pf8[mt][c] = k_phys c*32+quad*8+[0..7]
        short8 pf8[2][2];
#pragma unroll
        for (int mt = 0; mt < 2; ++mt)
#pragma unroll
            for (int nt = 0; nt < 4; ++nt)
#pragma unroll
                for (int r = 0; r < 4; ++r) {
                    unsigned int u = __float_as_uint(__builtin_amdgcn_exp2f(s[mt][nt][r]));
                    ls[mt] += __uint_as_float(u & 0xFFFF0000u);   // matched bf16 trunc
                    pf8[mt][nt >> 1][((nt & 1) << 2) | r] = (short)(u >> 16);
                }

        // PV: full-rate mfma32, P from registers
        __builtin_amdgcn_s_setprio(1);
#pragma unroll
        for (int dt = 0; dt < 4; ++dt)
#pragma unroll
            for (int c = 0; c < 2; ++c) {
                short8 vf = *(const short8*)&Vc[(dt * 16 + ln) * 72 + c * 32 + quad * 8];
#pragma unroll
                for (int mt = 0; mt < 2; ++mt)
                    O[mt][dt] = __builtin_amdgcn_mfma_f32_16x16x32_bf16(
                        pf8[mt][c], vf, O[mt][dt], 0, 0, 0);
            }
        __builtin_amdgcn_s_setprio(0);

        storeT(cur ^ 1);            // tile t+1 -> other buffer
        if (t + 2 <= 35) loadT(t + 2);
        __syncthreads();
    }

    // ---- global: 4 gathered tiles ----
    for (int tg = 0; tg < 4; ++tg) {
        const int t = 32 + tg;
        const int cur = t & 1;
        const unsigned short* Kc = KsB + cur * 4608;
        const unsigned short* Vc = VtB + cur * 4608;

        f32x4 s[2][4];
#pragma unroll
        for (int mt = 0; mt < 2; ++mt)
#pragma unroll
            for (int nt = 0; nt < 4; ++nt) s[mt][nt] = (f32x4){0.f, 0.f, 0.f, 0.f};
        __builtin_amdgcn_s_setprio(1);
#pragma unroll
        for (int nt = 0; nt < 4; ++nt) {
            short8 kf0 = *(const short8*)&Kc[(nt * 16 + ln) * 72 + quad * 8];
            short8 kf1 = *(const short8*)&Kc[(nt * 16 + ln) * 72 + 32 + quad * 8];
#pragma unroll
            for (int mt = 0; mt < 2; ++mt) {
                s[mt][nt] = __builtin_amdgcn_mfma_f32_16x16x32_bf16(kf0, qf[mt][0], s[mt][nt], 0, 0, 0);
                s[mt][nt] = __builtin_amdgcn_mfma_f32_16x16x32_bf16(kf1, qf[mt][1], s[mt][nt], 0, 0, 0);
            }
        }
        __builtin_amdgcn_s_setprio(0);

        short8 pf8[2][2];
#pragma unroll
        for (int nt = 0; nt < 4; ++nt)
#pragma unroll
            for (int r = 0; r < 4; ++r) {
                int phi = ((nt >> 1) << 5) | (quad << 3) | ((nt & 1) << 2) | r;
                bool valid = (tg * 64 + phi) < NG;
#pragma unroll
                for (int mt = 0; mt < 2; ++mt) {
                    float p = valid ? __builtin_amdgcn_exp2f(s[mt][nt][r]) : 0.f;
                    unsigned int u = __float_as_uint(p);
                    lg[mt] += __uint_as_float(u & 0xFFFF0000u);
                    pf8[mt][nt >> 1][((nt & 1) << 2) | r] = (short)(u >> 16);
                }
            }

        __builtin_amdgcn_s_setprio(1);
#pragma unroll
        for (int dt = 0; dt < 4; ++dt)
#pragma unroll
            for (int c = 0; c < 2; ++c) {
                short8 vf = *(const short8*)&Vc[(dt * 16 + ln) * 72 + c * 32 + quad * 8];
#pragma unroll
                for (int mt = 0; mt < 2; ++mt)
                    Og[mt][dt] = __builtin_amdgcn_mfma_f32_16x16x32_bf16(
                        pf8[mt][c], vf, Og[mt][dt], 0, 0, 0);
            }
        __builtin_amdgcn_s_setprio(0);

        if (t < 35) storeT(cur ^ 1);
        if (t + 2 <= 35) loadT(t + 2);
        __syncthreads();            // last iter: protects Ps alias in epilogue
    }

    // ---- reductions: ls/lg are per-q (q=..+ln) partials over (quad,r) ----
#pragma unroll
    for (int mt = 0; mt < 2; ++mt) {
        ls[mt] += __shfl_xor(ls[mt], 16);
        ls[mt] += __shfl_xor(ls[mt], 32);
        lg[mt] += __shfl_xor(lg[mt], 16);
        lg[mt] += __shfl_xor(lg[mt], 32);
    }
    // redistribute to O layout (q = quad*4+r): fetch from lane quad*4+r
    float invl[2][4], invg[2][4];
#pragma unroll
    for (int mt = 0; mt < 2; ++mt)
#pragma unroll
        for (int r = 0; r < 4; ++r) {
            invl[mt][r] = 1.f / __shfl(ls[mt], quad * 4 + r);
            invg[mt][r] = 1.f / __shfl(lg[mt], quad * 4 + r);
        }

    // ---- layernorm(global) ----
    float xs[2][4][4];
#pragma unroll
    for (int mt = 0; mt < 2; ++mt)
#pragma unroll
        for (int r = 0; r < 4; ++r) {
            float inv = invg[mt][r];
#pragma unroll
            for (int nt = 0; nt < 4; ++nt) xs[mt][nt][r] = Og[mt][nt][r] * inv;
        }
    float mu[2][4], rsd[2][4];
#pragma unroll
    for (int mt = 0; mt < 2; ++mt)
#pragma unroll
        for (int r = 0; r < 4; ++r) {
            float sm = xs[mt][0][r] + xs[mt][1][r] + xs[mt][2][r] + xs[mt][3][r];
#pragma unroll
            for (int off = 1; off <= 8; off <<= 1) sm += __shfl_xor(sm, off);
            mu[mt][r] = sm * (1.f / 64.f);
        }
#pragma unroll
    for (int mt = 0; mt < 2; ++mt)
#pragma unroll
        for (int r = 0; r < 4; ++r) {
            float sv = 0.f;
#pragma unroll
            for (int nt = 0; nt < 4; ++nt) {
                float d = xs[mt][nt][r] - mu[mt][r];
                sv += d * d;
            }
#pragma unroll
            for (int off = 1; off <= 8; off <<= 1) sv += __shfl_xor(sv, off);
            rsd[mt][r] = rsqrtf(sv * (1.f / 64.f) + LNEPS);
        }
#pragma unroll
    for (int nt = 0; nt < 4; ++nt) {
        float g = gamma[nt * 16 + ln], bb = beta[nt * 16 + ln];
#pragma unroll
        for (int mt = 0; mt < 2; ++mt)
#pragma unroll
            for (int r = 0; r < 4; ++r)
                xs[mt][nt][r] = (xs[mt][nt][r] - mu[mt][r]) * rsd[mt][r] * g + bb;
    }

    // ---- gate via MFMA (2 passes through Ps; intra-wave rows, no barrier) --
    float lf[2][4][4];
#pragma unroll
    for (int mt = 0; mt < 2; ++mt)
#pragma unroll
        for (int nt = 0; nt < 4; ++nt)
#pragma unroll
            for (int r = 0; r < 4; ++r) {
                lf[mt][nt][r] = O[mt][nt][r] * invl[mt][r];
                Ps[wave * 32 + mt * 16 + quad * 4 + r][nt * 16 + ln] = f2bf(lf[mt][nt][r]);
            }
    f32x4 gacc[2][4];
#pragma unroll
    for (int ng = 0; ng < 4; ++ng) {
        float bgv = bg[ng * 16 + ln];
#pragma unroll
        for (int mt = 0; mt < 2; ++mt)
            gacc[mt][ng] = (f32x4){bgv, bgv, bgv, bgv};
    }
#pragma unroll
    for (int ch = 0; ch < 2; ++ch) {
        short8 af[2];
#pragma unroll
        for (int mt = 0; mt < 2; ++mt)
            af[mt] = *(const short8*)&Ps[wave * 32 + mt * 16 + ln][ch * 32 + quad * 8];
#pragma unroll
        for (int ng = 0; ng < 4; ++ng) {
            short8 bf = *(const short8*)&Wgs[ng * 16 + ln][ch * 32 + quad * 8];
#pragma unroll
            for (int mt = 0; mt < 2; ++mt)
                gacc[mt][ng] = __builtin_amdgcn_mfma_f32_16x16x32_bf16(af[mt], bf, gacc[mt][ng], 0, 0, 0);
        }
    }
#pragma unroll
    for (int mt = 0; mt < 2; ++mt)
#pragma unroll
        for (int nt = 0; nt < 4; ++nt)
#pragma unroll
            for (int r = 0; r < 4; ++r)
                Ps[wave * 32 + mt * 16 + quad * 4 + r][nt * 16 + ln] = f2bf(xs[mt][nt][r]);
#pragma unroll
    for (int ch = 0; ch < 2; ++ch) {
        short8 af[2];
#pragma unroll
        for (int mt = 0; mt < 2; ++mt)
            af[mt] = *(const short8*)&Ps[wave * 32 + mt * 16 + ln][ch * 32 + quad * 8];
#pragma unroll
        for (int ng = 0; ng < 4; ++ng) {
            short8 bf = *(const short8*)&Wgs[ng * 16 + ln][64 + ch * 32 + quad * 8];
#pragma unroll
            for (int mt = 0; mt < 2; ++mt)
                gacc[mt][ng] = __builtin_amdgcn_mfma_f32_16x16x32_bf16(af[mt], bf, gacc[mt][ng], 0, 0, 0);
        }
    }

    // ---- fuse + store ----
    const int b = bh >> 4, h = bh & 15;
#pragma unroll
    for (int mt = 0; mt < 2; ++mt)
#pragma unroll
        for (int ng = 0; ng < 4; ++ng)
#pragma unroll
            for (int r = 0; r < 4; ++r) {
                float gt = 1.f / (1.f + __expf(-gacc[mt][ng][r]));
                float f = gt * lf[mt][ng][r] + (1.f - gt) * xs[mt][ng][r];
                int s = q0 + wave * 32 + mt * 16 + quad * 4 + r;
                fused[((size_t)(b * SEQ + s)) * DMODEL + h * DHEAD + ng * 16 + ln] = f2bf(f);
            }
}

// ---------------------------------------------------------------------------
extern "C" void kernel_launch(void* const* d_in, const int* in_sizes, int n_in,
                              void* d_out, int out_size, void* d_ws, size_t ws_size,
                              hipStream_t stream)
{
    (void)in_sizes; (void)n_in; (void)out_size; (void)ws_size;
    const float* x    = (const float*)d_in[0];
    const float* Wq   = (const float*)d_in[1];
    const float* Wk   = (const float*)d_in[2];
    const float* Wv   = (const float*)d_in[3];
    const float* Wo   = (const float*)d_in[4];
    const float* bo   = (const float*)d_in[5];
    const float* ln_g = (const float*)d_in[6];
    const float* ln_b = (const float*)d_in[7];
    const float* Wg   = (const float*)d_in[8];
    const float* bg   = (const float*)d_in[9];

    char* w = (char*)d_ws;
    const size_t MB = 1024ull * 1024ull;
    unsigned short* kb16  = (unsigned short*)(w);
    unsigned short* qb16  = (unsigned short*)(w + 8 * MB);
    unsigned short* vb16  = (unsigned short*)(w + 16 * MB);
    unsigned short* vt16  = (unsigned short*)(w + 24 * MB);
    unsigned short* xh    = (unsigned short*)(w + 32 * MB);
    unsigned short* xl    = (unsigned short*)(w + 40 * MB);
    unsigned short* Wqt   = (unsigned short*)(w + 48 * MB);
    unsigned short* Wvt   = (unsigned short*)(w + 50 * MB);   // contiguous after Wqt
    unsigned short* Wot   = (unsigned short*)(w + 52 * MB);
    unsigned short* Wkh   = (unsigned short*)(w + 54 * MB);
    unsigned short* Wkl   = (unsigned short*)(w + 56 * MB);
    unsigned short* Wgt   = (unsigned short*)(w + 58 * MB);
    float*          norms2= (float*)(w + 59 * MB);
    unsigned short* gk16  = (unsigned short*)(w + 60 * MB);
    unsigned short* gvt16 = (unsigned short*)(w + 61 * MB);
    unsigned short* fusedb = xh;   // xh dead after projections

    const int M = 4096, N = 1024, K = 1024;

    prep_k<<<3073, 256, 0, stream>>>(x, Wq, Wv, Wo, Wk, Wg,
                                     xh, xl, Wqt, Wvt, Wot, Wkh, Wkl, Wgt);

    dim3 gqv(2048 / 128, M / 128);
    gemm_bf16_k<<<gqv, 512, 0, stream>>>(xh, Wqt, nullptr, qb16, vb16, vt16,
                                         M, 2048, K, 3);

    dim3 gkp(N / 128, M / 64);
    gemm_kproj_mfma<<<gkp, 512, 0, stream>>>(xh, xl, Wkh, Wkl, kb16, norms2);

    topk_gather_k<<<BHT, 512, 0, stream>>>(norms2, kb16, vb16, gk16, gvt16);

    attn_fused_k<<<512, 256, 0, stream>>>(qb16, kb16, vt16, gk16, gvt16, Wgt,
                                          ln_g, ln_b, bg, fusedb);

    dim3 go_(N / 128, M / 128);
    gemm_bf16_k<<<go_, 512, 0, stream>>>(fusedb, Wot, bo, (float*)d_out, nullptr,
                                         nullptr, M, N, K, 0);
}

// Round 7
// 265.223 us; speedup vs baseline: 1.4973x; 1.0097x over previous
//
#include <hip/hip_runtime.h>

// SegmentedAttention round 16 = r15 attn (59us, verified) + kproj rewrite.
// r15 budget: attn 59us of 268 total -> 78% is the other 5 kernels. kproj
// (compensated 3x-MFMA K projection) had M_rep=1: 20 LDS b128 reads per 24
// mfma per wave-kstep (ratio 1.2) -> hard LDS-bound. r16: 128x128 tile,
// waves 4x2, M_rep=2/N_rep=4, nt-inner frag loop: 12 reads / 24 mfma per
// ch (ratio 2.0, 1.67x less LDS read traffic per output). LDS 73728B,
// grid 256. No launch_bounds cap (r14 lesson). Epilogue math identical.
// ws (MB): kb16@0(8) qb16@8(8) vb16@16(8) vt16@24(8) xh@32(8,=fusedb)
//   xl@40(8) Wqt@48(2) Wvt@50(2) Wot@52(2) Wkh@54(2) Wkl@56(2) Wgt@58(1)
//   norms2@59(1) gk@60(1) gvt@61(1) -> 62MB

constexpr int SEQ    = 2048;
constexpr int DMODEL = 1024;
constexpr int NH     = 16;
constexpr int DHEAD  = 64;
constexpr int BHT    = 32;
constexpr int NG     = 204;
constexpr int NGPAD  = 256;
constexpr float LNEPS = 1e-5f;

typedef __attribute__((ext_vector_type(8))) short short8;
typedef __attribute__((ext_vector_type(4))) short short4v;
typedef __attribute__((ext_vector_type(4))) float f32x4;

__device__ __forceinline__ unsigned short f2bf(float f) {
    unsigned int u = __float_as_uint(f);
    u += 0x7FFFu + ((u >> 16) & 1u);
    return (unsigned short)(u >> 16);
}
__device__ __forceinline__ float bf2f(unsigned short b) {
    return __uint_as_float(((unsigned int)b) << 16);
}

// ---------------------------------------------------------------------------
// prep: blocks [0,2048): x hilo split; [2048,3072): weight transposes;
// block 3072: Wg^T bf16.
// ---------------------------------------------------------------------------
__global__ __launch_bounds__(256)
void prep_k(const float* __restrict__ x,
            const float* __restrict__ Wq, const float* __restrict__ Wv,
            const float* __restrict__ Wo, const float* __restrict__ Wk,
            const float* __restrict__ Wg,
            unsigned short* __restrict__ xh, unsigned short* __restrict__ xl,
            unsigned short* __restrict__ Wqt, unsigned short* __restrict__ Wvt,
            unsigned short* __restrict__ Wot, unsigned short* __restrict__ Wkh,
            unsigned short* __restrict__ Wkl, unsigned short* __restrict__ Wgt)
{
    const int bid = blockIdx.x;
    const int tid = threadIdx.x;

    if (bid < 2048) {
        int i = (bid * 256 + tid) << 3;
        short8 h, l;
#pragma unroll
        for (int j = 0; j < 8; ++j) {
            float v = x[i + j];
            unsigned short hb = f2bf(v);
            h[j] = (short)hb;
            l[j] = (short)f2bf(v - bf2f(hb));
        }
        *(short8*)(xh + i) = h;
        *(short8*)(xl + i) = l;
        return;
    }
    if (bid == 3072) {
#pragma unroll
        for (int i = 0; i < 32; ++i) {
            int o = tid * 32 + i;
            int dg = o >> 7, jj = o & 127;
            Wgt[o] = f2bf(Wg[jj * 64 + dg]);
        }
        return;
    }

    __shared__ float tile[64][68];
    const int sub = bid - 2048;
    const int which = sub >> 8;             // 0:Wq 1:Wv 2:Wo 3:Wk
    const int b = sub & 255;
    const int n0 = (b & 15) * 64, k0 = (b >> 4) * 64;
    const float* W = (which == 0) ? Wq : (which == 1) ? Wv : (which == 2) ? Wo : Wk;
    const int Kd = DMODEL, Nd = DMODEL;

#pragma unroll
    for (int p = 0; p < 4; ++p) {
        int c = tid + (p << 8);
        int r = c >> 4, c4 = (c & 15) << 2;
        *(float4*)&tile[r][c4] = *(const float4*)(W + (size_t)(k0 + r) * Nd + n0 + c4);
    }
    __syncthreads();
#pragma unroll
    for (int p = 0; p < 4; ++p) {
        int c = tid + (p << 8);
        int n = c >> 4, k4 = (c & 15) << 2;
        if (which < 3) {
            unsigned short* Wt = (which == 0) ? Wqt : (which == 1) ? Wvt : Wot;
            short4v o;
#pragma unroll
            for (int j = 0; j < 4; ++j) o[j] = (short)f2bf(tile[k4 + j][n]);
            *(short4v*)(Wt + (size_t)(n0 + n) * Kd + k0 + k4) = o;
        } else {
            short4v oh, ol;
#pragma unroll
            for (int j = 0; j < 4; ++j) {
                float v = tile[k4 + j][n];
                unsigned short hb = f2bf(v);
                oh[j] = (short)hb;
                ol[j] = (short)f2bf(v - bf2f(hb));
            }
            *(short4v*)(Wkh + (size_t)(n0 + n) * Kd + k0 + k4) = oh;
            *(short4v*)(Wkl + (size_t)(n0 + n) * Kd + k0 + k4) = ol;
        }
    }
}

// ---------------------------------------------------------------------------
// bf16 MFMA GEMM, 512 thr, 128x128 tile, 8 waves 2x4, reg-prefetch dbuf.
// mode 0: fp32 out = acc + bias.
// mode 3: Q|V: n<1024 -> qb (acc*0.125*log2e, exp2-folded); n>=1024 -> vb
//         AND vt (transposed).
// ---------------------------------------------------------------------------
__global__ __launch_bounds__(512)
void gemm_bf16_k(const unsigned short* __restrict__ A,
                 const unsigned short* __restrict__ Bt,
                 const float* __restrict__ bias,
                 void* __restrict__ outv, void* __restrict__ outv2,
                 unsigned short* __restrict__ vtout,
                 int M, int N, int K, int mode)
{
    __shared__ __align__(16) unsigned short As[128][72];
    __shared__ __align__(16) unsigned short Bs[128][72];
    const int tid = threadIdx.x;
    const int lane = tid & 63, wave = tid >> 6;
    const int quad = lane >> 4, ln = lane & 15;
    const int mh = (wave >> 2) << 6;
    const int nh = (wave & 3) << 5;
    const int m0 = blockIdx.y * 128, n0 = blockIdx.x * 128;

    f32x4 acc[4][2];
#pragma unroll
    for (int i = 0; i < 4; ++i)
#pragma unroll
        for (int j = 0; j < 2; ++j) acc[i][j] = (f32x4){0.f, 0.f, 0.f, 0.f};

    short8 areg[2], breg[2];
#pragma unroll
    for (int p = 0; p < 2; ++p) {
        int c = tid + (p << 9);
        int row = c >> 3, col8 = (c & 7) << 3;
        areg[p] = *(const short8*)(A + (size_t)(m0 + row) * K + col8);
        breg[p] = *(const short8*)(Bt + (size_t)(n0 + row) * K + col8);
    }

    for (int k0 = 0; k0 < K; k0 += 64) {
        __syncthreads();
#pragma unroll
        for (int p = 0; p < 2; ++p) {
            int c = tid + (p << 9);
            int row = c >> 3, col8 = (c & 7) << 3;
            *(short8*)&As[row][col8] = areg[p];
            *(short8*)&Bs[row][col8] = breg[p];
        }
        __syncthreads();
        if (k0 + 64 < K) {
#pragma unroll
            for (int p = 0; p < 2; ++p) {
                int c = tid + (p << 9);
                int row = c >> 3, col8 = (c & 7) << 3;
                areg[p] = *(const short8*)(A + (size_t)(m0 + row) * K + k0 + 64 + col8);
                breg[p] = *(const short8*)(Bt + (size_t)(n0 + row) * K + k0 + 64 + col8);
            }
        }
#pragma unroll
        for (int ch = 0; ch < 2; ++ch) {
            short8 af[4], bf[2];
#pragma unroll
            for (int mt = 0; mt < 4; ++mt)
                af[mt] = *(const short8*)&As[mh + mt * 16 + ln][ch * 32 + quad * 8];
#pragma unroll
            for (int nt = 0; nt < 2; ++nt)
                bf[nt] = *(const short8*)&Bs[nh + nt * 16 + ln][ch * 32 + quad * 8];
#pragma unroll
            for (int mt = 0; mt < 4; ++mt)
#pragma unroll
                for (int nt = 0; nt < 2; ++nt)
                    acc[mt][nt] = __builtin_amdgcn_mfma_f32_16x16x32_bf16(
                        af[mt], bf[nt], acc[mt][nt], 0, 0, 0);
        }
    }

    if (mode == 0) {
        float* out = (float*)outv;
#pragma unroll
        for (int mt = 0; mt < 4; ++mt)
#pragma unroll
            for (int nt = 0; nt < 2; ++nt)
#pragma unroll
                for (int r = 0; r < 4; ++r) {
                    int m = m0 + mh + mt * 16 + quad * 4 + r;
                    int n = n0 + nh + nt * 16 + ln;
                    out[(size_t)m * N + n] = acc[mt][nt][r] + bias[n];
                }
    } else {
#pragma unroll
        for (int mt = 0; mt < 4; ++mt)
#pragma unroll
            for (int nt = 0; nt < 2; ++nt) {
                int n = n0 + nh + nt * 16 + ln;
                int mb = m0 + mh + mt * 16 + quad * 4;
                int b = mb >> 11, s0 = mb & (SEQ - 1);
                int d = n & 63;
                if (n < DMODEL) {           // Q, pre-scaled incl. log2(e)
                    int h = n >> 6;
                    unsigned short* qp_ =
                        (unsigned short*)outv + ((size_t)(b * NH + h) * SEQ + s0) * DHEAD + d;
#pragma unroll
                    for (int r = 0; r < 4; ++r)
                        qp_[(size_t)r * DHEAD] = f2bf(acc[mt][nt][r] * 0.18033688f);
                } else {                    // V: row-major + transposed
                    int h = (n >> 6) - NH;
                    unsigned short* vp_ =
                        (unsigned short*)outv2 + ((size_t)(b * NH + h) * SEQ + s0) * DHEAD + d;
                    short4v tv;
#pragma unroll
                    for (int r = 0; r < 4; ++r) {
                        unsigned short bv = f2bf(acc[mt][nt][r]);
                        vp_[(size_t)r * DHEAD] = bv;
                        tv[r] = (short)bv;
                    }
                    *(short4v*)(vtout + ((size_t)(b * NH + h) * DHEAD + d) * SEQ + s0) = tv;
                }
            }
    }
}

// ---------------------------------------------------------------------------
// Compensated K projection r16: 512 thr, 128x128 tile, waves 4x2,
// M_rep=2 / N_rep=4, nt-inner frags: 12 LDS reads / 24 mfma per ch.
// acc = ah*bh + ah*bl + al*bh (hi/lo compensation). Reg-prefetch dbuf.
// ---------------------------------------------------------------------------
__global__ __launch_bounds__(512)
void gemm_kproj_mfma(const unsigned short* __restrict__ xh,
                     const unsigned short* __restrict__ xl,
                     const unsigned short* __restrict__ Wh,
                     const unsigned short* __restrict__ Wl,
                     unsigned short* __restrict__ kout,
                     float* __restrict__ norms2)
{
    __shared__ __align__(16) unsigned short Ah[128][72];
    __shared__ __align__(16) unsigned short Al[128][72];
    __shared__ __align__(16) unsigned short Bh[128][72];
    __shared__ __align__(16) unsigned short Bl[128][72];
    const int K = DMODEL;
    const int tid = threadIdx.x;
    const int lane = tid & 63, wave = tid >> 6;
    const int quad = lane >> 4, ln = lane & 15;
    const int mh = (wave >> 1) << 5;      // 4 m-groups x 32 rows
    const int nh = (wave & 1) << 6;       // 2 n-groups x 64 cols
    const int m0 = blockIdx.y * 128, n0 = blockIdx.x * 128;

    f32x4 acc[2][4];
#pragma unroll
    for (int i = 0; i < 2; ++i)
#pragma unroll
        for (int j = 0; j < 4; ++j) acc[i][j] = (f32x4){0.f, 0.f, 0.f, 0.f};

    short8 ahreg[2], alreg[2], bhreg[2], blreg[2];
#pragma unroll
    for (int p = 0; p < 2; ++p) {
        int c = tid + (p << 9);
        int row = c >> 3, col8 = (c & 7) << 3;
        size_t ga = (size_t)(m0 + row) * K + col8;
        size_t gb = (size_t)(n0 + row) * K + col8;
        ahreg[p] = *(const short8*)(xh + ga);
        alreg[p] = *(const short8*)(xl + ga);
        bhreg[p] = *(const short8*)(Wh + gb);
        blreg[p] = *(const short8*)(Wl + gb);
    }

    for (int k0 = 0; k0 < K; k0 += 64) {
        __syncthreads();
#pragma unroll
        for (int p = 0; p < 2; ++p) {
            int c = tid + (p << 9);
            int row = c >> 3, col8 = (c & 7) << 3;
            *(short8*)&Ah[row][col8] = ahreg[p];
            *(short8*)&Al[row][col8] = alreg[p];
            *(short8*)&Bh[row][col8] = bhreg[p];
            *(short8*)&Bl[row][col8] = blreg[p];
        }
        __syncthreads();
        if (k0 + 64 < K) {
#pragma unroll
            for (int p = 0; p < 2; ++p) {
                int c = tid + (p << 9);
                int row = c >> 3, col8 = (c & 7) << 3;
                size_t ga = (size_t)(m0 + row) * K + k0 + 64 + col8;
                size_t gb = (size_t)(n0 + row) * K + k0 + 64 + col8;
                ahreg[p] = *(const short8*)(xh + ga);
                alreg[p] = *(const short8*)(xl + ga);
                bhreg[p] = *(const short8*)(Wh + gb);
                blreg[p] = *(const short8*)(Wl + gb);
            }
        }
#pragma unroll
        for (int ch = 0; ch < 2; ++ch) {
            short8 afh[2], afl[2];
#pragma unroll
            for (int mt = 0; mt < 2; ++mt) {
                afh[mt] = *(const short8*)&Ah[mh + mt * 16 + ln][ch * 32 + quad * 8];
                afl[mt] = *(const short8*)&Al[mh + mt * 16 + ln][ch * 32 + quad * 8];
            }
#pragma unroll
            for (int nt = 0; nt < 4; ++nt) {
                short8 bfh = *(const short8*)&Bh[nh + nt * 16 + ln][ch * 32 + quad * 8];
                short8 bfl = *(const short8*)&Bl[nh + nt * 16 + ln][ch * 32 + quad * 8];
#pragma unroll
                for (int mt = 0; mt < 2; ++mt) {
                    acc[mt][nt] = __builtin_amdgcn_mfma_f32_16x16x32_bf16(afh[mt], bfh, acc[mt][nt], 0, 0, 0);
                    acc[mt][nt] = __builtin_amdgcn_mfma_f32_16x16x32_bf16(afh[mt], bfl, acc[mt][nt], 0, 0, 0);
                    acc[mt][nt] = __builtin_amdgcn_mfma_f32_16x16x32_bf16(afl[mt], bfh, acc[mt][nt], 0, 0, 0);
                }
            }
        }
    }

    const int h = (n0 + nh) >> 6;
#pragma unroll
    for (int mt = 0; mt < 2; ++mt)
#pragma unroll
        for (int r = 0; r < 4; ++r) {
            int m = m0 + mh + mt * 16 + quad * 4 + r;
            int b = m >> 11, s = m & (SEQ - 1);
            size_t rowbase = ((size_t)(b * NH + h) * SEQ + s) * DHEAD;
#pragma unroll
            for (int nt = 0; nt < 4; ++nt)
                kout[rowbase + nt * 16 + ln] = f2bf(acc[mt][nt][r]);
            float s2 = acc[mt][0][r] * acc[mt][0][r] + acc[mt][1][r] * acc[mt][1][r] +
                       acc[mt][2][r] * acc[mt][2][r] + acc[mt][3][r] * acc[mt][3][r];
#pragma unroll
            for (int off = 1; off <= 8; off <<= 1)
                s2 += __shfl_xor(s2, off);
            if (ln == 0)
                norms2[(size_t)(b * NH + h) * SEQ + s] = s2;
        }
}

// ---------------------------------------------------------------------------
// topk + gather fused, 512 threads.
// ---------------------------------------------------------------------------
__global__ __launch_bounds__(512)
void topk_gather_k(const float* __restrict__ norms2,
                   const unsigned short* __restrict__ k,
                   const unsigned short* __restrict__ v,
                   unsigned short* __restrict__ gk,
                   unsigned short* __restrict__ gvt)
{
    __shared__ unsigned long long keys[SEQ];
    __shared__ int tix[NGPAD];
    __shared__ __align__(16) unsigned short T[64][72];
    const int bh = blockIdx.x;
    const int tid = threadIdx.x;
    const float* nb = norms2 + (size_t)bh * SEQ;
    const size_t base = (size_t)bh * SEQ * DHEAD;

    for (int i = tid; i < SEQ; i += 512) {
        float nrm = sqrtf(nb[i]);
        keys[i] = ((unsigned long long)__float_as_uint(nrm) << 32) |
                  (unsigned int)(0xFFFFFFFFu - (unsigned int)i);
    }
    __syncthreads();
    for (int kk = 2; kk <= SEQ; kk <<= 1) {
        for (int j = kk >> 1; j > 0; j >>= 1) {
            for (int i = tid; i < SEQ; i += 512) {
                int ixj = i ^ j;
                if (ixj > i) {
                    unsigned long long a = keys[i], b = keys[ixj];
                    bool up = ((i & kk) == 0);
                    if ((a > b) == up) { keys[i] = b; keys[ixj] = a; }
                }
            }
            __syncthreads();
        }
    }
    if (tid < NGPAD) {
        tix[tid] = (tid < NG)
            ? (int)(0xFFFFFFFFu - (unsigned int)(keys[SEQ - 1 - tid] & 0xFFFFFFFFu))
            : 0;
    }
    __syncthreads();

    for (int t = 0; t < NGPAD / 64; ++t) {
        {
            int idx = tid;
            int row = idx >> 3, col8 = (idx & 7) << 3;
            int g = t * 64 + row;
            short8 kv = (short8)0, vv = (short8)0;
            if (g < NG) {
                int sidx = tix[g];
                kv = *(const short8*)(k + base + (size_t)sidx * DHEAD + col8);
                vv = *(const short8*)(v + base + (size_t)sidx * DHEAD + col8);
            }
            *(short8*)(gk + ((size_t)bh * NGPAD + g) * DHEAD + col8) = kv;
            *(short8*)&T[row][col8] = vv;
        }
        __syncthreads();
        {
            int idx = tid;
            int d = idx >> 3, k8 = (idx & 7) << 3;
            short8 o;
#pragma unroll
            for (int i = 0; i < 8; ++i) o[i] = (short)T[k8 + i][d];
            *(short8*)(gvt + ((size_t)bh * DHEAD + d) * NGPAD + t * 64 + k8) = o;
        }
        __syncthreads();
    }
}

// ---------------------------------------------------------------------------
// Fused attention r15 (unchanged): 256 thr, 4 waves x 32 q-rows, swapped
// QK^T, P in registers as mfma32 A-frags via phi K-row permutation; K/V
// double-buffered, one barrier per tile; raw v_exp_f32.
// ---------------------------------------------------------------------------
__global__ __launch_bounds__(256, 2)
void attn_fused_k(const unsigned short* __restrict__ qb,
                  const unsigned short* __restrict__ kb,
                  const unsigned short* __restrict__ vt,
                  const unsigned short* __restrict__ gk,
                  const unsigned short* __restrict__ gvt,
                  const unsigned short* __restrict__ Wgt,
                  const float* __restrict__ gamma,
                  const float* __restrict__ beta,
                  const float* __restrict__ bg,
                  unsigned short* __restrict__ fused)
{
    // smem layout (shorts): [0,9216) Ks[2][64][72]  (= Ps[128][72] alias)
    //                       [9216,18432) Vt[2][64][72]
    //                       [18432,27136) Wgs[64][136]
    __shared__ __align__(16) unsigned short smem[27136];
    unsigned short* const KsB = smem;
    unsigned short* const VtB = smem + 9216;
    unsigned short (*Ps)[72]  = (unsigned short (*)[72])smem;
    unsigned short (*Wgs)[136] = (unsigned short (*)[136])(smem + 18432);

    const int flat = blockIdx.x;
    const int bh = ((flat >> 7) << 3) | (flat & 7);   // flat%8 == bh%8 (XCD)
    const int q0 = ((flat >> 3) & 15) * 128;
    const int tid = threadIdx.x;
    const int lane = tid & 63, wave = tid >> 6;       // 4 waves
    const int quad = lane >> 4, ln = lane & 15;
    const size_t base = (size_t)bh * SEQ * DHEAD;
    const unsigned short* gkb = gk + (size_t)bh * NGPAD * DHEAD;
    const unsigned short* gvb = gvt + (size_t)bh * DHEAD * NGPAD;

    // stage Wg^T (read only in epilogue; first barrier covers it)
#pragma unroll
    for (int p = 0; p < 4; ++p) {
        int idx = tid + (p << 8);
        *(short8*)&Wgs[idx >> 4][(idx & 15) << 3] = *(const short8*)(Wgt + idx * 8);
    }

    short8 qf[2][2];
#pragma unroll
    for (int mt = 0; mt < 2; ++mt) {
        const unsigned short* qp = qb + base + (size_t)(q0 + wave * 32 + mt * 16 + ln) * DHEAD;
        qf[mt][0] = *(const short8*)(qp + quad * 8);
        qf[mt][1] = *(const short8*)(qp + 32 + quad * 8);
    }

    f32x4 O[2][4], Og[2][4];
#pragma unroll
    for (int mt = 0; mt < 2; ++mt)
#pragma unroll
        for (int nt = 0; nt < 4; ++nt) {
            O[mt][nt] = (f32x4){0.f, 0.f, 0.f, 0.f};
            Og[mt][nt] = (f32x4){0.f, 0.f, 0.f, 0.f};
        }
    float ls[2] = {0.f, 0.f}, lg[2] = {0.f, 0.f};

    short8 kreg[2], vreg[2];
    int srow[2], scol8[2], psrow[2];
#pragma unroll
    for (int p = 0; p < 2; ++p) {
        int idx = tid + (p << 8);
        srow[p] = idx >> 3;
        scol8[p] = (idx & 7) << 3;
        // phi: [b5 | b3 b2 | b4 | b1 b0]  (K-row permutation, verified r14)
        psrow[p] = (srow[p] & 0x20) | ((srow[p] & 0x0C) << 1) |
                   ((srow[p] & 0x10) >> 2) | (srow[p] & 3);
    }

    auto loadT = [&](int i) {
#pragma unroll
        for (int p = 0; p < 2; ++p) {
            if (i < 32) {
                kreg[p] = *(const short8*)(kb + base + (size_t)(i * 64 + psrow[p]) * DHEAD + scol8[p]);
                vreg[p] = *(const short8*)(vt + base + (size_t)srow[p] * SEQ + i * 64 + scol8[p]);
            } else {
                int g = i - 32;
                kreg[p] = *(const short8*)(gkb + (size_t)(g * 64 + psrow[p]) * DHEAD + scol8[p]);
                vreg[p] = *(const short8*)(gvb + (size_t)srow[p] * NGPAD + g * 64 + scol8[p]);
            }
        }
    };
    auto storeT = [&](int buf) {
        unsigned short* kd = KsB + buf * 4608;
        unsigned short* vd = VtB + buf * 4608;
#pragma unroll
        for (int p = 0; p < 2; ++p) {
            *(short8*)&kd[srow[p] * 72 + scol8[p]] = kreg[p];
            *(short8*)&vd[srow[p] * 72 + scol8[p]] = vreg[p];
        }
    };

    loadT(0);
    storeT(0);
    loadT(1);
    __syncthreads();

    // ---- local: 32 tiles ----
    for (int t = 0; t < 32; ++t) {
        const int cur = t & 1;
        const unsigned short* Kc = KsB + cur * 4608;
        const unsigned short* Vc = VtB + cur * 4608;

        // swapped QK^T: lane holds S^T[k_phys = phi(nt*16+quad*4+r)][q=ln]
        f32x4 s[2][4];
#pragma unroll
        for (int mt = 0; mt < 2; ++mt)
#pragma unroll
            for (int nt = 0; nt < 4; ++nt) s[mt][nt] = (f32x4){0.f, 0.f, 0.f, 0.f};
        __builtin_amdgcn_s_setprio(1);
#pragma unroll
        for (int nt = 0; nt < 4; ++nt) {
            short8 kf0 = *(const short8*)&Kc[(nt * 16 + ln) * 72 + quad * 8];
            short8 kf1 = *(const short8*)&Kc[(nt * 16 + ln) * 72 + 32 + quad * 8];
#pragma unroll
            for (int mt = 0; mt < 2; ++mt) {
                s[mt][nt] = __builtin_amdgcn_mfma_f32_16x16x32_bf16(kf0, qf[mt][0], s[mt][nt], 0, 0, 0);
                s[mt][nt] = __builtin_amdgcn_mfma_f32_16x16x32_bf16(kf1, qf[mt][1], s[mt][nt], 0, 0, 0);
            }
        }
        __builtin_amdgcn_s_setprio(0);

        // exp + pack into mfma32 A-frags: pf8[mt][c] = k_phys c*32+quad*8+[0..7]
        short8 pf8[2][2];
#pragma unroll
        for (int mt = 0; mt < 2; ++mt)
#pragma unroll
            for (int nt = 0; nt < 4; ++nt)
#pragma unroll
                for (int r = 0; r < 4; ++r) {
                    unsigned int u = __float_as_uint(__builtin_amdgcn_exp2f(s[mt][nt][r]));
                    ls[mt] += __uint_as_float(u & 0xFFFF0000u);   // matched bf16 trunc
                    pf8[mt][nt >> 1][((nt & 1) << 2) | r] = (short)(u >> 16);
                }

        // PV: full-rate mfma32, P from registers
        __builtin_amdgcn_s_setprio(1);
#pragma unroll
        for (int dt = 0; dt < 4; ++dt)
#pragma unroll
            for (int c = 0; c < 2; ++c) {
                short8 vf = *(const short8*)&Vc[(dt * 16 + ln) * 72 + c * 32 + quad * 8];
#pragma unroll
                for (int mt = 0; mt < 2; ++mt)
                    O[mt][dt] = __builtin_amdgcn_mfma_f32_16x16x32_bf16(
                        pf8[mt][c], vf, O[mt][dt], 0, 0, 0);
            }
        __builtin_amdgcn_s_setprio(0);

        storeT(cur ^ 1);            // tile t+1 -> other buffer
        if (t + 2 <= 35) loadT(t + 2);
        __syncthreads();
    }

    // ---- global: 4 gathered tiles ----
    for (int tg = 0; tg < 4; ++tg) {
        const int t = 32 + tg;
        const int cur = t & 1;
        const unsigned short* Kc = KsB + cur * 4608;
        const unsigned short* Vc = VtB + cur * 4608;

        f32x4 s[2][4];
#pragma unroll
        for (int mt = 0; mt < 2; ++mt)
#pragma unroll
            for (int nt = 0; nt < 4; ++nt) s[mt][nt] = (f32x4){0.f, 0.f, 0.f, 0.f};
        __builtin_amdgcn_s_setprio(1);
#pragma unroll
        for (int nt = 0; nt < 4; ++nt) {
            short8 kf0 = *(const short8*)&Kc[(nt * 16 + ln) * 72 + quad * 8];
            short8 kf1 = *(const short8*)&Kc[(nt * 16 + ln) * 72 + 32 + quad * 8];
#pragma unroll
            for (int mt = 0; mt < 2; ++mt) {
                s[mt][nt] = __builtin_amdgcn_mfma_f32_16x16x32_bf16(kf0, qf[mt][0], s[mt][nt], 0, 0, 0);
                s[mt][nt] = __builtin_amdgcn_mfma_f32_16x16x32_bf16(kf1, qf[mt][1], s[mt][nt], 0, 0, 0);
            }
        }
        __builtin_amdgcn_s_setprio(0);

        short8 pf8[2][2];
#pragma unroll
        for (int nt = 0; nt < 4; ++nt)
#pragma unroll
            for (int r = 0; r < 4; ++r) {
                int phi = ((nt >> 1) << 5) | (quad << 3) | ((nt & 1) << 2) | r;
                bool valid = (tg * 64 + phi) < NG;
#pragma unroll
                for (int mt = 0; mt < 2; ++mt) {
                    float p = valid ? __builtin_amdgcn_exp2f(s[mt][nt][r]) : 0.f;
                    unsigned int u = __float_as_uint(p);
                    lg[mt] += __uint_as_float(u & 0xFFFF0000u);
                    pf8[mt][nt >> 1][((nt & 1) << 2) | r] = (short)(u >> 16);
                }
            }

        __builtin_amdgcn_s_setprio(1);
#pragma unroll
        for (int dt = 0; dt < 4; ++dt)
#pragma unroll
            for (int c = 0; c < 2; ++c) {
                short8 vf = *(const short8*)&Vc[(dt * 16 + ln) * 72 + c * 32 + quad * 8];
#pragma unroll
                for (int mt = 0; mt < 2; ++mt)
                    Og[mt][dt] = __builtin_amdgcn_mfma_f32_16x16x32_bf16(
                        pf8[mt][c], vf, Og[mt][dt], 0, 0, 0);
            }
        __builtin_amdgcn_s_setprio(0);

        if (t < 35) storeT(cur ^ 1);
        if (t + 2 <= 35) loadT(t + 2);
        __syncthreads();            // last iter: protects Ps alias in epilogue
    }

    // ---- reductions: ls/lg are per-q (q=..+ln) partials over (quad,r) ----
#pragma unroll
    for (int mt = 0; mt < 2; ++mt) {
        ls[mt] += __shfl_xor(ls[mt], 16);
        ls[mt] += __shfl_xor(ls[mt], 32);
        lg[mt] += __shfl_xor(lg[mt], 16);
        lg[mt] += __shfl_xor(lg[mt], 32);
    }
    // redistribute to O layout (q = quad*4+r): fetch from lane quad*4+r
    float invl[2][4], invg[2][4];
#pragma unroll
    for (int mt = 0; mt < 2; ++mt)
#pragma unroll
        for (int r = 0; r < 4; ++r) {
            invl[mt][r] = 1.f / __shfl(ls[mt], quad * 4 + r);
            invg[mt][r] = 1.f / __shfl(lg[mt], quad * 4 + r);
        }

    // ---- layernorm(global) ----
    float xs[2][4][4];
#pragma unroll
    for (int mt = 0; mt < 2; ++mt)
#pragma unroll
        for (int r = 0; r < 4; ++r) {
            float inv = invg[mt][r];
#pragma unroll
            for (int nt = 0; nt < 4; ++nt) xs[mt][nt][r] = Og[mt][nt][r] * inv;
        }
    float mu[2][4], rsd[2][4];
#pragma unroll
    for (int mt = 0; mt < 2; ++mt)
#pragma unroll
        for (int r = 0; r < 4; ++r) {
            float sm = xs[mt][0][r] + xs[mt][1][r] + xs[mt][2][r] + xs[mt][3][r];
#pragma unroll
            for (int off = 1; off <= 8; off <<= 1) sm += __shfl_xor(sm, off);
            mu[mt][r] = sm * (1.f / 64.f);
        }
#pragma unroll
    for (int mt = 0; mt < 2; ++mt)
#pragma unroll
        for (int r = 0; r < 4; ++r) {
            float sv = 0.f;
#pragma unroll
            for (int nt = 0; nt < 4; ++nt) {
                float d = xs[mt][nt][r] - mu[mt][r];
                sv += d * d;
            }
#pragma unroll
            for (int off = 1; off <= 8; off <<= 1) sv += __shfl_xor(sv, off);
            rsd[mt][r] = rsqrtf(sv * (1.f / 64.f) + LNEPS);
        }
#pragma unroll
    for (int nt = 0; nt < 4; ++nt) {
        float g = gamma[nt * 16 + ln], bb = beta[nt * 16 + ln];
#pragma unroll
        for (int mt = 0; mt < 2; ++mt)
#pragma unroll
            for (int r = 0; r < 4; ++r)
                xs[mt][nt][r] = (xs[mt][nt][r] - mu[mt][r]) * rsd[mt][r] * g + bb;
    }

    // ---- gate via MFMA (2 passes through Ps; intra-wave rows, no barrier) --
    float lf[2][4][4];
#pragma unroll
    for (int mt = 0; mt < 2; ++mt)
#pragma unroll
        for (int nt = 0; nt < 4; ++nt)
#pragma unroll
            for (int r = 0; r < 4; ++r) {
                lf[mt][nt][r] = O[mt][nt][r] * invl[mt][r];
                Ps[wave * 32 + mt * 16 + quad * 4 + r][nt * 16 + ln] = f2bf(lf[mt][nt][r]);
            }
    f32x4 gacc[2][4];
#pragma unroll
    for (int ng = 0; ng < 4; ++ng) {
        float bgv = bg[ng * 16 + ln];
#pragma unroll
        for (int mt = 0; mt < 2; ++mt)
            gacc[mt][ng] = (f32x4){bgv, bgv, bgv, bgv};
    }
#pragma unroll
    for (int ch = 0; ch < 2; ++ch) {
        short8 af[2];
#pragma unroll
        for (int mt = 0; mt < 2; ++mt)
            af[mt] = *(const short8*)&Ps[wave * 32 + mt * 16 + ln][ch * 32 + quad * 8];
#pragma unroll
        for (int ng = 0; ng < 4; ++ng) {
            short8 bf = *(const short8*)&Wgs[ng * 16 + ln][ch * 32 + quad * 8];
#pragma unroll
            for (int mt = 0; mt < 2; ++mt)
                gacc[mt][ng] = __builtin_amdgcn_mfma_f32_16x16x32_bf16(af[mt], bf, gacc[mt][ng], 0, 0, 0);
        }
    }
#pragma unroll
    for (int mt = 0; mt < 2; ++mt)
#pragma unroll
        for (int nt = 0; nt < 4; ++nt)
#pragma unroll
            for (int r = 0; r < 4; ++r)
                Ps[wave * 32 + mt * 16 + quad * 4 + r][nt * 16 + ln] = f2bf(xs[mt][nt][r]);
#pragma unroll
    for (int ch = 0; ch < 2; ++ch) {
        short8 af[2];
#pragma unroll
        for (int mt = 0; mt < 2; ++mt)
            af[mt] = *(const short8*)&Ps[wave * 32 + mt * 16 + ln][ch * 32 + quad * 8];
#pragma unroll
        for (int ng = 0; ng < 4; ++ng) {
            short8 bf = *(const short8*)&Wgs[ng * 16 + ln][64 + ch * 32 + quad * 8];
#pragma unroll
            for (int mt = 0; mt < 2; ++mt)
                gacc[mt][ng] = __builtin_amdgcn_mfma_f32_16x16x32_bf16(af[mt], bf, gacc[mt][ng], 0, 0, 0);
        }
    }

    // ---- fuse + store ----
    const int b = bh >> 4, h = bh & 15;
#pragma unroll
    for (int mt = 0; mt < 2; ++mt)
#pragma unroll
        for (int ng = 0; ng < 4; ++ng)
#pragma unroll
            for (int r = 0; r < 4; ++r) {
                float gt = 1.f / (1.f + __expf(-gacc[mt][ng][r]));
                float f = gt * lf[mt][ng][r] + (1.f - gt) * xs[mt][ng][r];
                int s = q0 + wave * 32 + mt * 16 + quad * 4 + r;
                fused[((size_t)(b * SEQ + s)) * DMODEL + h * DHEAD + ng * 16 + ln] = f2bf(f);
            }
}

// ---------------------------------------------------------------------------
extern "C" void kernel_launch(void* const* d_in, const int* in_sizes, int n_in,
                              void* d_out, int out_size, void* d_ws, size_t ws_size,
                              hipStream_t stream)
{
    (void)in_sizes; (void)n_in; (void)out_size; (void)ws_size;
    const float* x    = (const float*)d_in[0];
    const float* Wq   = (const float*)d_in[1];
    const float* Wk   = (const float*)d_in[2];
    const float* Wv   = (const float*)d_in[3];
    const float* Wo   = (const float*)d_in[4];
    const float* bo   = (const float*)d_in[5];
    const float* ln_g = (const float*)d_in[6];
    const float* ln_b = (const float*)d_in[7];
    const float* Wg   = (const float*)d_in[8];
    const float* bg   = (const float*)d_in[9];

    char* w = (char*)d_ws;
    const size_t MB = 1024ull * 1024ull;
    unsigned short* kb16  = (unsigned short*)(w);
    unsigned short* qb16  = (unsigned short*)(w + 8 * MB);
    unsigned short* vb16  = (unsigned short*)(w + 16 * MB);
    unsigned short* vt16  = (unsigned short*)(w + 24 * MB);
    unsigned short* xh    = (unsigned short*)(w + 32 * MB);
    unsigned short* xl    = (unsigned short*)(w + 40 * MB);
    unsigned short* Wqt   = (unsigned short*)(w + 48 * MB);
    unsigned short* Wvt   = (unsigned short*)(w + 50 * MB);   // contiguous after Wqt
    unsigned short* Wot   = (unsigned short*)(w + 52 * MB);
    unsigned short* Wkh   = (unsigned short*)(w + 54 * MB);
    unsigned short* Wkl   = (unsigned short*)(w + 56 * MB);
    unsigned short* Wgt   = (unsigned short*)(w + 58 * MB);
    float*          norms2= (float*)(w + 59 * MB);
    unsigned short* gk16  = (unsigned short*)(w + 60 * MB);
    unsigned short* gvt16 = (unsigned short*)(w + 61 * MB);
    unsigned short* fusedb = xh;   // xh dead after projections

    const int M = 4096, N = 1024, K = 1024;

    prep_k<<<3073, 256, 0, stream>>>(x, Wq, Wv, Wo, Wk, Wg,
                                     xh, xl, Wqt, Wvt, Wot, Wkh, Wkl, Wgt);

    dim3 gqv(2048 / 128, M / 128);
    gemm_bf16_k<<<gqv, 512, 0, stream>>>(xh, Wqt, nullptr, qb16, vb16, vt16,
                                         M, 2048, K, 3);

    dim3 gkp(N / 128, M / 128);
    gemm_kproj_mfma<<<gkp, 512, 0, stream>>>(xh, xl, Wkh, Wkl, kb16, norms2);

    topk_gather_k<<<BHT, 512, 0, stream>>>(norms2, kb16, vb16, gk16, gvt16);

    attn_fused_k<<<512, 256, 0, stream>>>(qb16, kb16, vt16, gk16, gvt16, Wgt,
                                          ln_g, ln_b, bg, fusedb);

    dim3 go_(N / 128, M / 128);
    gemm_bf16_k<<<go_, 512, 0, stream>>>(fusedb, Wot, bo, (float*)d_out, nullptr,
                                         nullptr, M, N, K, 0);
}

// Round 8
// 257.202 us; speedup vs baseline: 1.5440x; 1.0312x over previous
//
#include <hip/hip_runtime.h>

// SegmentedAttention round 17 = r16 + {QV∥kproj merged kernel, attn ls/lg
// via ones-MFMA}.
// r16 budget: attn 59 of 265; non-attn sum ~206. (1) QV gemm (512 blk) and
// kproj (256 blk = 1/CU, underfilled) have no mutual dependency -> merged
// into one 768-blk kernel (branch on blockIdx, 73728B LDS union, 2 blk/CU
// both paths): kproj co-schedules with QV tail, one less launch. (2) attn
// softmax row-sums moved off VALU: lsacc/lgacc = mfma(P_frag, ones_frag)
// (+4 mfma/tile vs ~128 VALU cyc saved), sums land in O-layout -> shfl
// redistribution deleted. Global-tile masking: tiles 0-2 fully valid
// (NG=204), tile 3 uses a constant mask-frag (k<12); padded rows have
// K=0 -> P=1 but V=0 and mask excludes from lg.
// ws (MB): kb16@0(8) qb16@8(8) vb16@16(8) vt16@24(8) xh@32(8,=fusedb)
//   xl@40(8) Wqt@48(2) Wvt@50(2) Wot@52(2) Wkh@54(2) Wkl@56(2) Wgt@58(1)
//   norms2@59(1) gk@60(1) gvt@61(1) -> 62MB

constexpr int SEQ    = 2048;
constexpr int DMODEL = 1024;
constexpr int NH     = 16;
constexpr int DHEAD  = 64;
constexpr int BHT    = 32;
constexpr int NG     = 204;
constexpr int NGPAD  = 256;
constexpr float LNEPS = 1e-5f;

typedef __attribute__((ext_vector_type(8))) short short8;
typedef __attribute__((ext_vector_type(4))) short short4v;
typedef __attribute__((ext_vector_type(4))) float f32x4;

__device__ __forceinline__ unsigned short f2bf(float f) {
    unsigned int u = __float_as_uint(f);
    u += 0x7FFFu + ((u >> 16) & 1u);
    return (unsigned short)(u >> 16);
}
__device__ __forceinline__ float bf2f(unsigned short b) {
    return __uint_as_float(((unsigned int)b) << 16);
}

// ---------------------------------------------------------------------------
// prep: blocks [0,2048): x hilo split; [2048,3072): weight transposes;
// block 3072: Wg^T bf16.
// ---------------------------------------------------------------------------
__global__ __launch_bounds__(256)
void prep_k(const float* __restrict__ x,
            const float* __restrict__ Wq, const float* __restrict__ Wv,
            const float* __restrict__ Wo, const float* __restrict__ Wk,
            const float* __restrict__ Wg,
            unsigned short* __restrict__ xh, unsigned short* __restrict__ xl,
            unsigned short* __restrict__ Wqt, unsigned short* __restrict__ Wvt,
            unsigned short* __restrict__ Wot, unsigned short* __restrict__ Wkh,
            unsigned short* __restrict__ Wkl, unsigned short* __restrict__ Wgt)
{
    const int bid = blockIdx.x;
    const int tid = threadIdx.x;

    if (bid < 2048) {
        int i = (bid * 256 + tid) << 3;
        short8 h, l;
#pragma unroll
        for (int j = 0; j < 8; ++j) {
            float v = x[i + j];
            unsigned short hb = f2bf(v);
            h[j] = (short)hb;
            l[j] = (short)f2bf(v - bf2f(hb));
        }
        *(short8*)(xh + i) = h;
        *(short8*)(xl + i) = l;
        return;
    }
    if (bid == 3072) {
#pragma unroll
        for (int i = 0; i < 32; ++i) {
            int o = tid * 32 + i;
            int dg = o >> 7, jj = o & 127;
            Wgt[o] = f2bf(Wg[jj * 64 + dg]);
        }
        return;
    }

    __shared__ float tile[64][68];
    const int sub = bid - 2048;
    const int which = sub >> 8;             // 0:Wq 1:Wv 2:Wo 3:Wk
    const int b = sub & 255;
    const int n0 = (b & 15) * 64, k0 = (b >> 4) * 64;
    const float* W = (which == 0) ? Wq : (which == 1) ? Wv : (which == 2) ? Wo : Wk;
    const int Kd = DMODEL, Nd = DMODEL;

#pragma unroll
    for (int p = 0; p < 4; ++p) {
        int c = tid + (p << 8);
        int r = c >> 4, c4 = (c & 15) << 2;
        *(float4*)&tile[r][c4] = *(const float4*)(W + (size_t)(k0 + r) * Nd + n0 + c4);
    }
    __syncthreads();
#pragma unroll
    for (int p = 0; p < 4; ++p) {
        int c = tid + (p << 8);
        int n = c >> 4, k4 = (c & 15) << 2;
        if (which < 3) {
            unsigned short* Wt = (which == 0) ? Wqt : (which == 1) ? Wvt : Wot;
            short4v o;
#pragma unroll
            for (int j = 0; j < 4; ++j) o[j] = (short)f2bf(tile[k4 + j][n]);
            *(short4v*)(Wt + (size_t)(n0 + n) * Kd + k0 + k4) = o;
        } else {
            short4v oh, ol;
#pragma unroll
            for (int j = 0; j < 4; ++j) {
                float v = tile[k4 + j][n];
                unsigned short hb = f2bf(v);
                oh[j] = (short)hb;
                ol[j] = (short)f2bf(v - bf2f(hb));
            }
            *(short4v*)(Wkh + (size_t)(n0 + n) * Kd + k0 + k4) = oh;
            *(short4v*)(Wkl + (size_t)(n0 + n) * Kd + k0 + k4) = ol;
        }
    }
}

// ---------------------------------------------------------------------------
// bf16 MFMA GEMM (OUT projection only now), 512 thr, 128x128 tile.
// mode 0: fp32 out = acc + bias.
// ---------------------------------------------------------------------------
__global__ __launch_bounds__(512)
void gemm_bf16_k(const unsigned short* __restrict__ A,
                 const unsigned short* __restrict__ Bt,
                 const float* __restrict__ bias,
                 float* __restrict__ out,
                 int M, int N, int K)
{
    __shared__ __align__(16) unsigned short As[128][72];
    __shared__ __align__(16) unsigned short Bs[128][72];
    const int tid = threadIdx.x;
    const int lane = tid & 63, wave = tid >> 6;
    const int quad = lane >> 4, ln = lane & 15;
    const int mh = (wave >> 2) << 6;
    const int nh = (wave & 3) << 5;
    const int m0 = blockIdx.y * 128, n0 = blockIdx.x * 128;

    f32x4 acc[4][2];
#pragma unroll
    for (int i = 0; i < 4; ++i)
#pragma unroll
        for (int j = 0; j < 2; ++j) acc[i][j] = (f32x4){0.f, 0.f, 0.f, 0.f};

    short8 areg[2], breg[2];
#pragma unroll
    for (int p = 0; p < 2; ++p) {
        int c = tid + (p << 9);
        int row = c >> 3, col8 = (c & 7) << 3;
        areg[p] = *(const short8*)(A + (size_t)(m0 + row) * K + col8);
        breg[p] = *(const short8*)(Bt + (size_t)(n0 + row) * K + col8);
    }

    for (int k0 = 0; k0 < K; k0 += 64) {
        __syncthreads();
#pragma unroll
        for (int p = 0; p < 2; ++p) {
            int c = tid + (p << 9);
            int row = c >> 3, col8 = (c & 7) << 3;
            *(short8*)&As[row][col8] = areg[p];
            *(short8*)&Bs[row][col8] = breg[p];
        }
        __syncthreads();
        if (k0 + 64 < K) {
#pragma unroll
            for (int p = 0; p < 2; ++p) {
                int c = tid + (p << 9);
                int row = c >> 3, col8 = (c & 7) << 3;
                areg[p] = *(const short8*)(A + (size_t)(m0 + row) * K + k0 + 64 + col8);
                breg[p] = *(const short8*)(Bt + (size_t)(n0 + row) * K + k0 + 64 + col8);
            }
        }
#pragma unroll
        for (int ch = 0; ch < 2; ++ch) {
            short8 af[4], bf[2];
#pragma unroll
            for (int mt = 0; mt < 4; ++mt)
                af[mt] = *(const short8*)&As[mh + mt * 16 + ln][ch * 32 + quad * 8];
#pragma unroll
            for (int nt = 0; nt < 2; ++nt)
                bf[nt] = *(const short8*)&Bs[nh + nt * 16 + ln][ch * 32 + quad * 8];
#pragma unroll
            for (int mt = 0; mt < 4; ++mt)
#pragma unroll
                for (int nt = 0; nt < 2; ++nt)
                    acc[mt][nt] = __builtin_amdgcn_mfma_f32_16x16x32_bf16(
                        af[mt], bf[nt], acc[mt][nt], 0, 0, 0);
        }
    }

#pragma unroll
    for (int mt = 0; mt < 4; ++mt)
#pragma unroll
        for (int nt = 0; nt < 2; ++nt)
#pragma unroll
            for (int r = 0; r < 4; ++r) {
                int m = m0 + mh + mt * 16 + quad * 4 + r;
                int n = n0 + nh + nt * 16 + ln;
                out[(size_t)m * N + n] = acc[mt][nt][r] + bias[n];
            }
}

// ---------------------------------------------------------------------------
// Merged projections: blocks [0,512) = QV (128x128 over N=2048, mode-3
// epilogue); blocks [512,768) = compensated kproj (128x128, M2xN4).
// Shared 73728B LDS union; both paths 2 blocks/CU.
// ---------------------------------------------------------------------------
__global__ __launch_bounds__(512)
void proj_qvk_k(const unsigned short* __restrict__ xh,
                const unsigned short* __restrict__ xl,
                const unsigned short* __restrict__ Wqt,
                const unsigned short* __restrict__ Wkh,
                const unsigned short* __restrict__ Wkl,
                unsigned short* __restrict__ qb,
                unsigned short* __restrict__ vb,
                unsigned short* __restrict__ vtout,
                unsigned short* __restrict__ kout,
                float* __restrict__ norms2)
{
    __shared__ __align__(16) unsigned short smem[36864];   // 73728 B
    const int blk = blockIdx.x;
    const int tid = threadIdx.x;
    const int lane = tid & 63, wave = tid >> 6;
    const int quad = lane >> 4, ln = lane & 15;
    const int K = DMODEL;

    if (blk < 512) {
        // ---------------- QV path ----------------
        unsigned short* As = smem;            // [128][72]
        unsigned short* Bs = smem + 9216;
        const int m0 = (blk >> 4) * 128, n0 = (blk & 15) * 128;
        const int mh = (wave >> 2) << 6;
        const int nh = (wave & 3) << 5;

        f32x4 acc[4][2];
#pragma unroll
        for (int i = 0; i < 4; ++i)
#pragma unroll
            for (int j = 0; j < 2; ++j) acc[i][j] = (f32x4){0.f, 0.f, 0.f, 0.f};

        short8 areg[2], breg[2];
#pragma unroll
        for (int p = 0; p < 2; ++p) {
            int c = tid + (p << 9);
            int row = c >> 3, col8 = (c & 7) << 3;
            areg[p] = *(const short8*)(xh + (size_t)(m0 + row) * K + col8);
            breg[p] = *(const short8*)(Wqt + (size_t)(n0 + row) * K + col8);
        }

        for (int k0 = 0; k0 < K; k0 += 64) {
            __syncthreads();
#pragma unroll
            for (int p = 0; p < 2; ++p) {
                int c = tid + (p << 9);
                int row = c >> 3, col8 = (c & 7) << 3;
                *(short8*)&As[row * 72 + col8] = areg[p];
                *(short8*)&Bs[row * 72 + col8] = breg[p];
            }
            __syncthreads();
            if (k0 + 64 < K) {
#pragma unroll
                for (int p = 0; p < 2; ++p) {
                    int c = tid + (p << 9);
                    int row = c >> 3, col8 = (c & 7) << 3;
                    areg[p] = *(const short8*)(xh + (size_t)(m0 + row) * K + k0 + 64 + col8);
                    breg[p] = *(const short8*)(Wqt + (size_t)(n0 + row) * K + k0 + 64 + col8);
                }
            }
#pragma unroll
            for (int ch = 0; ch < 2; ++ch) {
                short8 af[4], bf[2];
#pragma unroll
                for (int mt = 0; mt < 4; ++mt)
                    af[mt] = *(const short8*)&As[(mh + mt * 16 + ln) * 72 + ch * 32 + quad * 8];
#pragma unroll
                for (int nt = 0; nt < 2; ++nt)
                    bf[nt] = *(const short8*)&Bs[(nh + nt * 16 + ln) * 72 + ch * 32 + quad * 8];
#pragma unroll
                for (int mt = 0; mt < 4; ++mt)
#pragma unroll
                    for (int nt = 0; nt < 2; ++nt)
                        acc[mt][nt] = __builtin_amdgcn_mfma_f32_16x16x32_bf16(
                            af[mt], bf[nt], acc[mt][nt], 0, 0, 0);
            }
        }

#pragma unroll
        for (int mt = 0; mt < 4; ++mt)
#pragma unroll
            for (int nt = 0; nt < 2; ++nt) {
                int n = n0 + nh + nt * 16 + ln;
                int mb = m0 + mh + mt * 16 + quad * 4;
                int b = mb >> 11, s0 = mb & (SEQ - 1);
                int d = n & 63;
                if (n < DMODEL) {           // Q, pre-scaled incl. log2(e)
                    int h = n >> 6;
                    unsigned short* qp_ =
                        qb + ((size_t)(b * NH + h) * SEQ + s0) * DHEAD + d;
#pragma unroll
                    for (int r = 0; r < 4; ++r)
                        qp_[(size_t)r * DHEAD] = f2bf(acc[mt][nt][r] * 0.18033688f);
                } else {                    // V: row-major + transposed
                    int h = (n >> 6) - NH;
                    unsigned short* vp_ =
                        vb + ((size_t)(b * NH + h) * SEQ + s0) * DHEAD + d;
                    short4v tv;
#pragma unroll
                    for (int r = 0; r < 4; ++r) {
                        unsigned short bv = f2bf(acc[mt][nt][r]);
                        vp_[(size_t)r * DHEAD] = bv;
                        tv[r] = (short)bv;
                    }
                    *(short4v*)(vtout + ((size_t)(b * NH + h) * DHEAD + d) * SEQ + s0) = tv;
                }
            }
    } else {
        // ---------------- kproj path (compensated, M2xN4) ----------------
        unsigned short* Ah = smem;            // [128][72] each
        unsigned short* Al = smem + 9216;
        unsigned short* Bh = smem + 18432;
        unsigned short* Bl = smem + 27648;
        const int sb = blk - 512;
        const int m0 = (sb >> 3) * 128, n0 = (sb & 7) * 128;
        const int mh = (wave >> 1) << 5;      // 4 m-groups x 32 rows
        const int nh = (wave & 1) << 6;       // 2 n-groups x 64 cols

        f32x4 acc[2][4];
#pragma unroll
        for (int i = 0; i < 2; ++i)
#pragma unroll
            for (int j = 0; j < 4; ++j) acc[i][j] = (f32x4){0.f, 0.f, 0.f, 0.f};

        short8 ahreg[2], alreg[2], bhreg[2], blreg[2];
#pragma unroll
        for (int p = 0; p < 2; ++p) {
            int c = tid + (p << 9);
            int row = c >> 3, col8 = (c & 7) << 3;
            size_t ga = (size_t)(m0 + row) * K + col8;
            size_t gb = (size_t)(n0 + row) * K + col8;
            ahreg[p] = *(const short8*)(xh + ga);
            alreg[p] = *(const short8*)(xl + ga);
            bhreg[p] = *(const short8*)(Wkh + gb);
            blreg[p] = *(const short8*)(Wkl + gb);
        }

        for (int k0 = 0; k0 < K; k0 += 64) {
            __syncthreads();
#pragma unroll
            for (int p = 0; p < 2; ++p) {
                int c = tid + (p << 9);
                int row = c >> 3, col8 = (c & 7) << 3;
                *(short8*)&Ah[row * 72 + col8] = ahreg[p];
                *(short8*)&Al[row * 72 + col8] = alreg[p];
                *(short8*)&Bh[row * 72 + col8] = bhreg[p];
                *(short8*)&Bl[row * 72 + col8] = blreg[p];
            }
            __syncthreads();
            if (k0 + 64 < K) {
#pragma unroll
                for (int p = 0; p < 2; ++p) {
                    int c = tid + (p << 9);
                    int row = c >> 3, col8 = (c & 7) << 3;
                    size_t ga = (size_t)(m0 + row) * K + k0 + 64 + col8;
                    size_t gb = (size_t)(n0 + row) * K + k0 + 64 + col8;
                    ahreg[p] = *(const short8*)(xh + ga);
                    alreg[p] = *(const short8*)(xl + ga);
                    bhreg[p] = *(const short8*)(Wkh + gb);
                    blreg[p] = *(const short8*)(Wkl + gb);
                }
            }
#pragma unroll
            for (int ch = 0; ch < 2; ++ch) {
                short8 afh[2], afl[2];
#pragma unroll
                for (int mt = 0; mt < 2; ++mt) {
                    afh[mt] = *(const short8*)&Ah[(mh + mt * 16 + ln) * 72 + ch * 32 + quad * 8];
                    afl[mt] = *(const short8*)&Al[(mh + mt * 16 + ln) * 72 + ch * 32 + quad * 8];
                }
#pragma unroll
                for (int nt = 0; nt < 4; ++nt) {
                    short8 bfh = *(const short8*)&Bh[(nh + nt * 16 + ln) * 72 + ch * 32 + quad * 8];
                    short8 bfl = *(const short8*)&Bl[(nh + nt * 16 + ln) * 72 + ch * 32 + quad * 8];
#pragma unroll
                    for (int mt = 0; mt < 2; ++mt) {
                        acc[mt][nt] = __builtin_amdgcn_mfma_f32_16x16x32_bf16(afh[mt], bfh, acc[mt][nt], 0, 0, 0);
                        acc[mt][nt] = __builtin_amdgcn_mfma_f32_16x16x32_bf16(afh[mt], bfl, acc[mt][nt], 0, 0, 0);
                        acc[mt][nt] = __builtin_amdgcn_mfma_f32_16x16x32_bf16(afl[mt], bfh, acc[mt][nt], 0, 0, 0);
                    }
                }
            }
        }

        const int h = (n0 + nh) >> 6;
#pragma unroll
        for (int mt = 0; mt < 2; ++mt)
#pragma unroll
            for (int r = 0; r < 4; ++r) {
                int m = m0 + mh + mt * 16 + quad * 4 + r;
                int b = m >> 11, s = m & (SEQ - 1);
                size_t rowbase = ((size_t)(b * NH + h) * SEQ + s) * DHEAD;
#pragma unroll
                for (int nt = 0; nt < 4; ++nt)
                    kout[rowbase + nt * 16 + ln] = f2bf(acc[mt][nt][r]);
                float s2 = acc[mt][0][r] * acc[mt][0][r] + acc[mt][1][r] * acc[mt][1][r] +
                           acc[mt][2][r] * acc[mt][2][r] + acc[mt][3][r] * acc[mt][3][r];
#pragma unroll
                for (int off = 1; off <= 8; off <<= 1)
                    s2 += __shfl_xor(s2, off);
                if (ln == 0)
                    norms2[(size_t)(b * NH + h) * SEQ + s] = s2;
            }
    }
}

// ---------------------------------------------------------------------------
// topk + gather fused, 512 threads.
// ---------------------------------------------------------------------------
__global__ __launch_bounds__(512)
void topk_gather_k(const float* __restrict__ norms2,
                   const unsigned short* __restrict__ k,
                   const unsigned short* __restrict__ v,
                   unsigned short* __restrict__ gk,
                   unsigned short* __restrict__ gvt)
{
    __shared__ unsigned long long keys[SEQ];
    __shared__ int tix[NGPAD];
    __shared__ __align__(16) unsigned short T[64][72];
    const int bh = blockIdx.x;
    const int tid = threadIdx.x;
    const float* nb = norms2 + (size_t)bh * SEQ;
    const size_t base = (size_t)bh * SEQ * DHEAD;

    for (int i = tid; i < SEQ; i += 512) {
        float nrm = sqrtf(nb[i]);
        keys[i] = ((unsigned long long)__float_as_uint(nrm) << 32) |
                  (unsigned int)(0xFFFFFFFFu - (unsigned int)i);
    }
    __syncthreads();
    for (int kk = 2; kk <= SEQ; kk <<= 1) {
        for (int j = kk >> 1; j > 0; j >>= 1) {
            for (int i = tid; i < SEQ; i += 512) {
                int ixj = i ^ j;
                if (ixj > i) {
                    unsigned long long a = keys[i], b = keys[ixj];
                    bool up = ((i & kk) == 0);
                    if ((a > b) == up) { keys[i] = b; keys[ixj] = a; }
                }
            }
            __syncthreads();
        }
    }
    if (tid < NGPAD) {
        tix[tid] = (tid < NG)
            ? (int)(0xFFFFFFFFu - (unsigned int)(keys[SEQ - 1 - tid] & 0xFFFFFFFFu))
            : 0;
    }
    __syncthreads();

    for (int t = 0; t < NGPAD / 64; ++t) {
        {
            int idx = tid;
            int row = idx >> 3, col8 = (idx & 7) << 3;
            int g = t * 64 + row;
            short8 kv = (short8)0, vv = (short8)0;
            if (g < NG) {
                int sidx = tix[g];
                kv = *(const short8*)(k + base + (size_t)sidx * DHEAD + col8);
                vv = *(const short8*)(v + base + (size_t)sidx * DHEAD + col8);
            }
            *(short8*)(gk + ((size_t)bh * NGPAD + g) * DHEAD + col8) = kv;
            *(short8*)&T[row][col8] = vv;
        }
        __syncthreads();
        {
            int idx = tid;
            int d = idx >> 3, k8 = (idx & 7) << 3;
            short8 o;
#pragma unroll
            for (int i = 0; i < 8; ++i) o[i] = (short)T[k8 + i][d];
            *(short8*)(gvt + ((size_t)bh * DHEAD + d) * NGPAD + t * 64 + k8) = o;
        }
        __syncthreads();
    }
}

// ---------------------------------------------------------------------------
// Fused attention r17: r15 structure + row-sums via ones-MFMA (lsacc/lgacc
// in O-layout, no shfl redistribution, no per-element global masking).
// ---------------------------------------------------------------------------
__global__ __launch_bounds__(256, 2)
void attn_fused_k(const unsigned short* __restrict__ qb,
                  const unsigned short* __restrict__ kb,
                  const unsigned short* __restrict__ vt,
                  const unsigned short* __restrict__ gk,
                  const unsigned short* __restrict__ gvt,
                  const unsigned short* __restrict__ Wgt,
                  const float* __restrict__ gamma,
                  const float* __restrict__ beta,
                  const float* __restrict__ bg,
                  unsigned short* __restrict__ fused)
{
    // smem layout (shorts): [0,9216) Ks[2][64][72]  (= Ps[128][72] alias)
    //                       [9216,18432) Vt[2][64][72]
    //                       [18432,27136) Wgs[64][136]
    __shared__ __align__(16) unsigned short smem[27136];
    unsigned short* const KsB = smem;
    unsigned short* const VtB = smem + 9216;
    unsigned short (*Ps)[72]  = (unsigned short (*)[72])smem;
    unsigned short (*Wgs)[136] = (unsigned short (*)[136])(smem + 18432);

    const int flat = blockIdx.x;
    const int bh = ((flat >> 7) << 3) | (flat & 7);   // flat%8 == bh%8 (XCD)
    const int q0 = ((flat >> 3) & 15) * 128;
    const int tid = threadIdx.x;
    const int lane = tid & 63, wave = tid >> 6;       // 4 waves
    const int quad = lane >> 4, ln = lane & 15;
    const size_t base = (size_t)bh * SEQ * DHEAD;
    const unsigned short* gkb = gk + (size_t)bh * NGPAD * DHEAD;
    const unsigned short* gvb = gvt + (size_t)bh * DHEAD * NGPAD;

    // stage Wg^T (read only in epilogue; first barrier covers it)
#pragma unroll
    for (int p = 0; p < 4; ++p) {
        int idx = tid + (p << 8);
        *(short8*)&Wgs[idx >> 4][(idx & 15) << 3] = *(const short8*)(Wgt + idx * 8);
    }

    short8 qf[2][2];
#pragma unroll
    for (int mt = 0; mt < 2; ++mt) {
        const unsigned short* qp = qb + base + (size_t)(q0 + wave * 32 + mt * 16 + ln) * DHEAD;
        qf[mt][0] = *(const short8*)(qp + quad * 8);
        qf[mt][1] = *(const short8*)(qp + 32 + quad * 8);
    }

    // ones / last-tile-mask B-frags for row-sum MFMAs
    short8 onesv, maskv;
#pragma unroll
    for (int j = 0; j < 8; ++j) {
        onesv[j] = (short)0x3F80;                              // bf16 1.0
        maskv[j] = (short)((quad * 8 + j) < 12 ? 0x3F80 : 0);  // NG-192=12
    }

    f32x4 O[2][4], Og[2][4], lsacc[2], lgacc[2];
#pragma unroll
    for (int mt = 0; mt < 2; ++mt) {
#pragma unroll
        for (int nt = 0; nt < 4; ++nt) {
            O[mt][nt] = (f32x4){0.f, 0.f, 0.f, 0.f};
            Og[mt][nt] = (f32x4){0.f, 0.f, 0.f, 0.f};
        }
        lsacc[mt] = (f32x4){0.f, 0.f, 0.f, 0.f};
        lgacc[mt] = (f32x4){0.f, 0.f, 0.f, 0.f};
    }

    short8 kreg[2], vreg[2];
    int srow[2], scol8[2], psrow[2];
#pragma unroll
    for (int p = 0; p < 2; ++p) {
        int idx = tid + (p << 8);
        srow[p] = idx >> 3;
        scol8[p] = (idx & 7) << 3;
        // phi: [b5 | b3 b2 | b4 | b1 b0]  (K-row permutation, verified r14)
        psrow[p] = (srow[p] & 0x20) | ((srow[p] & 0x0C) << 1) |
                   ((srow[p] & 0x10) >> 2) | (srow[p] & 3);
    }

    auto loadT = [&](int i) {
#pragma unroll
        for (int p = 0; p < 2; ++p) {
            if (i < 32) {
                kreg[p] = *(const short8*)(kb + base + (size_t)(i * 64 + psrow[p]) * DHEAD + scol8[p]);
                vreg[p] = *(const short8*)(vt + base + (size_t)srow[p] * SEQ + i * 64 + scol8[p]);
            } else {
                int g = i - 32;
                kreg[p] = *(const short8*)(gkb + (size_t)(g * 64 + psrow[p]) * DHEAD + scol8[p]);
                vreg[p] = *(const short8*)(gvb + (size_t)srow[p] * NGPAD + g * 64 + scol8[p]);
            }
        }
    };
    auto storeT = [&](int buf) {
        unsigned short* kd = KsB + buf * 4608;
        unsigned short* vd = VtB + buf * 4608;
#pragma unroll
        for (int p = 0; p < 2; ++p) {
            *(short8*)&kd[srow[p] * 72 + scol8[p]] = kreg[p];
            *(short8*)&vd[srow[p] * 72 + scol8[p]] = vreg[p];
        }
    };

    loadT(0);
    storeT(0);
    loadT(1);
    __syncthreads();

    // ---- local: 32 tiles ----
    for (int t = 0; t < 32; ++t) {
        const int cur = t & 1;
        const unsigned short* Kc = KsB + cur * 4608;
        const unsigned short* Vc = VtB + cur * 4608;

        // swapped QK^T: lane holds S^T[k_phys = phi(nt*16+quad*4+r)][q=ln]
        f32x4 s[2][4];
#pragma unroll
        for (int mt = 0; mt < 2; ++mt)
#pragma unroll
            for (int nt = 0; nt < 4; ++nt) s[mt][nt] = (f32x4){0.f, 0.f, 0.f, 0.f};
        __builtin_amdgcn_s_setprio(1);
#pragma unroll
        for (int nt = 0; nt < 4; ++nt) {
            short8 kf0 = *(const short8*)&Kc[(nt * 16 + ln) * 72 + quad * 8];
            short8 kf1 = *(const short8*)&Kc[(nt * 16 + ln) * 72 + 32 + quad * 8];
#pragma unroll
            for (int mt = 0; mt < 2; ++mt) {
                s[mt][nt] = __builtin_amdgcn_mfma_f32_16x16x32_bf16(kf0, qf[mt][0], s[mt][nt], 0, 0, 0);
                s[mt][nt] = __builtin_amdgcn_mfma_f32_16x16x32_bf16(kf1, qf[mt][1], s[mt][nt], 0, 0, 0);
            }
        }
        __builtin_amdgcn_s_setprio(0);

        // exp + pack into mfma32 A-frags: pf8[mt][c] = k_phys c*32+quad*8+[0..7]
        short8 pf8[2][2];
#pragma unroll
        for (int mt = 0; mt < 2; ++mt)
#pragma unroll
            for (int nt = 0; nt < 4; ++nt)
#pragma unroll
                for (int r = 0; r < 4; ++r) {
                    unsigned int u = __float_as_uint(__builtin_amdgcn_exp2f(s[mt][nt][r]));
                    pf8[mt][nt >> 1][((nt & 1) << 2) | r] = (short)(u >> 16);
                }

        // PV + row-sum: full-rate mfma32, P from registers
        __builtin_amdgcn_s_setprio(1);
#pragma unroll
        for (int dt = 0; dt < 4; ++dt)
#pragma unroll
            for (int c = 0; c < 2; ++c) {
                short8 vf = *(const short8*)&Vc[(dt * 16 + ln) * 72 + c * 32 + quad * 8];
#pragma unroll
                for (int mt = 0; mt < 2; ++mt)
                    O[mt][dt] = __builtin_amdgcn_mfma_f32_16x16x32_bf16(
                        pf8[mt][c], vf, O[mt][dt], 0, 0, 0);
            }
#pragma unroll
        for (int c = 0; c < 2; ++c)
#pragma unroll
            for (int mt = 0; mt < 2; ++mt)
                lsacc[mt] = __builtin_amdgcn_mfma_f32_16x16x32_bf16(
                    pf8[mt][c], onesv, lsacc[mt], 0, 0, 0);
        __builtin_amdgcn_s_setprio(0);

        storeT(cur ^ 1);            // tile t+1 -> other buffer
        if (t + 2 <= 35) loadT(t + 2);
        __syncthreads();
    }

    // ---- global: 4 gathered tiles (padded rows: K=0 -> P=1, V=0; mask
    //      excludes them from lgacc; tiles 0-2 fully valid) ----
    for (int tg = 0; tg < 4; ++tg) {
        const int t = 32 + tg;
        const int cur = t & 1;
        const unsigned short* Kc = KsB + cur * 4608;
        const unsigned short* Vc = VtB + cur * 4608;

        f32x4 s[2][4];
#pragma unroll
        for (int mt = 0; mt < 2; ++mt)
#pragma unroll
            for (int nt = 0; nt < 4; ++nt) s[mt][nt] = (f32x4){0.f, 0.f, 0.f, 0.f};
        __builtin_amdgcn_s_setprio(1);
#pragma unroll
        for (int nt = 0; nt < 4; ++nt) {
            short8 kf0 = *(const short8*)&Kc[(nt * 16 + ln) * 72 + quad * 8];
            short8 kf1 = *(const short8*)&Kc[(nt * 16 + ln) * 72 + 32 + quad * 8];
#pragma unroll
            for (int mt = 0; mt < 2; ++mt) {
                s[mt][nt] = __builtin_amdgcn_mfma_f32_16x16x32_bf16(kf0, qf[mt][0], s[mt][nt], 0, 0, 0);
                s[mt][nt] = __builtin_amdgcn_mfma_f32_16x16x32_bf16(kf1, qf[mt][1], s[mt][nt], 0, 0, 0);
            }
        }
        __builtin_amdgcn_s_setprio(0);

        short8 pf8[2][2];
#pragma unroll
        for (int mt = 0; mt < 2; ++mt)
#pragma unroll
            for (int nt = 0; nt < 4; ++nt)
#pragma unroll
                for (int r = 0; r < 4; ++r) {
                    unsigned int u = __float_as_uint(__builtin_amdgcn_exp2f(s[mt][nt][r]));
                    pf8[mt][nt >> 1][((nt & 1) << 2) | r] = (short)(u >> 16);
                }

        __builtin_amdgcn_s_setprio(1);
#pragma unroll
        for (int dt = 0; dt < 4; ++dt)
#pragma unroll
            for (int c = 0; c < 2; ++c) {
                short8 vf = *(const short8*)&Vc[(dt * 16 + ln) * 72 + c * 32 + quad * 8];
#pragma unroll
                for (int mt = 0; mt < 2; ++mt)
                    Og[mt][dt] = __builtin_amdgcn_mfma_f32_16x16x32_bf16(
                        pf8[mt][c], vf, Og[mt][dt], 0, 0, 0);
            }
        if (tg < 3) {
#pragma unroll
            for (int c = 0; c < 2; ++c)
#pragma unroll
                for (int mt = 0; mt < 2; ++mt)
                    lgacc[mt] = __builtin_amdgcn_mfma_f32_16x16x32_bf16(
                        pf8[mt][c], onesv, lgacc[mt], 0, 0, 0);
        } else {
            // last tile: only k_phys < 12 valid (c=0 chunk), via maskv
#pragma unroll
            for (int mt = 0; mt < 2; ++mt)
                lgacc[mt] = __builtin_amdgcn_mfma_f32_16x16x32_bf16(
                    pf8[mt][0], maskv, lgacc[mt], 0, 0, 0);
        }
        __builtin_amdgcn_s_setprio(0);

        if (t < 35) storeT(cur ^ 1);
        if (t + 2 <= 35) loadT(t + 2);
        __syncthreads();            // last iter: protects Ps alias in epilogue
    }

    // ---- row sums already in O layout (q = quad*4+r) ----
    float invl[2][4], invg[2][4];
#pragma unroll
    for (int mt = 0; mt < 2; ++mt)
#pragma unroll
        for (int r = 0; r < 4; ++r) {
            invl[mt][r] = 1.f / lsacc[mt][r];
            invg[mt][r] = 1.f / lgacc[mt][r];
        }

    // ---- layernorm(global) ----
    float xs[2][4][4];
#pragma unroll
    for (int mt = 0; mt < 2; ++mt)
#pragma unroll
        for (int r = 0; r < 4; ++r) {
            float inv = invg[mt][r];
#pragma unroll
            for (int nt = 0; nt < 4; ++nt) xs[mt][nt][r] = Og[mt][nt][r] * inv;
        }
    float mu[2][4], rsd[2][4];
#pragma unroll
    for (int mt = 0; mt < 2; ++mt)
#pragma unroll
        for (int r = 0; r < 4; ++r) {
            float sm = xs[mt][0][r] + xs[mt][1][r] + xs[mt][2][r] + xs[mt][3][r];
#pragma unroll
            for (int off = 1; off <= 8; off <<= 1) sm += __shfl_xor(sm, off);
            mu[mt][r] = sm * (1.f / 64.f);
        }
#pragma unroll
    for (int mt = 0; mt < 2; ++mt)
#pragma unroll
        for (int r = 0; r < 4; ++r) {
            float sv = 0.f;
#pragma unroll
            for (int nt = 0; nt < 4; ++nt) {
                float d = xs[mt][nt][r] - mu[mt][r];
                sv += d * d;
            }
#pragma unroll
            for (int off = 1; off <= 8; off <<= 1) sv += __shfl_xor(sv, off);
            rsd[mt][r] = rsqrtf(sv * (1.f / 64.f) + LNEPS);
        }
#pragma unroll
    for (int nt = 0; nt < 4; ++nt) {
        float g = gamma[nt * 16 + ln], bb = beta[nt * 16 + ln];
#pragma unroll
        for (int mt = 0; mt < 2; ++mt)
#pragma unroll
            for (int r = 0; r < 4; ++r)
                xs[mt][nt][r] = (xs[mt][nt][r] - mu[mt][r]) * rsd[mt][r] * g + bb;
    }

    // ---- gate via MFMA (2 passes through Ps; intra-wave rows, no barrier) --
    float lf[2][4][4];
#pragma unroll
    for (int mt = 0; mt < 2; ++mt)
#pragma unroll
        for (int nt = 0; nt < 4; ++nt)
#pragma unroll
            for (int r = 0; r < 4; ++r) {
                lf[mt][nt][r] = O[mt][nt][r] * invl[mt][r];
                Ps[wave * 32 + mt * 16 + quad * 4 + r][nt * 16 + ln] = f2bf(lf[mt][nt][r]);
            }
    f32x4 gacc[2][4];
#pragma unroll
    for (int ng = 0; ng < 4; ++ng) {
        float bgv = bg[ng * 16 + ln];
#pragma unroll
        for (int mt = 0; mt < 2; ++mt)
            gacc[mt][ng] = (f32x4){bgv, bgv, bgv, bgv};
    }
#pragma unroll
    for (int ch = 0; ch < 2; ++ch) {
        short8 af[2];
#pragma unroll
        for (int mt = 0; mt < 2; ++mt)
            af[mt] = *(const short8*)&Ps[wave * 32 + mt * 16 + ln][ch * 32 + quad * 8];
#pragma unroll
        for (int ng = 0; ng < 4; ++ng) {
            short8 bf = *(const short8*)&Wgs[ng * 16 + ln][ch * 32 + quad * 8];
#pragma unroll
            for (int mt = 0; mt < 2; ++mt)
                gacc[mt][ng] = __builtin_amdgcn_mfma_f32_16x16x32_bf16(af[mt], bf, gacc[mt][ng], 0, 0, 0);
        }
    }
#pragma unroll
    for (int mt = 0; mt < 2; ++mt)
#pragma unroll
        for (int nt = 0; nt < 4; ++nt)
#pragma unroll
            for (int r = 0; r < 4; ++r)
                Ps[wave * 32 + mt * 16 + quad * 4 + r][nt * 16 + ln] = f2bf(xs[mt][nt][r]);
#pragma unroll
    for (int ch = 0; ch < 2; ++ch) {
        short8 af[2];
#pragma unroll
        for (int mt = 0; mt < 2; ++mt)
            af[mt] = *(const short8*)&Ps[wave * 32 + mt * 16 + ln][ch * 32 + quad * 8];
#pragma unroll
        for (int ng = 0; ng < 4; ++ng) {
            short8 bf = *(const short8*)&Wgs[ng * 16 + ln][64 + ch * 32 + quad * 8];
#pragma unroll
            for (int mt = 0; mt < 2; ++mt)
                gacc[mt][ng] = __builtin_amdgcn_mfma_f32_16x16x32_bf16(af[mt], bf, gacc[mt][ng], 0, 0, 0);
        }
    }

    // ---- fuse + store ----
    const int b = bh >> 4, h = bh & 15;
#pragma unroll
    for (int mt = 0; mt < 2; ++mt)
#pragma unroll
        for (int ng = 0; ng < 4; ++ng)
#pragma unroll
            for (int r = 0; r < 4; ++r) {
                float gt = 1.f / (1.f + __expf(-gacc[mt][ng][r]));
                float f = gt * lf[mt][ng][r] + (1.f - gt) * xs[mt][ng][r];
                int s = q0 + wave * 32 + mt * 16 + quad * 4 + r;
                fused[((size_t)(b * SEQ + s)) * DMODEL + h * DHEAD + ng * 16 + ln] = f2bf(f);
            }
}

// ---------------------------------------------------------------------------
extern "C" void kernel_launch(void* const* d_in, const int* in_sizes, int n_in,
                              void* d_out, int out_size, void* d_ws, size_t ws_size,
                              hipStream_t stream)
{
    (void)in_sizes; (void)n_in; (void)out_size; (void)ws_size;
    const float* x    = (const float*)d_in[0];
    const float* Wq   = (const float*)d_in[1];
    const float* Wk   = (const float*)d_in[2];
    const float* Wv   = (const float*)d_in[3];
    const float* Wo   = (const float*)d_in[4];
    const float* bo   = (const float*)d_in[5];
    const float* ln_g = (const float*)d_in[6];
    const float* ln_b = (const float*)d_in[7];
    const float* Wg   = (const float*)d_in[8];
    const float* bg   = (const float*)d_in[9];

    char* w = (char*)d_ws;
    const size_t MB = 1024ull * 1024ull;
    unsigned short* kb16  = (unsigned short*)(w);
    unsigned short* qb16  = (unsigned short*)(w + 8 * MB);
    unsigned short* vb16  = (unsigned short*)(w + 16 * MB);
    unsigned short* vt16  = (unsigned short*)(w + 24 * MB);
    unsigned short* xh    = (unsigned short*)(w + 32 * MB);
    unsigned short* xl    = (unsigned short*)(w + 40 * MB);
    unsigned short* Wqt   = (unsigned short*)(w + 48 * MB);
    unsigned short* Wvt   = (unsigned short*)(w + 50 * MB);   // contiguous after Wqt
    unsigned short* Wot   = (unsigned short*)(w + 52 * MB);
    unsigned short* Wkh   = (unsigned short*)(w + 54 * MB);
    unsigned short* Wkl   = (unsigned short*)(w + 56 * MB);
    unsigned short* Wgt   = (unsigned short*)(w + 58 * MB);
    float*          norms2= (float*)(w + 59 * MB);
    unsigned short* gk16  = (unsigned short*)(w + 60 * MB);
    unsigned short* gvt16 = (unsigned short*)(w + 61 * MB);
    unsigned short* fusedb = xh;   // xh dead after projections
    (void)Wvt;

    const int M = 4096, N = 1024, K = 1024;

    prep_k<<<3073, 256, 0, stream>>>(x, Wq, Wv, Wo, Wk, Wg,
                                     xh, xl, Wqt, Wvt, Wot, Wkh, Wkl, Wgt);

    proj_qvk_k<<<768, 512, 0, stream>>>(xh, xl, Wqt, Wkh, Wkl,
                                        qb16, vb16, vt16, kb16, norms2);

    topk_gather_k<<<BHT, 512, 0, stream>>>(norms2, kb16, vb16, gk16, gvt16);

    attn_fused_k<<<512, 256, 0, stream>>>(qb16, kb16, vt16, gk16, gvt16, Wgt,
                                          ln_g, ln_b, bg, fusedb);

    dim3 go_(N / 128, M / 128);
    gemm_bf16_k<<<go_, 512, 0, stream>>>(fusedb, Wot, bo, (float*)d_out,
                                         M, N, K);
}

// Round 9
// 243.580 us; speedup vs baseline: 1.6304x; 1.0559x over previous
//
#include <hip/hip_runtime.h>

// SegmentedAttention round 18 = r17 + {XCD-aware tile swizzle in proj &
// out-gemm, topk at 1024 threads}.
// r17: proj_qvk_k 63us, FETCH 103MB vs 22MB unique (4.7x over-fetch),
// MfmaUtil 27 / VALU 13 / HBM 27% -> latency-bound on cross-XCD panel
// re-fetch. Fix: decode blockIdx so blk%8 (XCD) == m%8 -> each XCD keeps
// its 4 A-panels L2-resident across all n-tiles (QV: 32mx16n; kproj:
// 32mx8n; outgemm: 32mx8n, now 1D grid). topk: 1024 thr (2 CE/thread
// over 66 bitonic stages). NOTE: b128 "bank conflicts" are the 8-cycle
// floor of 1KB accesses, not a real stall - stop chasing that counter.
// ws (MB): kb16@0(8) qb16@8(8) vb16@16(8) vt16@24(8) xh@32(8,=fusedb)
//   xl@40(8) Wqt@48(2) Wvt@50(2) Wot@52(2) Wkh@54(2) Wkl@56(2) Wgt@58(1)
//   norms2@59(1) gk@60(1) gvt@61(1) -> 62MB

constexpr int SEQ    = 2048;
constexpr int DMODEL = 1024;
constexpr int NH     = 16;
constexpr int DHEAD  = 64;
constexpr int BHT    = 32;
constexpr int NG     = 204;
constexpr int NGPAD  = 256;
constexpr float LNEPS = 1e-5f;

typedef __attribute__((ext_vector_type(8))) short short8;
typedef __attribute__((ext_vector_type(4))) short short4v;
typedef __attribute__((ext_vector_type(4))) float f32x4;

__device__ __forceinline__ unsigned short f2bf(float f) {
    unsigned int u = __float_as_uint(f);
    u += 0x7FFFu + ((u >> 16) & 1u);
    return (unsigned short)(u >> 16);
}
__device__ __forceinline__ float bf2f(unsigned short b) {
    return __uint_as_float(((unsigned int)b) << 16);
}

// ---------------------------------------------------------------------------
// prep: blocks [0,2048): x hilo split; [2048,3072): weight transposes;
// block 3072: Wg^T bf16.
// ---------------------------------------------------------------------------
__global__ __launch_bounds__(256)
void prep_k(const float* __restrict__ x,
            const float* __restrict__ Wq, const float* __restrict__ Wv,
            const float* __restrict__ Wo, const float* __restrict__ Wk,
            const float* __restrict__ Wg,
            unsigned short* __restrict__ xh, unsigned short* __restrict__ xl,
            unsigned short* __restrict__ Wqt, unsigned short* __restrict__ Wvt,
            unsigned short* __restrict__ Wot, unsigned short* __restrict__ Wkh,
            unsigned short* __restrict__ Wkl, unsigned short* __restrict__ Wgt)
{
    const int bid = blockIdx.x;
    const int tid = threadIdx.x;

    if (bid < 2048) {
        int i = (bid * 256 + tid) << 3;
        short8 h, l;
#pragma unroll
        for (int j = 0; j < 8; ++j) {
            float v = x[i + j];
            unsigned short hb = f2bf(v);
            h[j] = (short)hb;
            l[j] = (short)f2bf(v - bf2f(hb));
        }
        *(short8*)(xh + i) = h;
        *(short8*)(xl + i) = l;
        return;
    }
    if (bid == 3072) {
#pragma unroll
        for (int i = 0; i < 32; ++i) {
            int o = tid * 32 + i;
            int dg = o >> 7, jj = o & 127;
            Wgt[o] = f2bf(Wg[jj * 64 + dg]);
        }
        return;
    }

    __shared__ float tile[64][68];
    const int sub = bid - 2048;
    const int which = sub >> 8;             // 0:Wq 1:Wv 2:Wo 3:Wk
    const int b = sub & 255;
    const int n0 = (b & 15) * 64, k0 = (b >> 4) * 64;
    const float* W = (which == 0) ? Wq : (which == 1) ? Wv : (which == 2) ? Wo : Wk;
    const int Kd = DMODEL, Nd = DMODEL;

#pragma unroll
    for (int p = 0; p < 4; ++p) {
        int c = tid + (p << 8);
        int r = c >> 4, c4 = (c & 15) << 2;
        *(float4*)&tile[r][c4] = *(const float4*)(W + (size_t)(k0 + r) * Nd + n0 + c4);
    }
    __syncthreads();
#pragma unroll
    for (int p = 0; p < 4; ++p) {
        int c = tid + (p << 8);
        int n = c >> 4, k4 = (c & 15) << 2;
        if (which < 3) {
            unsigned short* Wt = (which == 0) ? Wqt : (which == 1) ? Wvt : Wot;
            short4v o;
#pragma unroll
            for (int j = 0; j < 4; ++j) o[j] = (short)f2bf(tile[k4 + j][n]);
            *(short4v*)(Wt + (size_t)(n0 + n) * Kd + k0 + k4) = o;
        } else {
            short4v oh, ol;
#pragma unroll
            for (int j = 0; j < 4; ++j) {
                float v = tile[k4 + j][n];
                unsigned short hb = f2bf(v);
                oh[j] = (short)hb;
                ol[j] = (short)f2bf(v - bf2f(hb));
            }
            *(short4v*)(Wkh + (size_t)(n0 + n) * Kd + k0 + k4) = oh;
            *(short4v*)(Wkl + (size_t)(n0 + n) * Kd + k0 + k4) = ol;
        }
    }
}

// ---------------------------------------------------------------------------
// bf16 MFMA GEMM (OUT projection), 512 thr, 128x128 tile, 1D XCD-swizzled
// grid of 256: blk%8 == m%8 -> A-panels L2-resident per XCD.
// ---------------------------------------------------------------------------
__global__ __launch_bounds__(512)
void gemm_bf16_k(const unsigned short* __restrict__ A,
                 const unsigned short* __restrict__ Bt,
                 const float* __restrict__ bias,
                 float* __restrict__ out,
                 int M, int N, int K)
{
    __shared__ __align__(16) unsigned short As[128][72];
    __shared__ __align__(16) unsigned short Bs[128][72];
    const int tid = threadIdx.x;
    const int lane = tid & 63, wave = tid >> 6;
    const int quad = lane >> 4, ln = lane & 15;
    const int mh = (wave >> 2) << 6;
    const int nh = (wave & 3) << 5;
    // decode: blk = (m%8) + 8*((m/8) + 4*n), m in [0,32), n in [0,8)
    const int blk = blockIdx.x;
    const int xcd = blk & 7, t2 = blk >> 3;
    const int m0 = ((t2 & 3) * 8 + xcd) * 128, n0 = (t2 >> 2) * 128;

    f32x4 acc[4][2];
#pragma unroll
    for (int i = 0; i < 4; ++i)
#pragma unroll
        for (int j = 0; j < 2; ++j) acc[i][j] = (f32x4){0.f, 0.f, 0.f, 0.f};

    short8 areg[2], breg[2];
#pragma unroll
    for (int p = 0; p < 2; ++p) {
        int c = tid + (p << 9);
        int row = c >> 3, col8 = (c & 7) << 3;
        areg[p] = *(const short8*)(A + (size_t)(m0 + row) * K + col8);
        breg[p] = *(const short8*)(Bt + (size_t)(n0 + row) * K + col8);
    }

    for (int k0 = 0; k0 < K; k0 += 64) {
        __syncthreads();
#pragma unroll
        for (int p = 0; p < 2; ++p) {
            int c = tid + (p << 9);
            int row = c >> 3, col8 = (c & 7) << 3;
            *(short8*)&As[row][col8] = areg[p];
            *(short8*)&Bs[row][col8] = breg[p];
        }
        __syncthreads();
        if (k0 + 64 < K) {
#pragma unroll
            for (int p = 0; p < 2; ++p) {
                int c = tid + (p << 9);
                int row = c >> 3, col8 = (c & 7) << 3;
                areg[p] = *(const short8*)(A + (size_t)(m0 + row) * K + k0 + 64 + col8);
                breg[p] = *(const short8*)(Bt + (size_t)(n0 + row) * K + k0 + 64 + col8);
            }
        }
#pragma unroll
        for (int ch = 0; ch < 2; ++ch) {
            short8 af[4], bf[2];
#pragma unroll
            for (int mt = 0; mt < 4; ++mt)
                af[mt] = *(const short8*)&As[mh + mt * 16 + ln][ch * 32 + quad * 8];
#pragma unroll
            for (int nt = 0; nt < 2; ++nt)
                bf[nt] = *(const short8*)&Bs[nh + nt * 16 + ln][ch * 32 + quad * 8];
#pragma unroll
            for (int mt = 0; mt < 4; ++mt)
#pragma unroll
                for (int nt = 0; nt < 2; ++nt)
                    acc[mt][nt] = __builtin_amdgcn_mfma_f32_16x16x32_bf16(
                        af[mt], bf[nt], acc[mt][nt], 0, 0, 0);
        }
    }

#pragma unroll
    for (int mt = 0; mt < 4; ++mt)
#pragma unroll
        for (int nt = 0; nt < 2; ++nt)
#pragma unroll
            for (int r = 0; r < 4; ++r) {
                int m = m0 + mh + mt * 16 + quad * 4 + r;
                int n = n0 + nh + nt * 16 + ln;
                out[(size_t)m * N + n] = acc[mt][nt][r] + bias[n];
            }
}

// ---------------------------------------------------------------------------
// Merged projections, XCD-swizzled: blocks [0,512) = QV (32m x 16n tiles,
// blk = m%8 + 8*(n + 16*(m/8))); blocks [512,768) = kproj (32m x 8n,
// sb = m%8 + 8*((m/8) + 4*n)). blk%8 == m%8 -> per-XCD A-panel residency.
// ---------------------------------------------------------------------------
__global__ __launch_bounds__(512)
void proj_qvk_k(const unsigned short* __restrict__ xh,
                const unsigned short* __restrict__ xl,
                const unsigned short* __restrict__ Wqt,
                const unsigned short* __restrict__ Wkh,
                const unsigned short* __restrict__ Wkl,
                unsigned short* __restrict__ qb,
                unsigned short* __restrict__ vb,
                unsigned short* __restrict__ vtout,
                unsigned short* __restrict__ kout,
                float* __restrict__ norms2)
{
    __shared__ __align__(16) unsigned short smem[36864];   // 73728 B
    const int blk = blockIdx.x;
    const int tid = threadIdx.x;
    const int lane = tid & 63, wave = tid >> 6;
    const int quad = lane >> 4, ln = lane & 15;
    const int K = DMODEL;

    if (blk < 512) {
        // ---------------- QV path ----------------
        unsigned short* As = smem;            // [128][72]
        unsigned short* Bs = smem + 9216;
        const int xcd = blk & 7, t2 = blk >> 3;      // t2 = n + 16*(m/8)
        const int m0 = ((t2 >> 4) * 8 + xcd) * 128;  // m in [0,32)
        const int n0 = (t2 & 15) * 128;              // n in [0,16)
        const int mh = (wave >> 2) << 6;
        const int nh = (wave & 3) << 5;

        f32x4 acc[4][2];
#pragma unroll
        for (int i = 0; i < 4; ++i)
#pragma unroll
            for (int j = 0; j < 2; ++j) acc[i][j] = (f32x4){0.f, 0.f, 0.f, 0.f};

        short8 areg[2], breg[2];
#pragma unroll
        for (int p = 0; p < 2; ++p) {
            int c = tid + (p << 9);
            int row = c >> 3, col8 = (c & 7) << 3;
            areg[p] = *(const short8*)(xh + (size_t)(m0 + row) * K + col8);
            breg[p] = *(const short8*)(Wqt + (size_t)(n0 + row) * K + col8);
        }

        for (int k0 = 0; k0 < K; k0 += 64) {
            __syncthreads();
#pragma unroll
            for (int p = 0; p < 2; ++p) {
                int c = tid + (p << 9);
                int row = c >> 3, col8 = (c & 7) << 3;
                *(short8*)&As[row * 72 + col8] = areg[p];
                *(short8*)&Bs[row * 72 + col8] = breg[p];
            }
            __syncthreads();
            if (k0 + 64 < K) {
#pragma unroll
                for (int p = 0; p < 2; ++p) {
                    int c = tid + (p << 9);
                    int row = c >> 3, col8 = (c & 7) << 3;
                    areg[p] = *(const short8*)(xh + (size_t)(m0 + row) * K + k0 + 64 + col8);
                    breg[p] = *(const short8*)(Wqt + (size_t)(n0 + row) * K + k0 + 64 + col8);
                }
            }
#pragma unroll
            for (int ch = 0; ch < 2; ++ch) {
                short8 af[4], bf[2];
#pragma unroll
                for (int mt = 0; mt < 4; ++mt)
                    af[mt] = *(const short8*)&As[(mh + mt * 16 + ln) * 72 + ch * 32 + quad * 8];
#pragma unroll
                for (int nt = 0; nt < 2; ++nt)
                    bf[nt] = *(const short8*)&Bs[(nh + nt * 16 + ln) * 72 + ch * 32 + quad * 8];
#pragma unroll
                for (int mt = 0; mt < 4; ++mt)
#pragma unroll
                    for (int nt = 0; nt < 2; ++nt)
                        acc[mt][nt] = __builtin_amdgcn_mfma_f32_16x16x32_bf16(
                            af[mt], bf[nt], acc[mt][nt], 0, 0, 0);
            }
        }

#pragma unroll
        for (int mt = 0; mt < 4; ++mt)
#pragma unroll
            for (int nt = 0; nt < 2; ++nt) {
                int n = n0 + nh + nt * 16 + ln;
                int mb = m0 + mh + mt * 16 + quad * 4;
                int b = mb >> 11, s0 = mb & (SEQ - 1);
                int d = n & 63;
                if (n < DMODEL) {           // Q, pre-scaled incl. log2(e)
                    int h = n >> 6;
                    unsigned short* qp_ =
                        qb + ((size_t)(b * NH + h) * SEQ + s0) * DHEAD + d;
#pragma unroll
                    for (int r = 0; r < 4; ++r)
                        qp_[(size_t)r * DHEAD] = f2bf(acc[mt][nt][r] * 0.18033688f);
                } else {                    // V: row-major + transposed
                    int h = (n >> 6) - NH;
                    unsigned short* vp_ =
                        vb + ((size_t)(b * NH + h) * SEQ + s0) * DHEAD + d;
                    short4v tv;
#pragma unroll
                    for (int r = 0; r < 4; ++r) {
                        unsigned short bv = f2bf(acc[mt][nt][r]);
                        vp_[(size_t)r * DHEAD] = bv;
                        tv[r] = (short)bv;
                    }
                    *(short4v*)(vtout + ((size_t)(b * NH + h) * DHEAD + d) * SEQ + s0) = tv;
                }
            }
    } else {
        // ---------------- kproj path (compensated, M2xN4) ----------------
        unsigned short* Ah = smem;            // [128][72] each
        unsigned short* Al = smem + 9216;
        unsigned short* Bh = smem + 18432;
        unsigned short* Bl = smem + 27648;
        const int sb = blk - 512;
        const int xcd = sb & 7, t2 = sb >> 3;        // t2 = (m/8) + 4*n
        const int m0 = ((t2 & 3) * 8 + xcd) * 128;   // m in [0,32)
        const int n0 = (t2 >> 2) * 128;              // n in [0,8)
        const int mh = (wave >> 1) << 5;      // 4 m-groups x 32 rows
        const int nh = (wave & 1) << 6;       // 2 n-groups x 64 cols

        f32x4 acc[2][4];
#pragma unroll
        for (int i = 0; i < 2; ++i)
#pragma unroll
            for (int j = 0; j < 4; ++j) acc[i][j] = (f32x4){0.f, 0.f, 0.f, 0.f};

        short8 ahreg[2], alreg[2], bhreg[2], blreg[2];
#pragma unroll
        for (int p = 0; p < 2; ++p) {
            int c = tid + (p << 9);
            int row = c >> 3, col8 = (c & 7) << 3;
            size_t ga = (size_t)(m0 + row) * K + col8;
            size_t gb = (size_t)(n0 + row) * K + col8;
            ahreg[p] = *(const short8*)(xh + ga);
            alreg[p] = *(const short8*)(xl + ga);
            bhreg[p] = *(const short8*)(Wkh + gb);
            blreg[p] = *(const short8*)(Wkl + gb);
        }

        for (int k0 = 0; k0 < K; k0 += 64) {
            __syncthreads();
#pragma unroll
            for (int p = 0; p < 2; ++p) {
                int c = tid + (p << 9);
                int row = c >> 3, col8 = (c & 7) << 3;
                *(short8*)&Ah[row * 72 + col8] = ahreg[p];
                *(short8*)&Al[row * 72 + col8] = alreg[p];
                *(short8*)&Bh[row * 72 + col8] = bhreg[p];
                *(short8*)&Bl[row * 72 + col8] = blreg[p];
            }
            __syncthreads();
            if (k0 + 64 < K) {
#pragma unroll
                for (int p = 0; p < 2; ++p) {
                    int c = tid + (p << 9);
                    int row = c >> 3, col8 = (c & 7) << 3;
                    size_t ga = (size_t)(m0 + row) * K + k0 + 64 + col8;
                    size_t gb = (size_t)(n0 + row) * K + k0 + 64 + col8;
                    ahreg[p] = *(const short8*)(xh + ga);
                    alreg[p] = *(const short8*)(xl + ga);
                    bhreg[p] = *(const short8*)(Wkh + gb);
                    blreg[p] = *(const short8*)(Wkl + gb);
                }
            }
#pragma unroll
            for (int ch = 0; ch < 2; ++ch) {
                short8 afh[2], afl[2];
#pragma unroll
                for (int mt = 0; mt < 2; ++mt) {
                    afh[mt] = *(const short8*)&Ah[(mh + mt * 16 + ln) * 72 + ch * 32 + quad * 8];
                    afl[mt] = *(const short8*)&Al[(mh + mt * 16 + ln) * 72 + ch * 32 + quad * 8];
                }
#pragma unroll
                for (int nt = 0; nt < 4; ++nt) {
                    short8 bfh = *(const short8*)&Bh[(nh + nt * 16 + ln) * 72 + ch * 32 + quad * 8];
                    short8 bfl = *(const short8*)&Bl[(nh + nt * 16 + ln) * 72 + ch * 32 + quad * 8];
#pragma unroll
                    for (int mt = 0; mt < 2; ++mt) {
                        acc[mt][nt] = __builtin_amdgcn_mfma_f32_16x16x32_bf16(afh[mt], bfh, acc[mt][nt], 0, 0, 0);
                        acc[mt][nt] = __builtin_amdgcn_mfma_f32_16x16x32_bf16(afh[mt], bfl, acc[mt][nt], 0, 0, 0);
                        acc[mt][nt] = __builtin_amdgcn_mfma_f32_16x16x32_bf16(afl[mt], bfh, acc[mt][nt], 0, 0, 0);
                    }
                }
            }
        }

        const int h = (n0 + nh) >> 6;
#pragma unroll
        for (int mt = 0; mt < 2; ++mt)
#pragma unroll
            for (int r = 0; r < 4; ++r) {
                int m = m0 + mh + mt * 16 + quad * 4 + r;
                int b = m >> 11, s = m & (SEQ - 1);
                size_t rowbase = ((size_t)(b * NH + h) * SEQ + s) * DHEAD;
#pragma unroll
                for (int nt = 0; nt < 4; ++nt)
                    kout[rowbase + nt * 16 + ln] = f2bf(acc[mt][nt][r]);
                float s2 = acc[mt][0][r] * acc[mt][0][r] + acc[mt][1][r] * acc[mt][1][r] +
                           acc[mt][2][r] * acc[mt][2][r] + acc[mt][3][r] * acc[mt][3][r];
#pragma unroll
                for (int off = 1; off <= 8; off <<= 1)
                    s2 += __shfl_xor(s2, off);
                if (ln == 0)
                    norms2[(size_t)(b * NH + h) * SEQ + s] = s2;
            }
    }
}

// ---------------------------------------------------------------------------
// topk + gather fused, 1024 threads (2 CE/thread over 66 bitonic stages).
// ---------------------------------------------------------------------------
__global__ __launch_bounds__(1024)
void topk_gather_k(const float* __restrict__ norms2,
                   const unsigned short* __restrict__ k,
                   const unsigned short* __restrict__ v,
                   unsigned short* __restrict__ gk,
                   unsigned short* __restrict__ gvt)
{
    __shared__ unsigned long long keys[SEQ];
    __shared__ int tix[NGPAD];
    __shared__ __align__(16) unsigned short T[64][72];
    const int bh = blockIdx.x;
    const int tid = threadIdx.x;
    const float* nb = norms2 + (size_t)bh * SEQ;
    const size_t base = (size_t)bh * SEQ * DHEAD;

    for (int i = tid; i < SEQ; i += 1024) {
        float nrm = sqrtf(nb[i]);
        keys[i] = ((unsigned long long)__float_as_uint(nrm) << 32) |
                  (unsigned int)(0xFFFFFFFFu - (unsigned int)i);
    }
    __syncthreads();
    for (int kk = 2; kk <= SEQ; kk <<= 1) {
        for (int j = kk >> 1; j > 0; j >>= 1) {
            for (int i = tid; i < SEQ; i += 1024) {
                int ixj = i ^ j;
                if (ixj > i) {
                    unsigned long long a = keys[i], b = keys[ixj];
                    bool up = ((i & kk) == 0);
                    if ((a > b) == up) { keys[i] = b; keys[ixj] = a; }
                }
            }
            __syncthreads();
        }
    }
    if (tid < NGPAD) {
        tix[tid] = (tid < NG)
            ? (int)(0xFFFFFFFFu - (unsigned int)(keys[SEQ - 1 - tid] & 0xFFFFFFFFu))
            : 0;
    }
    __syncthreads();

    for (int t = 0; t < NGPAD / 64; ++t) {
        {
            int row = tid >> 4, col4 = (tid & 15) << 2;   // 64 rows x 64 cols
            int g = t * 64 + row;
            short4v kv = (short4v)0, vv = (short4v)0;
            if (g < NG) {
                int sidx = tix[g];
                kv = *(const short4v*)(k + base + (size_t)sidx * DHEAD + col4);
                vv = *(const short4v*)(v + base + (size_t)sidx * DHEAD + col4);
            }
            *(short4v*)(gk + ((size_t)bh * NGPAD + g) * DHEAD + col4) = kv;
            *(short4v*)&T[row][col4] = vv;
        }
        __syncthreads();
        {
            int d = tid >> 4, k4 = (tid & 15) << 2;
            short4v o;
#pragma unroll
            for (int i = 0; i < 4; ++i) o[i] = (short)T[k4 + i][d];
            *(short4v*)(gvt + ((size_t)bh * DHEAD + d) * NGPAD + t * 64 + k4) = o;
        }
        __syncthreads();
    }
}

// ---------------------------------------------------------------------------
// Fused attention (r17, unchanged): 256 thr, 4 waves x 32 q-rows, swapped
// QK^T, P in registers as mfma32 A-frags via phi K-row permutation; K/V
// double-buffered, one barrier per tile; row-sums via ones-MFMA.
// ---------------------------------------------------------------------------
__global__ __launch_bounds__(256, 2)
void attn_fused_k(const unsigned short* __restrict__ qb,
                  const unsigned short* __restrict__ kb,
                  const unsigned short* __restrict__ vt,
                  const unsigned short* __restrict__ gk,
                  const unsigned short* __restrict__ gvt,
                  const unsigned short* __restrict__ Wgt,
                  const float* __restrict__ gamma,
                  const float* __restrict__ beta,
                  const float* __restrict__ bg,
                  unsigned short* __restrict__ fused)
{
    // smem layout (shorts): [0,9216) Ks[2][64][72]  (= Ps[128][72] alias)
    //                       [9216,18432) Vt[2][64][72]
    //                       [18432,27136) Wgs[64][136]
    __shared__ __align__(16) unsigned short smem[27136];
    unsigned short* const KsB = smem;
    unsigned short* const VtB = smem + 9216;
    unsigned short (*Ps)[72]  = (unsigned short (*)[72])smem;
    unsigned short (*Wgs)[136] = (unsigned short (*)[136])(smem + 18432);

    const int flat = blockIdx.x;
    const int bh = ((flat >> 7) << 3) | (flat & 7);   // flat%8 == bh%8 (XCD)
    const int q0 = ((flat >> 3) & 15) * 128;
    const int tid = threadIdx.x;
    const int lane = tid & 63, wave = tid >> 6;       // 4 waves
    const int quad = lane >> 4, ln = lane & 15;
    const size_t base = (size_t)bh * SEQ * DHEAD;
    const unsigned short* gkb = gk + (size_t)bh * NGPAD * DHEAD;
    const unsigned short* gvb = gvt + (size_t)bh * DHEAD * NGPAD;

    // stage Wg^T (read only in epilogue; first barrier covers it)
#pragma unroll
    for (int p = 0; p < 4; ++p) {
        int idx = tid + (p << 8);
        *(short8*)&Wgs[idx >> 4][(idx & 15) << 3] = *(const short8*)(Wgt + idx * 8);
    }

    short8 qf[2][2];
#pragma unroll
    for (int mt = 0; mt < 2; ++mt) {
        const unsigned short* qp = qb + base + (size_t)(q0 + wave * 32 + mt * 16 + ln) * DHEAD;
        qf[mt][0] = *(const short8*)(qp + quad * 8);
        qf[mt][1] = *(const short8*)(qp + 32 + quad * 8);
    }

    // ones / last-tile-mask B-frags for row-sum MFMAs
    short8 onesv, maskv;
#pragma unroll
    for (int j = 0; j < 8; ++j) {
        onesv[j] = (short)0x3F80;                              // bf16 1.0
        maskv[j] = (short)((quad * 8 + j) < 12 ? 0x3F80 : 0);  // NG-192=12
    }

    f32x4 O[2][4], Og[2][4], lsacc[2], lgacc[2];
#pragma unroll
    for (int mt = 0; mt < 2; ++mt) {
#pragma unroll
        for (int nt = 0; nt < 4; ++nt) {
            O[mt][nt] = (f32x4){0.f, 0.f, 0.f, 0.f};
            Og[mt][nt] = (f32x4){0.f, 0.f, 0.f, 0.f};
        }
        lsacc[mt] = (f32x4){0.f, 0.f, 0.f, 0.f};
        lgacc[mt] = (f32x4){0.f, 0.f, 0.f, 0.f};
    }

    short8 kreg[2], vreg[2];
    int srow[2], scol8[2], psrow[2];
#pragma unroll
    for (int p = 0; p < 2; ++p) {
        int idx = tid + (p << 8);
        srow[p] = idx >> 3;
        scol8[p] = (idx & 7) << 3;
        // phi: [b5 | b3 b2 | b4 | b1 b0]  (K-row permutation, verified r14)
        psrow[p] = (srow[p] & 0x20) | ((srow[p] & 0x0C) << 1) |
                   ((srow[p] & 0x10) >> 2) | (srow[p] & 3);
    }

    auto loadT = [&](int i) {
#pragma unroll
        for (int p = 0; p < 2; ++p) {
            if (i < 32) {
                kreg[p] = *(const short8*)(kb + base + (size_t)(i * 64 + psrow[p]) * DHEAD + scol8[p]);
                vreg[p] = *(const short8*)(vt + base + (size_t)srow[p] * SEQ + i * 64 + scol8[p]);
            } else {
                int g = i - 32;
                kreg[p] = *(const short8*)(gkb + (size_t)(g * 64 + psrow[p]) * DHEAD + scol8[p]);
                vreg[p] = *(const short8*)(gvb + (size_t)srow[p] * NGPAD + g * 64 + scol8[p]);
            }
        }
    };
    auto storeT = [&](int buf) {
        unsigned short* kd = KsB + buf * 4608;
        unsigned short* vd = VtB + buf * 4608;
#pragma unroll
        for (int p = 0; p < 2; ++p) {
            *(short8*)&kd[srow[p] * 72 + scol8[p]] = kreg[p];
            *(short8*)&vd[srow[p] * 72 + scol8[p]] = vreg[p];
        }
    };

    loadT(0);
    storeT(0);
    loadT(1);
    __syncthreads();

    // ---- local: 32 tiles ----
    for (int t = 0; t < 32; ++t) {
        const int cur = t & 1;
        const unsigned short* Kc = KsB + cur * 4608;
        const unsigned short* Vc = VtB + cur * 4608;

        // swapped QK^T: lane holds S^T[k_phys = phi(nt*16+quad*4+r)][q=ln]
        f32x4 s[2][4];
#pragma unroll
        for (int mt = 0; mt < 2; ++mt)
#pragma unroll
            for (int nt = 0; nt < 4; ++nt) s[mt][nt] = (f32x4){0.f, 0.f, 0.f, 0.f};
        __builtin_amdgcn_s_setprio(1);
#pragma unroll
        for (int nt = 0; nt < 4; ++nt) {
            short8 kf0 = *(const short8*)&Kc[(nt * 16 + ln) * 72 + quad * 8];
            short8 kf1 = *(const short8*)&Kc[(nt * 16 + ln) * 72 + 32 + quad * 8];
#pragma unroll
            for (int mt = 0; mt < 2; ++mt) {
                s[mt][nt] = __builtin_amdgcn_mfma_f32_16x16x32_bf16(kf0, qf[mt][0], s[mt][nt], 0, 0, 0);
                s[mt][nt] = __builtin_amdgcn_mfma_f32_16x16x32_bf16(kf1, qf[mt][1], s[mt][nt], 0, 0, 0);
            }
        }
        __builtin_amdgcn_s_setprio(0);

        // exp + pack into mfma32 A-frags: pf8[mt][c] = k_phys c*32+quad*8+[0..7]
        short8 pf8[2][2];
#pragma unroll
        for (int mt = 0; mt < 2; ++mt)
#pragma unroll
            for (int nt = 0; nt < 4; ++nt)
#pragma unroll
                for (int r = 0; r < 4; ++r) {
                    unsigned int u = __float_as_uint(__builtin_amdgcn_exp2f(s[mt][nt][r]));
                    pf8[mt][nt >> 1][((nt & 1) << 2) | r] = (short)(u >> 16);
                }

        // PV + row-sum: full-rate mfma32, P from registers
        __builtin_amdgcn_s_setprio(1);
#pragma unroll
        for (int dt = 0; dt < 4; ++dt)
#pragma unroll
            for (int c = 0; c < 2; ++c) {
                short8 vf = *(const short8*)&Vc[(dt * 16 + ln) * 72 + c * 32 + quad * 8];
#pragma unroll
                for (int mt = 0; mt < 2; ++mt)
                    O[mt][dt] = __builtin_amdgcn_mfma_f32_16x16x32_bf16(
                        pf8[mt][c], vf, O[mt][dt], 0, 0, 0);
            }
#pragma unroll
        for (int c = 0; c < 2; ++c)
#pragma unroll
            for (int mt = 0; mt < 2; ++mt)
                lsacc[mt] = __builtin_amdgcn_mfma_f32_16x16x32_bf16(
                    pf8[mt][c], onesv, lsacc[mt], 0, 0, 0);
        __builtin_amdgcn_s_setprio(0);

        storeT(cur ^ 1);            // tile t+1 -> other buffer
        if (t + 2 <= 35) loadT(t + 2);
        __syncthreads();
    }

    // ---- global: 4 gathered tiles (padded rows: K=0 -> P=1, V=0; mask
    //      excludes them from lgacc; tiles 0-2 fully valid) ----
    for (int tg = 0; tg < 4; ++tg) {
        const int t = 32 + tg;
        const int cur = t & 1;
        const unsigned short* Kc = KsB + cur * 4608;
        const unsigned short* Vc = VtB + cur * 4608;

        f32x4 s[2][4];
#pragma unroll
        for (int mt = 0; mt < 2; ++mt)
#pragma unroll
            for (int nt = 0; nt < 4; ++nt) s[mt][nt] = (f32x4){0.f, 0.f, 0.f, 0.f};
        __builtin_amdgcn_s_setprio(1);
#pragma unroll
        for (int nt = 0; nt < 4; ++nt) {
            short8 kf0 = *(const short8*)&Kc[(nt * 16 + ln) * 72 + quad * 8];
            short8 kf1 = *(const short8*)&Kc[(nt * 16 + ln) * 72 + 32 + quad * 8];
#pragma unroll
            for (int mt = 0; mt < 2; ++mt) {
                s[mt][nt] = __builtin_amdgcn_mfma_f32_16x16x32_bf16(kf0, qf[mt][0], s[mt][nt], 0, 0, 0);
                s[mt][nt] = __builtin_amdgcn_mfma_f32_16x16x32_bf16(kf1, qf[mt][1], s[mt][nt], 0, 0, 0);
            }
        }
        __builtin_amdgcn_s_setprio(0);

        short8 pf8[2][2];
#pragma unroll
        for (int mt = 0; mt < 2; ++mt)
#pragma unroll
            for (int nt = 0; nt < 4; ++nt)
#pragma unroll
                for (int r = 0; r < 4; ++r) {
                    unsigned int u = __float_as_uint(__builtin_amdgcn_exp2f(s[mt][nt][r]));
                    pf8[mt][nt >> 1][((nt & 1) << 2) | r] = (short)(u >> 16);
                }

        __builtin_amdgcn_s_setprio(1);
#pragma unroll
        for (int dt = 0; dt < 4; ++dt)
#pragma unroll
            for (int c = 0; c < 2; ++c) {
                short8 vf = *(const short8*)&Vc[(dt * 16 + ln) * 72 + c * 32 + quad * 8];
#pragma unroll
                for (int mt = 0; mt < 2; ++mt)
                    Og[mt][dt] = __builtin_amdgcn_mfma_f32_16x16x32_bf16(
                        pf8[mt][c], vf, Og[mt][dt], 0, 0, 0);
            }
        if (tg < 3) {
#pragma unroll
            for (int c = 0; c < 2; ++c)
#pragma unroll
                for (int mt = 0; mt < 2; ++mt)
                    lgacc[mt] = __builtin_amdgcn_mfma_f32_16x16x32_bf16(
                        pf8[mt][c], onesv, lgacc[mt], 0, 0, 0);
        } else {
            // last tile: only k_phys < 12 valid (c=0 chunk), via maskv
#pragma unroll
            for (int mt = 0; mt < 2; ++mt)
                lgacc[mt] = __builtin_amdgcn_mfma_f32_16x16x32_bf16(
                    pf8[mt][0], maskv, lgacc[mt], 0, 0, 0);
        }
        __builtin_amdgcn_s_setprio(0);

        if (t < 35) storeT(cur ^ 1);
        if (t + 2 <= 35) loadT(t + 2);
        __syncthreads();            // last iter: protects Ps alias in epilogue
    }

    // ---- row sums already in O layout (q = quad*4+r) ----
    float invl[2][4], invg[2][4];
#pragma unroll
    for (int mt = 0; mt < 2; ++mt)
#pragma unroll
        for (int r = 0; r < 4; ++r) {
            invl[mt][r] = 1.f / lsacc[mt][r];
            invg[mt][r] = 1.f / lgacc[mt][r];
        }

    // ---- layernorm(global) ----
    float xs[2][4][4];
#pragma unroll
    for (int mt = 0; mt < 2; ++mt)
#pragma unroll
        for (int r = 0; r < 4; ++r) {
            float inv = invg[mt][r];
#pragma unroll
            for (int nt = 0; nt < 4; ++nt) xs[mt][nt][r] = Og[mt][nt][r] * inv;
        }
    float mu[2][4], rsd[2][4];
#pragma unroll
    for (int mt = 0; mt < 2; ++mt)
#pragma unroll
        for (int r = 0; r < 4; ++r) {
            float sm = xs[mt][0][r] + xs[mt][1][r] + xs[mt][2][r] + xs[mt][3][r];
#pragma unroll
            for (int off = 1; off <= 8; off <<= 1) sm += __shfl_xor(sm, off);
            mu[mt][r] = sm * (1.f / 64.f);
        }
#pragma unroll
    for (int mt = 0; mt < 2; ++mt)
#pragma unroll
        for (int r = 0; r < 4; ++r) {
            float sv = 0.f;
#pragma unroll
            for (int nt = 0; nt < 4; ++nt) {
                float d = xs[mt][nt][r] - mu[mt][r];
                sv += d * d;
            }
#pragma unroll
            for (int off = 1; off <= 8; off <<= 1) sv += __shfl_xor(sv, off);
            rsd[mt][r] = rsqrtf(sv * (1.f / 64.f) + LNEPS);
        }
#pragma unroll
    for (int nt = 0; nt < 4; ++nt) {
        float g = gamma[nt * 16 + ln], bb = beta[nt * 16 + ln];
#pragma unroll
        for (int mt = 0; mt < 2; ++mt)
#pragma unroll
            for (int r = 0; r < 4; ++r)
                xs[mt][nt][r] = (xs[mt][nt][r] - mu[mt][r]) * rsd[mt][r] * g + bb;
    }

    // ---- gate via MFMA (2 passes through Ps; intra-wave rows, no barrier) --
    float lf[2][4][4];
#pragma unroll
    for (int mt = 0; mt < 2; ++mt)
#pragma unroll
        for (int nt = 0; nt < 4; ++nt)
#pragma unroll
            for (int r = 0; r < 4; ++r) {
                lf[mt][nt][r] = O[mt][nt][r] * invl[mt][r];
                Ps[wave * 32 + mt * 16 + quad * 4 + r][nt * 16 + ln] = f2bf(lf[mt][nt][r]);
            }
    f32x4 gacc[2][4];
#pragma unroll
    for (int ng = 0; ng < 4; ++ng) {
        float bgv = bg[ng * 16 + ln];
#pragma unroll
        for (int mt = 0; mt < 2; ++mt)
            gacc[mt][ng] = (f32x4){bgv, bgv, bgv, bgv};
    }
#pragma unroll
    for (int ch = 0; ch < 2; ++ch) {
        short8 af[2];
#pragma unroll
        for (int mt = 0; mt < 2; ++mt)
            af[mt] = *(const short8*)&Ps[wave * 32 + mt * 16 + ln][ch * 32 + quad * 8];
#pragma unroll
        for (int ng = 0; ng < 4; ++ng) {
            short8 bf = *(const short8*)&Wgs[ng * 16 + ln][ch * 32 + quad * 8];
#pragma unroll
            for (int mt = 0; mt < 2; ++mt)
                gacc[mt][ng] = __builtin_amdgcn_mfma_f32_16x16x32_bf16(af[mt], bf, gacc[mt][ng], 0, 0, 0);
        }
    }
#pragma unroll
    for (int mt = 0; mt < 2; ++mt)
#pragma unroll
        for (int nt = 0; nt < 4; ++nt)
#pragma unroll
            for (int r = 0; r < 4; ++r)
                Ps[wave * 32 + mt * 16 + quad * 4 + r][nt * 16 + ln] = f2bf(xs[mt][nt][r]);
#pragma unroll
    for (int ch = 0; ch < 2; ++ch) {
        short8 af[2];
#pragma unroll
        for (int mt = 0; mt < 2; ++mt)
            af[mt] = *(const short8*)&Ps[wave * 32 + mt * 16 + ln][ch * 32 + quad * 8];
#pragma unroll
        for (int ng = 0; ng < 4; ++ng) {
            short8 bf = *(const short8*)&Wgs[ng * 16 + ln][64 + ch * 32 + quad * 8];
#pragma unroll
            for (int mt = 0; mt < 2; ++mt)
                gacc[mt][ng] = __builtin_amdgcn_mfma_f32_16x16x32_bf16(af[mt], bf, gacc[mt][ng], 0, 0, 0);
        }
    }

    // ---- fuse + store ----
    const int b = bh >> 4, h = bh & 15;
#pragma unroll
    for (int mt = 0; mt < 2; ++mt)
#pragma unroll
        for (int ng = 0; ng < 4; ++ng)
#pragma unroll
            for (int r = 0; r < 4; ++r) {
                float gt = 1.f / (1.f + __expf(-gacc[mt][ng][r]));
                float f = gt * lf[mt][ng][r] + (1.f - gt) * xs[mt][ng][r];
                int s = q0 + wave * 32 + mt * 16 + quad * 4 + r;
                fused[((size_t)(b * SEQ + s)) * DMODEL + h * DHEAD + ng * 16 + ln] = f2bf(f);
            }
}

// ---------------------------------------------------------------------------
extern "C" void kernel_launch(void* const* d_in, const int* in_sizes, int n_in,
                              void* d_out, int out_size, void* d_ws, size_t ws_size,
                              hipStream_t stream)
{
    (void)in_sizes; (void)n_in; (void)out_size; (void)ws_size;
    const float* x    = (const float*)d_in[0];
    const float* Wq   = (const float*)d_in[1];
    const float* Wk   = (const float*)d_in[2];
    const float* Wv   = (const float*)d_in[3];
    const float* Wo   = (const float*)d_in[4];
    const float* bo   = (const float*)d_in[5];
    const float* ln_g = (const float*)d_in[6];
    const float* ln_b = (const float*)d_in[7];
    const float* Wg   = (const float*)d_in[8];
    const float* bg   = (const float*)d_in[9];

    char* w = (char*)d_ws;
    const size_t MB = 1024ull * 1024ull;
    unsigned short* kb16  = (unsigned short*)(w);
    unsigned short* qb16  = (unsigned short*)(w + 8 * MB);
    unsigned short* vb16  = (unsigned short*)(w + 16 * MB);
    unsigned short* vt16  = (unsigned short*)(w + 24 * MB);
    unsigned short* xh    = (unsigned short*)(w + 32 * MB);
    unsigned short* xl    = (unsigned short*)(w + 40 * MB);
    unsigned short* Wqt   = (unsigned short*)(w + 48 * MB);
    unsigned short* Wvt   = (unsigned short*)(w + 50 * MB);   // contiguous after Wqt
    unsigned short* Wot   = (unsigned short*)(w + 52 * MB);
    unsigned short* Wkh   = (unsigned short*)(w + 54 * MB);
    unsigned short* Wkl   = (unsigned short*)(w + 56 * MB);
    unsigned short* Wgt   = (unsigned short*)(w + 58 * MB);
    float*          norms2= (float*)(w + 59 * MB);
    unsigned short* gk16  = (unsigned short*)(w + 60 * MB);
    unsigned short* gvt16 = (unsigned short*)(w + 61 * MB);
    unsigned short* fusedb = xh;   // xh dead after projections
    (void)Wvt;

    const int M = 4096, N = 1024, K = 1024;

    prep_k<<<3073, 256, 0, stream>>>(x, Wq, Wv, Wo, Wk, Wg,
                                     xh, xl, Wqt, Wvt, Wot, Wkh, Wkl, Wgt);

    proj_qvk_k<<<768, 512, 0, stream>>>(xh, xl, Wqt, Wkh, Wkl,
                                        qb16, vb16, vt16, kb16, norms2);

    topk_gather_k<<<BHT, 1024, 0, stream>>>(norms2, kb16, vb16, gk16, gvt16);

    attn_fused_k<<<512, 256, 0, stream>>>(qb16, kb16, vt16, gk16, gvt16, Wgt,
                                          ln_g, ln_b, bg, fusedb);

    gemm_bf16_k<<<256, 512, 0, stream>>>(fusedb, Wot, bo, (float*)d_out,
                                         M, N, K);
}

// Round 10
// 243.379 us; speedup vs baseline: 1.6317x; 1.0008x over previous
//
#include <hip/hip_runtime.h>

// SegmentedAttention round 19 = r18 + occupancy push on proj & attn.
// r18: proj 63us unchanged despite FETCH 103->50MB -> latency-bound
// (MFMA 27% = the 17us floor, occupancy 28%). Fix A: kproj path -> BK=32,
// 4x[128][40] tiles (pad 40 keeps b128 16B-align; 80B stride = 2-way =
// free); proj LDS union 73728 -> 40960B = exactly 4 blk/CU. Fix B: attn
// drops Wgs LDS staging (gate reads Wgt direct from global, r14-verified
// path); attn LDS 54272 -> 36864B -> 4 blk/CU (VGPR 120 <= 128, no
// launch_bounds cap per r14 lesson).
// ws (MB): kb16@0(8) qb16@8(8) vb16@16(8) vt16@24(8) xh@32(8,=fusedb)
//   xl@40(8) Wqt@48(2) Wvt@50(2) Wot@52(2) Wkh@54(2) Wkl@56(2) Wgt@58(1)
//   norms2@59(1) gk@60(1) gvt@61(1) -> 62MB

constexpr int SEQ    = 2048;
constexpr int DMODEL = 1024;
constexpr int NH     = 16;
constexpr int DHEAD  = 64;
constexpr int BHT    = 32;
constexpr int NG     = 204;
constexpr int NGPAD  = 256;
constexpr float LNEPS = 1e-5f;

typedef __attribute__((ext_vector_type(8))) short short8;
typedef __attribute__((ext_vector_type(4))) short short4v;
typedef __attribute__((ext_vector_type(4))) float f32x4;

__device__ __forceinline__ unsigned short f2bf(float f) {
    unsigned int u = __float_as_uint(f);
    u += 0x7FFFu + ((u >> 16) & 1u);
    return (unsigned short)(u >> 16);
}
__device__ __forceinline__ float bf2f(unsigned short b) {
    return __uint_as_float(((unsigned int)b) << 16);
}

// ---------------------------------------------------------------------------
// prep: blocks [0,2048): x hilo split; [2048,3072): weight transposes;
// block 3072: Wg^T bf16.
// ---------------------------------------------------------------------------
__global__ __launch_bounds__(256)
void prep_k(const float* __restrict__ x,
            const float* __restrict__ Wq, const float* __restrict__ Wv,
            const float* __restrict__ Wo, const float* __restrict__ Wk,
            const float* __restrict__ Wg,
            unsigned short* __restrict__ xh, unsigned short* __restrict__ xl,
            unsigned short* __restrict__ Wqt, unsigned short* __restrict__ Wvt,
            unsigned short* __restrict__ Wot, unsigned short* __restrict__ Wkh,
            unsigned short* __restrict__ Wkl, unsigned short* __restrict__ Wgt)
{
    const int bid = blockIdx.x;
    const int tid = threadIdx.x;

    if (bid < 2048) {
        int i = (bid * 256 + tid) << 3;
        short8 h, l;
#pragma unroll
        for (int j = 0; j < 8; ++j) {
            float v = x[i + j];
            unsigned short hb = f2bf(v);
            h[j] = (short)hb;
            l[j] = (short)f2bf(v - bf2f(hb));
        }
        *(short8*)(xh + i) = h;
        *(short8*)(xl + i) = l;
        return;
    }
    if (bid == 3072) {
#pragma unroll
        for (int i = 0; i < 32; ++i) {
            int o = tid * 32 + i;
            int dg = o >> 7, jj = o & 127;
            Wgt[o] = f2bf(Wg[jj * 64 + dg]);
        }
        return;
    }

    __shared__ float tile[64][68];
    const int sub = bid - 2048;
    const int which = sub >> 8;             // 0:Wq 1:Wv 2:Wo 3:Wk
    const int b = sub & 255;
    const int n0 = (b & 15) * 64, k0 = (b >> 4) * 64;
    const float* W = (which == 0) ? Wq : (which == 1) ? Wv : (which == 2) ? Wo : Wk;
    const int Kd = DMODEL, Nd = DMODEL;

#pragma unroll
    for (int p = 0; p < 4; ++p) {
        int c = tid + (p << 8);
        int r = c >> 4, c4 = (c & 15) << 2;
        *(float4*)&tile[r][c4] = *(const float4*)(W + (size_t)(k0 + r) * Nd + n0 + c4);
    }
    __syncthreads();
#pragma unroll
    for (int p = 0; p < 4; ++p) {
        int c = tid + (p << 8);
        int n = c >> 4, k4 = (c & 15) << 2;
        if (which < 3) {
            unsigned short* Wt = (which == 0) ? Wqt : (which == 1) ? Wvt : Wot;
            short4v o;
#pragma unroll
            for (int j = 0; j < 4; ++j) o[j] = (short)f2bf(tile[k4 + j][n]);
            *(short4v*)(Wt + (size_t)(n0 + n) * Kd + k0 + k4) = o;
        } else {
            short4v oh, ol;
#pragma unroll
            for (int j = 0; j < 4; ++j) {
                float v = tile[k4 + j][n];
                unsigned short hb = f2bf(v);
                oh[j] = (short)hb;
                ol[j] = (short)f2bf(v - bf2f(hb));
            }
            *(short4v*)(Wkh + (size_t)(n0 + n) * Kd + k0 + k4) = oh;
            *(short4v*)(Wkl + (size_t)(n0 + n) * Kd + k0 + k4) = ol;
        }
    }
}

// ---------------------------------------------------------------------------
// bf16 MFMA GEMM (OUT projection), 512 thr, 128x128 tile, 1D XCD-swizzled
// grid of 256: blk%8 == m%8 -> A-panels L2-resident per XCD.
// ---------------------------------------------------------------------------
__global__ __launch_bounds__(512)
void gemm_bf16_k(const unsigned short* __restrict__ A,
                 const unsigned short* __restrict__ Bt,
                 const float* __restrict__ bias,
                 float* __restrict__ out,
                 int M, int N, int K)
{
    __shared__ __align__(16) unsigned short As[128][72];
    __shared__ __align__(16) unsigned short Bs[128][72];
    const int tid = threadIdx.x;
    const int lane = tid & 63, wave = tid >> 6;
    const int quad = lane >> 4, ln = lane & 15;
    const int mh = (wave >> 2) << 6;
    const int nh = (wave & 3) << 5;
    // decode: blk = (m%8) + 8*((m/8) + 4*n), m in [0,32), n in [0,8)
    const int blk = blockIdx.x;
    const int xcd = blk & 7, t2 = blk >> 3;
    const int m0 = ((t2 & 3) * 8 + xcd) * 128, n0 = (t2 >> 2) * 128;

    f32x4 acc[4][2];
#pragma unroll
    for (int i = 0; i < 4; ++i)
#pragma unroll
        for (int j = 0; j < 2; ++j) acc[i][j] = (f32x4){0.f, 0.f, 0.f, 0.f};

    short8 areg[2], breg[2];
#pragma unroll
    for (int p = 0; p < 2; ++p) {
        int c = tid + (p << 9);
        int row = c >> 3, col8 = (c & 7) << 3;
        areg[p] = *(const short8*)(A + (size_t)(m0 + row) * K + col8);
        breg[p] = *(const short8*)(Bt + (size_t)(n0 + row) * K + col8);
    }

    for (int k0 = 0; k0 < K; k0 += 64) {
        __syncthreads();
#pragma unroll
        for (int p = 0; p < 2; ++p) {
            int c = tid + (p << 9);
            int row = c >> 3, col8 = (c & 7) << 3;
            *(short8*)&As[row][col8] = areg[p];
            *(short8*)&Bs[row][col8] = breg[p];
        }
        __syncthreads();
        if (k0 + 64 < K) {
#pragma unroll
            for (int p = 0; p < 2; ++p) {
                int c = tid + (p << 9);
                int row = c >> 3, col8 = (c & 7) << 3;
                areg[p] = *(const short8*)(A + (size_t)(m0 + row) * K + k0 + 64 + col8);
                breg[p] = *(const short8*)(Bt + (size_t)(n0 + row) * K + k0 + 64 + col8);
            }
        }
#pragma unroll
        for (int ch = 0; ch < 2; ++ch) {
            short8 af[4], bf[2];
#pragma unroll
            for (int mt = 0; mt < 4; ++mt)
                af[mt] = *(const short8*)&As[mh + mt * 16 + ln][ch * 32 + quad * 8];
#pragma unroll
            for (int nt = 0; nt < 2; ++nt)
                bf[nt] = *(const short8*)&Bs[nh + nt * 16 + ln][ch * 32 + quad * 8];
#pragma unroll
            for (int mt = 0; mt < 4; ++mt)
#pragma unroll
                for (int nt = 0; nt < 2; ++nt)
                    acc[mt][nt] = __builtin_amdgcn_mfma_f32_16x16x32_bf16(
                        af[mt], bf[nt], acc[mt][nt], 0, 0, 0);
        }
    }

#pragma unroll
    for (int mt = 0; mt < 4; ++mt)
#pragma unroll
        for (int nt = 0; nt < 2; ++nt)
#pragma unroll
            for (int r = 0; r < 4; ++r) {
                int m = m0 + mh + mt * 16 + quad * 4 + r;
                int n = n0 + nh + nt * 16 + ln;
                out[(size_t)m * N + n] = acc[mt][nt][r] + bias[n];
            }
}

// ---------------------------------------------------------------------------
// Merged projections, XCD-swizzled, LDS 40960B -> 4 blocks/CU.
// blocks [0,512) = QV (BK=64, 2x[128][72]); blocks [512,768) = kproj
// (compensated, BK=32, 4x[128][40]; pad 40 keeps b128 16B-aligned).
// ---------------------------------------------------------------------------
__global__ __launch_bounds__(512)
void proj_qvk_k(const unsigned short* __restrict__ xh,
                const unsigned short* __restrict__ xl,
                const unsigned short* __restrict__ Wqt,
                const unsigned short* __restrict__ Wkh,
                const unsigned short* __restrict__ Wkl,
                unsigned short* __restrict__ qb,
                unsigned short* __restrict__ vb,
                unsigned short* __restrict__ vtout,
                unsigned short* __restrict__ kout,
                float* __restrict__ norms2)
{
    __shared__ __align__(16) unsigned short smem[20480];   // 40960 B
    const int blk = blockIdx.x;
    const int tid = threadIdx.x;
    const int lane = tid & 63, wave = tid >> 6;
    const int quad = lane >> 4, ln = lane & 15;
    const int K = DMODEL;

    if (blk < 512) {
        // ---------------- QV path (BK=64) ----------------
        unsigned short* As = smem;            // [128][72]
        unsigned short* Bs = smem + 9216;
        const int xcd = blk & 7, t2 = blk >> 3;      // t2 = n + 16*(m/8)
        const int m0 = ((t2 >> 4) * 8 + xcd) * 128;  // m in [0,32)
        const int n0 = (t2 & 15) * 128;              // n in [0,16)
        const int mh = (wave >> 2) << 6;
        const int nh = (wave & 3) << 5;

        f32x4 acc[4][2];
#pragma unroll
        for (int i = 0; i < 4; ++i)
#pragma unroll
            for (int j = 0; j < 2; ++j) acc[i][j] = (f32x4){0.f, 0.f, 0.f, 0.f};

        short8 areg[2], breg[2];
#pragma unroll
        for (int p = 0; p < 2; ++p) {
            int c = tid + (p << 9);
            int row = c >> 3, col8 = (c & 7) << 3;
            areg[p] = *(const short8*)(xh + (size_t)(m0 + row) * K + col8);
            breg[p] = *(const short8*)(Wqt + (size_t)(n0 + row) * K + col8);
        }

        for (int k0 = 0; k0 < K; k0 += 64) {
            __syncthreads();
#pragma unroll
            for (int p = 0; p < 2; ++p) {
                int c = tid + (p << 9);
                int row = c >> 3, col8 = (c & 7) << 3;
                *(short8*)&As[row * 72 + col8] = areg[p];
                *(short8*)&Bs[row * 72 + col8] = breg[p];
            }
            __syncthreads();
            if (k0 + 64 < K) {
#pragma unroll
                for (int p = 0; p < 2; ++p) {
                    int c = tid + (p << 9);
                    int row = c >> 3, col8 = (c & 7) << 3;
                    areg[p] = *(const short8*)(xh + (size_t)(m0 + row) * K + k0 + 64 + col8);
                    breg[p] = *(const short8*)(Wqt + (size_t)(n0 + row) * K + k0 + 64 + col8);
                }
            }
#pragma unroll
            for (int ch = 0; ch < 2; ++ch) {
                short8 af[4], bf[2];
#pragma unroll
                for (int mt = 0; mt < 4; ++mt)
                    af[mt] = *(const short8*)&As[(mh + mt * 16 + ln) * 72 + ch * 32 + quad * 8];
#pragma unroll
                for (int nt = 0; nt < 2; ++nt)
                    bf[nt] = *(const short8*)&Bs[(nh + nt * 16 + ln) * 72 + ch * 32 + quad * 8];
#pragma unroll
                for (int mt = 0; mt < 4; ++mt)
#pragma unroll
                    for (int nt = 0; nt < 2; ++nt)
                        acc[mt][nt] = __builtin_amdgcn_mfma_f32_16x16x32_bf16(
                            af[mt], bf[nt], acc[mt][nt], 0, 0, 0);
            }
        }

#pragma unroll
        for (int mt = 0; mt < 4; ++mt)
#pragma unroll
            for (int nt = 0; nt < 2; ++nt) {
                int n = n0 + nh + nt * 16 + ln;
                int mb = m0 + mh + mt * 16 + quad * 4;
                int b = mb >> 11, s0 = mb & (SEQ - 1);
                int d = n & 63;
                if (n < DMODEL) {           // Q, pre-scaled incl. log2(e)
                    int h = n >> 6;
                    unsigned short* qp_ =
                        qb + ((size_t)(b * NH + h) * SEQ + s0) * DHEAD + d;
#pragma unroll
                    for (int r = 0; r < 4; ++r)
                        qp_[(size_t)r * DHEAD] = f2bf(acc[mt][nt][r] * 0.18033688f);
                } else {                    // V: row-major + transposed
                    int h = (n >> 6) - NH;
                    unsigned short* vp_ =
                        vb + ((size_t)(b * NH + h) * SEQ + s0) * DHEAD + d;
                    short4v tv;
#pragma unroll
                    for (int r = 0; r < 4; ++r) {
                        unsigned short bv = f2bf(acc[mt][nt][r]);
                        vp_[(size_t)r * DHEAD] = bv;
                        tv[r] = (short)bv;
                    }
                    *(short4v*)(vtout + ((size_t)(b * NH + h) * DHEAD + d) * SEQ + s0) = tv;
                }
            }
    } else {
        // ---------------- kproj path (compensated, BK=32, M2xN4) ---------
        unsigned short* Ah = smem;            // [128][40] each
        unsigned short* Al = smem + 5120;
        unsigned short* Bh = smem + 10240;
        unsigned short* Bl = smem + 15360;
        const int sb = blk - 512;
        const int xcd = sb & 7, t2 = sb >> 3;        // t2 = (m/8) + 4*n
        const int m0 = ((t2 & 3) * 8 + xcd) * 128;   // m in [0,32)
        const int n0 = (t2 >> 2) * 128;              // n in [0,8)
        const int mh = (wave >> 1) << 5;      // 4 m-groups x 32 rows
        const int nh = (wave & 1) << 6;       // 2 n-groups x 64 cols

        f32x4 acc[2][4];
#pragma unroll
        for (int i = 0; i < 2; ++i)
#pragma unroll
            for (int j = 0; j < 4; ++j) acc[i][j] = (f32x4){0.f, 0.f, 0.f, 0.f};

        const int krow = tid >> 2, kcol8 = (tid & 3) << 3;   // 128 x 32
        short8 ahreg, alreg, bhreg, blreg;
        {
            size_t ga = (size_t)(m0 + krow) * K + kcol8;
            size_t gb = (size_t)(n0 + krow) * K + kcol8;
            ahreg = *(const short8*)(xh + ga);
            alreg = *(const short8*)(xl + ga);
            bhreg = *(const short8*)(Wkh + gb);
            blreg = *(const short8*)(Wkl + gb);
        }

        for (int k0 = 0; k0 < K; k0 += 32) {
            __syncthreads();
            *(short8*)&Ah[krow * 40 + kcol8] = ahreg;
            *(short8*)&Al[krow * 40 + kcol8] = alreg;
            *(short8*)&Bh[krow * 40 + kcol8] = bhreg;
            *(short8*)&Bl[krow * 40 + kcol8] = blreg;
            __syncthreads();
            if (k0 + 32 < K) {
                size_t ga = (size_t)(m0 + krow) * K + k0 + 32 + kcol8;
                size_t gb = (size_t)(n0 + krow) * K + k0 + 32 + kcol8;
                ahreg = *(const short8*)(xh + ga);
                alreg = *(const short8*)(xl + ga);
                bhreg = *(const short8*)(Wkh + gb);
                blreg = *(const short8*)(Wkl + gb);
            }
            short8 afh[2], afl[2];
#pragma unroll
            for (int mt = 0; mt < 2; ++mt) {
                afh[mt] = *(const short8*)&Ah[(mh + mt * 16 + ln) * 40 + quad * 8];
                afl[mt] = *(const short8*)&Al[(mh + mt * 16 + ln) * 40 + quad * 8];
            }
#pragma unroll
            for (int nt = 0; nt < 4; ++nt) {
                short8 bfh = *(const short8*)&Bh[(nh + nt * 16 + ln) * 40 + quad * 8];
                short8 bfl = *(const short8*)&Bl[(nh + nt * 16 + ln) * 40 + quad * 8];
#pragma unroll
                for (int mt = 0; mt < 2; ++mt) {
                    acc[mt][nt] = __builtin_amdgcn_mfma_f32_16x16x32_bf16(afh[mt], bfh, acc[mt][nt], 0, 0, 0);
                    acc[mt][nt] = __builtin_amdgcn_mfma_f32_16x16x32_bf16(afh[mt], bfl, acc[mt][nt], 0, 0, 0);
                    acc[mt][nt] = __builtin_amdgcn_mfma_f32_16x16x32_bf16(afl[mt], bfh, acc[mt][nt], 0, 0, 0);
                }
            }
        }

        const int h = (n0 + nh) >> 6;
#pragma unroll
        for (int mt = 0; mt < 2; ++mt)
#pragma unroll
            for (int r = 0; r < 4; ++r) {
                int m = m0 + mh + mt * 16 + quad * 4 + r;
                int b = m >> 11, s = m & (SEQ - 1);
                size_t rowbase = ((size_t)(b * NH + h) * SEQ + s) * DHEAD;
#pragma unroll
                for (int nt = 0; nt < 4; ++nt)
                    kout[rowbase + nt * 16 + ln] = f2bf(acc[mt][nt][r]);
                float s2 = acc[mt][0][r] * acc[mt][0][r] + acc[mt][1][r] * acc[mt][1][r] +
                           acc[mt][2][r] * acc[mt][2][r] + acc[mt][3][r] * acc[mt][3][r];
#pragma unroll
                for (int off = 1; off <= 8; off <<= 1)
                    s2 += __shfl_xor(s2, off);
                if (ln == 0)
                    norms2[(size_t)(b * NH + h) * SEQ + s] = s2;
            }
    }
}

// ---------------------------------------------------------------------------
// topk + gather fused, 1024 threads (2 CE/thread over 66 bitonic stages).
// ---------------------------------------------------------------------------
__global__ __launch_bounds__(1024)
void topk_gather_k(const float* __restrict__ norms2,
                   const unsigned short* __restrict__ k,
                   const unsigned short* __restrict__ v,
                   unsigned short* __restrict__ gk,
                   unsigned short* __restrict__ gvt)
{
    __shared__ unsigned long long keys[SEQ];
    __shared__ int tix[NGPAD];
    __shared__ __align__(16) unsigned short T[64][72];
    const int bh = blockIdx.x;
    const int tid = threadIdx.x;
    const float* nb = norms2 + (size_t)bh * SEQ;
    const size_t base = (size_t)bh * SEQ * DHEAD;

    for (int i = tid; i < SEQ; i += 1024) {
        float nrm = sqrtf(nb[i]);
        keys[i] = ((unsigned long long)__float_as_uint(nrm) << 32) |
                  (unsigned int)(0xFFFFFFFFu - (unsigned int)i);
    }
    __syncthreads();
    for (int kk = 2; kk <= SEQ; kk <<= 1) {
        for (int j = kk >> 1; j > 0; j >>= 1) {
            for (int i = tid; i < SEQ; i += 1024) {
                int ixj = i ^ j;
                if (ixj > i) {
                    unsigned long long a = keys[i], b = keys[ixj];
                    bool up = ((i & kk) == 0);
                    if ((a > b) == up) { keys[i] = b; keys[ixj] = a; }
                }
            }
            __syncthreads();
        }
    }
    if (tid < NGPAD) {
        tix[tid] = (tid < NG)
            ? (int)(0xFFFFFFFFu - (unsigned int)(keys[SEQ - 1 - tid] & 0xFFFFFFFFu))
            : 0;
    }
    __syncthreads();

    for (int t = 0; t < NGPAD / 64; ++t) {
        {
            int row = tid >> 4, col4 = (tid & 15) << 2;   // 64 rows x 64 cols
            int g = t * 64 + row;
            short4v kv = (short4v)0, vv = (short4v)0;
            if (g < NG) {
                int sidx = tix[g];
                kv = *(const short4v*)(k + base + (size_t)sidx * DHEAD + col4);
                vv = *(const short4v*)(v + base + (size_t)sidx * DHEAD + col4);
            }
            *(short4v*)(gk + ((size_t)bh * NGPAD + g) * DHEAD + col4) = kv;
            *(short4v*)&T[row][col4] = vv;
        }
        __syncthreads();
        {
            int d = tid >> 4, k4 = (tid & 15) << 2;
            short4v o;
#pragma unroll
            for (int i = 0; i < 4; ++i) o[i] = (short)T[k4 + i][d];
            *(short4v*)(gvt + ((size_t)bh * DHEAD + d) * NGPAD + t * 64 + k4) = o;
        }
        __syncthreads();
    }
}

// ---------------------------------------------------------------------------
// Fused attention r19: r17 structure, Wg gate weights read DIRECT from
// global (r14-verified path) -> LDS 36864B -> 4 blocks/CU.
// ---------------------------------------------------------------------------
__global__ __launch_bounds__(256, 2)
void attn_fused_k(const unsigned short* __restrict__ qb,
                  const unsigned short* __restrict__ kb,
                  const unsigned short* __restrict__ vt,
                  const unsigned short* __restrict__ gk,
                  const unsigned short* __restrict__ gvt,
                  const unsigned short* __restrict__ Wgt,
                  const float* __restrict__ gamma,
                  const float* __restrict__ beta,
                  const float* __restrict__ bg,
                  unsigned short* __restrict__ fused)
{
    // smem layout (shorts): [0,9216) Ks[2][64][72]  (= Ps[128][72] alias)
    //                       [9216,18432) Vt[2][64][72]
    __shared__ __align__(16) unsigned short smem[18432];
    unsigned short* const KsB = smem;
    unsigned short* const VtB = smem + 9216;
    unsigned short (*Ps)[72]  = (unsigned short (*)[72])smem;

    const int flat = blockIdx.x;
    const int bh = ((flat >> 7) << 3) | (flat & 7);   // flat%8 == bh%8 (XCD)
    const int q0 = ((flat >> 3) & 15) * 128;
    const int tid = threadIdx.x;
    const int lane = tid & 63, wave = tid >> 6;       // 4 waves
    const int quad = lane >> 4, ln = lane & 15;
    const size_t base = (size_t)bh * SEQ * DHEAD;
    const unsigned short* gkb = gk + (size_t)bh * NGPAD * DHEAD;
    const unsigned short* gvb = gvt + (size_t)bh * DHEAD * NGPAD;

    short8 qf[2][2];
#pragma unroll
    for (int mt = 0; mt < 2; ++mt) {
        const unsigned short* qp = qb + base + (size_t)(q0 + wave * 32 + mt * 16 + ln) * DHEAD;
        qf[mt][0] = *(const short8*)(qp + quad * 8);
        qf[mt][1] = *(const short8*)(qp + 32 + quad * 8);
    }

    // ones / last-tile-mask B-frags for row-sum MFMAs
    short8 onesv, maskv;
#pragma unroll
    for (int j = 0; j < 8; ++j) {
        onesv[j] = (short)0x3F80;                              // bf16 1.0
        maskv[j] = (short)((quad * 8 + j) < 12 ? 0x3F80 : 0);  // NG-192=12
    }

    f32x4 O[2][4], Og[2][4], lsacc[2], lgacc[2];
#pragma unroll
    for (int mt = 0; mt < 2; ++mt) {
#pragma unroll
        for (int nt = 0; nt < 4; ++nt) {
            O[mt][nt] = (f32x4){0.f, 0.f, 0.f, 0.f};
            Og[mt][nt] = (f32x4){0.f, 0.f, 0.f, 0.f};
        }
        lsacc[mt] = (f32x4){0.f, 0.f, 0.f, 0.f};
        lgacc[mt] = (f32x4){0.f, 0.f, 0.f, 0.f};
    }

    short8 kreg[2], vreg[2];
    int srow[2], scol8[2], psrow[2];
#pragma unroll
    for (int p = 0; p < 2; ++p) {
        int idx = tid + (p << 8);
        srow[p] = idx >> 3;
        scol8[p] = (idx & 7) << 3;
        // phi: [b5 | b3 b2 | b4 | b1 b0]  (K-row permutation, verified r14)
        psrow[p] = (srow[p] & 0x20) | ((srow[p] & 0x0C) << 1) |
                   ((srow[p] & 0x10) >> 2) | (srow[p] & 3);
    }

    auto loadT = [&](int i) {
#pragma unroll
        for (int p = 0; p < 2; ++p) {
            if (i < 32) {
                kreg[p] = *(const short8*)(kb + base + (size_t)(i * 64 + psrow[p]) * DHEAD + scol8[p]);
                vreg[p] = *(const short8*)(vt + base + (size_t)srow[p] * SEQ + i * 64 + scol8[p]);
            } else {
                int g = i - 32;
                kreg[p] = *(const short8*)(gkb + (size_t)(g * 64 + psrow[p]) * DHEAD + scol8[p]);
                vreg[p] = *(const short8*)(gvb + (size_t)srow[p] * NGPAD + g * 64 + scol8[p]);
            }
        }
    };
    auto storeT = [&](int buf) {
        unsigned short* kd = KsB + buf * 4608;
        unsigned short* vd = VtB + buf * 4608;
#pragma unroll
        for (int p = 0; p < 2; ++p) {
            *(short8*)&kd[srow[p] * 72 + scol8[p]] = kreg[p];
            *(short8*)&vd[srow[p] * 72 + scol8[p]] = vreg[p];
        }
    };

    loadT(0);
    storeT(0);
    loadT(1);
    __syncthreads();

    // ---- local: 32 tiles ----
    for (int t = 0; t < 32; ++t) {
        const int cur = t & 1;
        const unsigned short* Kc = KsB + cur * 4608;
        const unsigned short* Vc = VtB + cur * 4608;

        // swapped QK^T: lane holds S^T[k_phys = phi(nt*16+quad*4+r)][q=ln]
        f32x4 s[2][4];
#pragma unroll
        for (int mt = 0; mt < 2; ++mt)
#pragma unroll
            for (int nt = 0; nt < 4; ++nt) s[mt][nt] = (f32x4){0.f, 0.f, 0.f, 0.f};
        __builtin_amdgcn_s_setprio(1);
#pragma unroll
        for (int nt = 0; nt < 4; ++nt) {
            short8 kf0 = *(const short8*)&Kc[(nt * 16 + ln) * 72 + quad * 8];
            short8 kf1 = *(const short8*)&Kc[(nt * 16 + ln) * 72 + 32 + quad * 8];
#pragma unroll
            for (int mt = 0; mt < 2; ++mt) {
                s[mt][nt] = __builtin_amdgcn_mfma_f32_16x16x32_bf16(kf0, qf[mt][0], s[mt][nt], 0, 0, 0);
                s[mt][nt] = __builtin_amdgcn_mfma_f32_16x16x32_bf16(kf1, qf[mt][1], s[mt][nt], 0, 0, 0);
            }
        }
        __builtin_amdgcn_s_setprio(0);

        // exp + pack into mfma32 A-frags: pf8[mt][c] = k_phys c*32+quad*8+[0..7]
        short8 pf8[2][2];
#pragma unroll
        for (int mt = 0; mt < 2; ++mt)
#pragma unroll
            for (int nt = 0; nt < 4; ++nt)
#pragma unroll
                for (int r = 0; r < 4; ++r) {
                    unsigned int u = __float_as_uint(__builtin_amdgcn_exp2f(s[mt][nt][r]));
                    pf8[mt][nt >> 1][((nt & 1) << 2) | r] = (short)(u >> 16);
                }

        // PV + row-sum: full-rate mfma32, P from registers
        __builtin_amdgcn_s_setprio(1);
#pragma unroll
        for (int dt = 0; dt < 4; ++dt)
#pragma unroll
            for (int c = 0; c < 2; ++c) {
                short8 vf = *(const short8*)&Vc[(dt * 16 + ln) * 72 + c * 32 + quad * 8];
#pragma unroll
                for (int mt = 0; mt < 2; ++mt)
                    O[mt][dt] = __builtin_amdgcn_mfma_f32_16x16x32_bf16(
                        pf8[mt][c], vf, O[mt][dt], 0, 0, 0);
            }
#pragma unroll
        for (int c = 0; c < 2; ++c)
#pragma unroll
            for (int mt = 0; mt < 2; ++mt)
                lsacc[mt] = __builtin_amdgcn_mfma_f32_16x16x32_bf16(
                    pf8[mt][c], onesv, lsacc[mt], 0, 0, 0);
        __builtin_amdgcn_s_setprio(0);

        storeT(cur ^ 1);            // tile t+1 -> other buffer
        if (t + 2 <= 35) loadT(t + 2);
        __syncthreads();
    }

    // ---- global: 4 gathered tiles (padded rows: K=0 -> P=1, V=0; mask
    //      excludes them from lgacc; tiles 0-2 fully valid) ----
    for (int tg = 0; tg < 4; ++tg) {
        const int t = 32 + tg;
        const int cur = t & 1;
        const unsigned short* Kc = KsB + cur * 4608;
        const unsigned short* Vc = VtB + cur * 4608;

        f32x4 s[2][4];
#pragma unroll
        for (int mt = 0; mt < 2; ++mt)
#pragma unroll
            for (int nt = 0; nt < 4; ++nt) s[mt][nt] = (f32x4){0.f, 0.f, 0.f, 0.f};
        __builtin_amdgcn_s_setprio(1);
#pragma unroll
        for (int nt = 0; nt < 4; ++nt) {
            short8 kf0 = *(const short8*)&Kc[(nt * 16 + ln) * 72 + quad * 8];
            short8 kf1 = *(const short8*)&Kc[(nt * 16 + ln) * 72 + 32 + quad * 8];
#pragma unroll
            for (int mt = 0; mt < 2; ++mt) {
                s[mt][nt] = __builtin_amdgcn_mfma_f32_16x16x32_bf16(kf0, qf[mt][0], s[mt][nt], 0, 0, 0);
                s[mt][nt] = __builtin_amdgcn_mfma_f32_16x16x32_bf16(kf1, qf[mt][1], s[mt][nt], 0, 0, 0);
            }
        }
        __builtin_amdgcn_s_setprio(0);

        short8 pf8[2][2];
#pragma unroll
        for (int mt = 0; mt < 2; ++mt)
#pragma unroll
            for (int nt = 0; nt < 4; ++nt)
#pragma unroll
                for (int r = 0; r < 4; ++r) {
                    unsigned int u = __float_as_uint(__builtin_amdgcn_exp2f(s[mt][nt][r]));
                    pf8[mt][nt >> 1][((nt & 1) << 2) | r] = (short)(u >> 16);
                }

        __builtin_amdgcn_s_setprio(1);
#pragma unroll
        for (int dt = 0; dt < 4; ++dt)
#pragma unroll
            for (int c = 0; c < 2; ++c) {
                short8 vf = *(const short8*)&Vc[(dt * 16 + ln) * 72 + c * 32 + quad * 8];
#pragma unroll
                for (int mt = 0; mt < 2; ++mt)
                    Og[mt][dt] = __builtin_amdgcn_mfma_f32_16x16x32_bf16(
                        pf8[mt][c], vf, Og[mt][dt], 0, 0, 0);
            }
        if (tg < 3) {
#pragma unroll
            for (int c = 0; c < 2; ++c)
#pragma unroll
                for (int mt = 0; mt < 2; ++mt)
                    lgacc[mt] = __builtin_amdgcn_mfma_f32_16x16x32_bf16(
                        pf8[mt][c], onesv, lgacc[mt], 0, 0, 0);
        } else {
            // last tile: only k_phys < 12 valid (c=0 chunk), via maskv
#pragma unroll
            for (int mt = 0; mt < 2; ++mt)
                lgacc[mt] = __builtin_amdgcn_mfma_f32_16x16x32_bf16(
                    pf8[mt][0], maskv, lgacc[mt], 0, 0, 0);
        }
        __builtin_amdgcn_s_setprio(0);

        if (t < 35) storeT(cur ^ 1);
        if (t + 2 <= 35) loadT(t + 2);
        __syncthreads();            // last iter: protects Ps alias in epilogue
    }

    // ---- row sums already in O layout (q = quad*4+r) ----
    float invl[2][4], invg[2][4];
#pragma unroll
    for (int mt = 0; mt < 2; ++mt)
#pragma unroll
        for (int r = 0; r < 4; ++r) {
            invl[mt][r] = 1.f / lsacc[mt][r];
            invg[mt][r] = 1.f / lgacc[mt][r];
        }

    // ---- layernorm(global) ----
    float xs[2][4][4];
#pragma unroll
    for (int mt = 0; mt < 2; ++mt)
#pragma unroll
        for (int r = 0; r < 4; ++r) {
            float inv = invg[mt][r];
#pragma unroll
            for (int nt = 0; nt < 4; ++nt) xs[mt][nt][r] = Og[mt][nt][r] * inv;
        }
    float mu[2][4], rsd[2][4];
#pragma unroll
    for (int mt = 0; mt < 2; ++mt)
#pragma unroll
        for (int r = 0; r < 4; ++r) {
            float sm = xs[mt][0][r] + xs[mt][1][r] + xs[mt][2][r] + xs[mt][3][r];
#pragma unroll
            for (int off = 1; off <= 8; off <<= 1) sm += __shfl_xor(sm, off);
            mu[mt][r] = sm * (1.f / 64.f);
        }
#pragma unroll
    for (int mt = 0; mt < 2; ++mt)
#pragma unroll
        for (int r = 0; r < 4; ++r) {
            float sv = 0.f;
#pragma unroll
            for (int nt = 0; nt < 4; ++nt) {
                float d = xs[mt][nt][r] - mu[mt][r];
                sv += d * d;
            }
#pragma unroll
            for (int off = 1; off <= 8; off <<= 1) sv += __shfl_xor(sv, off);
            rsd[mt][r] = rsqrtf(sv * (1.f / 64.f) + LNEPS);
        }
#pragma unroll
    for (int nt = 0; nt < 4; ++nt) {
        float g = gamma[nt * 16 + ln], bb = beta[nt * 16 + ln];
#pragma unroll
        for (int mt = 0; mt < 2; ++mt)
#pragma unroll
            for (int r = 0; r < 4; ++r)
                xs[mt][nt][r] = (xs[mt][nt][r] - mu[mt][r]) * rsd[mt][r] * g + bb;
    }

    // ---- gate via MFMA (Ps alias; intra-wave rows, no barrier; Wg from
    //      global Wgt - r14-verified path) ----
    float lf[2][4][4];
#pragma unroll
    for (int mt = 0; mt < 2; ++mt)
#pragma unroll
        for (int nt = 0; nt < 4; ++nt)
#pragma unroll
            for (int r = 0; r < 4; ++r) {
                lf[mt][nt][r] = O[mt][nt][r] * invl[mt][r];
                Ps[wave * 32 + mt * 16 + quad * 4 + r][nt * 16 + ln] = f2bf(lf[mt][nt][r]);
            }
    f32x4 gacc[2][4];
#pragma unroll
    for (int ng = 0; ng < 4; ++ng) {
        float bgv = bg[ng * 16 + ln];
#pragma unroll
        for (int mt = 0; mt < 2; ++mt)
            gacc[mt][ng] = (f32x4){bgv, bgv, bgv, bgv};
    }
#pragma unroll
    for (int ch = 0; ch < 2; ++ch) {
        short8 af[2];
#pragma unroll
        for (int mt = 0; mt < 2; ++mt)
            af[mt] = *(const short8*)&Ps[wave * 32 + mt * 16 + ln][ch * 32 + quad * 8];
#pragma unroll
        for (int ng = 0; ng < 4; ++ng) {
            short8 bf = *(const short8*)(Wgt + (size_t)(ng * 16 + ln) * 128 + ch * 32 + quad * 8);
#pragma unroll
            for (int mt = 0; mt < 2; ++mt)
                gacc[mt][ng] = __builtin_amdgcn_mfma_f32_16x16x32_bf16(af[mt], bf, gacc[mt][ng], 0, 0, 0);
        }
    }
#pragma unroll
    for (int mt = 0; mt < 2; ++mt)
#pragma unroll
        for (int nt = 0; nt < 4; ++nt)
#pragma unroll
            for (int r = 0; r < 4; ++r)
                Ps[wave * 32 + mt * 16 + quad * 4 + r][nt * 16 + ln] = f2bf(xs[mt][nt][r]);
#pragma unroll
    for (int ch = 0; ch < 2; ++ch) {
        short8 af[2];
#pragma unroll
        for (int mt = 0; mt < 2; ++mt)
            af[mt] = *(const short8*)&Ps[wave * 32 + mt * 16 + ln][ch * 32 + quad * 8];
#pragma unroll
        for (int ng = 0; ng < 4; ++ng) {
            short8 bf = *(const short8*)(Wgt + (size_t)(ng * 16 + ln) * 128 + 64 + ch * 32 + quad * 8);
#pragma unroll
            for (int mt = 0; mt < 2; ++mt)
                gacc[mt][ng] = __builtin_amdgcn_mfma_f32_16x16x32_bf16(af[mt], bf, gacc[mt][ng], 0, 0, 0);
        }
    }

    // ---- fuse + store ----
    const int b = bh >> 4, h = bh & 15;
#pragma unroll
    for (int mt = 0; mt < 2; ++mt)
#pragma unroll
        for (int ng = 0; ng < 4; ++ng)
#pragma unroll
            for (int r = 0; r < 4; ++r) {
                float gt = 1.f / (1.f + __expf(-gacc[mt][ng][r]));
                float f = gt * lf[mt][ng][r] + (1.f - gt) * xs[mt][ng][r];
                int s = q0 + wave * 32 + mt * 16 + quad * 4 + r;
                fused[((size_t)(b * SEQ + s)) * DMODEL + h * DHEAD + ng * 16 + ln] = f2bf(f);
            }
}

// ---------------------------------------------------------------------------
extern "C" void kernel_launch(void* const* d_in, const int* in_sizes, int n_in,
                              void* d_out, int out_size, void* d_ws, size_t ws_size,
                              hipStream_t stream)
{
    (void)in_sizes; (void)n_in; (void)out_size; (void)ws_size;
    const float* x    = (const float*)d_in[0];
    const float* Wq   = (const float*)d_in[1];
    const float* Wk   = (const float*)d_in[2];
    const float* Wv   = (const float*)d_in[3];
    const float* Wo   = (const float*)d_in[4];
    const float* bo   = (const float*)d_in[5];
    const float* ln_g = (const float*)d_in[6];
    const float* ln_b = (const float*)d_in[7];
    const float* Wg   = (const float*)d_in[8];
    const float* bg   = (const float*)d_in[9];

    char* w = (char*)d_ws;
    const size_t MB = 1024ull * 1024ull;
    unsigned short* kb16  = (unsigned short*)(w);
    unsigned short* qb16  = (unsigned short*)(w + 8 * MB);
    unsigned short* vb16  = (unsigned short*)(w + 16 * MB);
    unsigned short* vt16  = (unsigned short*)(w + 24 * MB);
    unsigned short* xh    = (unsigned short*)(w + 32 * MB);
    unsigned short* xl    = (unsigned short*)(w + 40 * MB);
    unsigned short* Wqt   = (unsigned short*)(w + 48 * MB);
    unsigned short* Wvt   = (unsigned short*)(w + 50 * MB);   // contiguous after Wqt
    unsigned short* Wot   = (unsigned short*)(w + 52 * MB);
    unsigned short* Wkh   = (unsigned short*)(w + 54 * MB);
    unsigned short* Wkl   = (unsigned short*)(w + 56 * MB);
    unsigned short* Wgt   = (unsigned short*)(w + 58 * MB);
    float*          norms2= (float*)(w + 59 * MB);
    unsigned short* gk16  = (unsigned short*)(w + 60 * MB);
    unsigned short* gvt16 = (unsigned short*)(w + 61 * MB);
    unsigned short* fusedb = xh;   // xh dead after projections
    (void)Wvt;

    const int M = 4096, N = 1024, K = 1024;

    prep_k<<<3073, 256, 0, stream>>>(x, Wq, Wv, Wo, Wk, Wg,
                                     xh, xl, Wqt, Wvt, Wot, Wkh, Wkl, Wgt);

    proj_qvk_k<<<768, 512, 0, stream>>>(xh, xl, Wqt, Wkh, Wkl,
                                        qb16, vb16, vt16, kb16, norms2);

    topk_gather_k<<<BHT, 1024, 0, stream>>>(norms2, kb16, vb16, gk16, gvt16);

    attn_fused_k<<<512, 256, 0, stream>>>(qb16, kb16, vt16, gk16, gvt16, Wgt,
                                          ln_g, ln_b, bg, fusedb);

    gemm_bf16_k<<<256, 512, 0, stream>>>(fusedb, Wot, bo, (float*)d_out,
                                         M, N, K);
}